// Round 3
// baseline (563.058 us; speedup 1.0000x reference)
//
#include <hip/hip_runtime.h>
#include <math.h>
#include <stdint.h>

#define DEV __device__ __forceinline__

using f32x4  = __attribute__((ext_vector_type(4))) float;
using short8 = __attribute__((ext_vector_type(8))) short;

DEV float lrelu(float x){ return x > 0.f ? x : 0.01f*x; }
DEV float elu1(float x){ return x > 0.f ? x : __expf(x)-1.f; }

DEV uint32_t bf16_rne(float x){
  uint32_t b = __float_as_uint(x);
  return (b + 0x7fffu + ((b >> 16) & 1u)) >> 16;
}
// pack f32 -> (hi bf16 | lo bf16), value ~= hi + lo to ~16 mantissa bits
DEV uint32_t pack_hl(float x){
  uint32_t hi = bf16_rne(x);
  float lo = x - __uint_as_float(hi << 16);
  return (hi << 16) | bf16_rne(lo);
}
DEV float unpack_hl(uint32_t u){
  return __uint_as_float(u & 0xffff0000u) + __uint_as_float(u << 16);
}

DEV int lower_bound_i(const int* __restrict__ a, int n, int key){
  int lo = 0, hi = n;
  while (lo < hi){ int mid = (lo+hi)>>1; if (a[mid] < key) lo = mid+1; else hi = mid; }
  return lo;
}

// ============ input prep: f32 -> packed hi/lo ============
__global__ void xprep(const float* __restrict__ x, uint32_t* __restrict__ xp, int n4){
  int i = blockIdx.x*256 + threadIdx.x;
  if (i >= n4) return;
  float4 v = ((const float4*)x)[i];
  uint4 o;
  o.x = pack_hl(v.x); o.y = pack_hl(v.y); o.z = pack_hl(v.z); o.w = pack_hl(v.w);
  ((uint4*)xp)[i] = o;
}

// ============ weight prep: W[K][128] f32 -> Wt_hi/Wt_lo [128][K] bf16 ============
__global__ void wprep(const float* __restrict__ W, unsigned short* __restrict__ Hi,
                      unsigned short* __restrict__ Lo, int K, int tot){
  int idx = blockIdx.x*256 + threadIdx.x;
  if (idx >= tot) return;
  int kn = K*128;
  int mat = idx / kn;
  int rem = idx - mat*kn;
  int k = rem >> 7;
  int n = rem & 127;
  float v = W[idx];
  uint32_t hi = bf16_rne(v);
  float lo = v - __uint_as_float(hi << 16);
  size_t o = (size_t)mat*kn + (size_t)n*K + k;
  Hi[o] = (unsigned short)hi;
  Lo[o] = (unsigned short)bf16_rne(lo);
}

// ============ MFMA GEMM: C[M,128] = A[M,K] @ W[K,128], bf16x2 triple scheme ============
// Block 256 = 4 waves; block tile = 128 rows x 128 cols; wave = 128 rows x 32 cols.
// W frags VGPR-resident per wave (loaded once). A: global->reg, v_perm split.
// mfma_f32_16x16x32_bf16: A/B lane&15 = m/n, lane>>4 = k-group of 8; D: col=lane&15,
// row=(lane>>4)*4+reg (m89-verified).
template<int KC, bool BIAS, bool PACK_OUT, bool F32_OUT, bool DOTA, bool DOTB>
__global__ __launch_bounds__(256) void gemm_mfma(
    const uint32_t* __restrict__ Apk, const unsigned short* __restrict__ Wt_hi,
    const unsigned short* __restrict__ Wt_lo, const float* __restrict__ bias,
    const float* __restrict__ va, const float* __restrict__ vb,
    float* __restrict__ Cf, uint32_t* __restrict__ Cp,
    float* __restrict__ outa, float* __restrict__ outb, int M)
{
  constexpr int K = KC*32;
  const int tid = threadIdx.x;
  const int lane = tid & 63;
  const int wv = tid >> 6;
  const int ml = lane & 15;
  const int kg = lane >> 4;
  const int R0 = blockIdx.x * 128;

  __shared__ float sd[4][128][2];

  // resident B fragments
  short8 Bh[KC][2], Bl[KC][2];
  #pragma unroll
  for (int kc = 0; kc < KC; ++kc){
    #pragma unroll
    for (int nt = 0; nt < 2; ++nt){
      int n = wv*32 + nt*16 + ml;
      int k = kc*32 + kg*8;
      Bh[kc][nt] = *(const short8*)(Wt_hi + (size_t)n*K + k);
      Bl[kc][nt] = *(const short8*)(Wt_lo + (size_t)n*K + k);
    }
  }

  const uint32_t* arow[8];
  #pragma unroll
  for (int mt = 0; mt < 8; ++mt){
    int r = R0 + mt*16 + ml; r = r < M ? r : M-1;
    arow[mt] = Apk + (size_t)r*K + kg*8;
  }

  f32x4 acc[8][2];
  #pragma unroll
  for (int mt = 0; mt < 8; ++mt)
    #pragma unroll
    for (int nt = 0; nt < 2; ++nt)
      acc[mt][nt] = (f32x4){0.f,0.f,0.f,0.f};

  #pragma unroll
  for (int kc = 0; kc < KC; ++kc){
    #pragma unroll
    for (int mt = 0; mt < 8; ++mt){
      uint4 a0 = *(const uint4*)(arow[mt] + kc*32);
      uint4 a1 = *(const uint4*)(arow[mt] + kc*32 + 4);
      union { uint32_t u[4]; short8 s; } H, L;
      H.u[0] = __builtin_amdgcn_perm(a0.y, a0.x, 0x07060302u);
      H.u[1] = __builtin_amdgcn_perm(a0.w, a0.z, 0x07060302u);
      H.u[2] = __builtin_amdgcn_perm(a1.y, a1.x, 0x07060302u);
      H.u[3] = __builtin_amdgcn_perm(a1.w, a1.z, 0x07060302u);
      L.u[0] = __builtin_amdgcn_perm(a0.y, a0.x, 0x05040100u);
      L.u[1] = __builtin_amdgcn_perm(a0.w, a0.z, 0x05040100u);
      L.u[2] = __builtin_amdgcn_perm(a1.y, a1.x, 0x05040100u);
      L.u[3] = __builtin_amdgcn_perm(a1.w, a1.z, 0x05040100u);
      #pragma unroll
      for (int nt = 0; nt < 2; ++nt){
        acc[mt][nt] = __builtin_amdgcn_mfma_f32_16x16x32_bf16(H.s, Bh[kc][nt], acc[mt][nt], 0, 0, 0);
        acc[mt][nt] = __builtin_amdgcn_mfma_f32_16x16x32_bf16(H.s, Bl[kc][nt], acc[mt][nt], 0, 0, 0);
        acc[mt][nt] = __builtin_amdgcn_mfma_f32_16x16x32_bf16(L.s, Bh[kc][nt], acc[mt][nt], 0, 0, 0);
      }
    }
  }

  // ---- epilogue ----
  float bv[2];
  if constexpr (BIAS){
    bv[0] = bias[wv*32 + ml];
    bv[1] = bias[wv*32 + 16 + ml];
  }
  #pragma unroll
  for (int mt = 0; mt < 8; ++mt){
    #pragma unroll
    for (int nt = 0; nt < 2; ++nt){
      #pragma unroll
      for (int r = 0; r < 4; ++r){
        int row = R0 + mt*16 + kg*4 + r;
        int col = wv*32 + nt*16 + ml;
        float v = acc[mt][nt][r];
        if (row < M){
          if constexpr (F32_OUT) Cf[(size_t)row*128 + col] = v;
          if constexpr (PACK_OUT){
            float o = v;
            if constexpr (BIAS) o = lrelu(o + bv[nt]);
            Cp[(size_t)row*128 + col] = pack_hl(o);
          }
        }
      }
    }
  }

  if constexpr (DOTA || DOTB){
    float vaL[2] = {0.f,0.f}, vbL[2] = {0.f,0.f};
    if constexpr (DOTA){ vaL[0] = va[wv*32 + ml]; vaL[1] = va[wv*32 + 16 + ml]; }
    if constexpr (DOTB){ vbL[0] = vb[wv*32 + ml]; vbL[1] = vb[wv*32 + 16 + ml]; }
    #pragma unroll
    for (int mt = 0; mt < 8; ++mt){
      #pragma unroll
      for (int r = 0; r < 4; ++r){
        float pa = 0.f, pb = 0.f;
        #pragma unroll
        for (int nt = 0; nt < 2; ++nt){
          float v = acc[mt][nt][r];
          if constexpr (DOTA) pa = fmaf(v, vaL[nt], pa);
          if constexpr (DOTB) pb = fmaf(v, vbL[nt], pb);
        }
        #pragma unroll
        for (int o = 8; o; o >>= 1){
          if constexpr (DOTA) pa += __shfl_xor(pa, o, 64);
          if constexpr (DOTB) pb += __shfl_xor(pb, o, 64);
        }
        if (ml == 0){
          int rl = mt*16 + kg*4 + r;
          sd[wv][rl][0] = pa;
          sd[wv][rl][1] = pb;
        }
      }
    }
    __syncthreads();
    if (tid < 128){
      int row = R0 + tid;
      if (row < M){
        if constexpr (DOTA){
          float da = sd[0][tid][0] + sd[1][tid][0] + sd[2][tid][0] + sd[3][tid][0];
          outa[row] = da;
        }
        if constexpr (DOTB){
          float db = sd[0][tid][1] + sd[1][tid][1] + sd[2][tid][1] + sd[3][tid][1];
          outb[row] = db;
        }
      }
    }
  }
}

// ============ CSR build ============
__global__ void hist_k(const int* __restrict__ dstv, int* __restrict__ deg, int E){
  int e = blockIdx.x*256 + threadIdx.x;
  if (e < E) atomicAdd(&deg[dstv[e]], 1);
}

__global__ void scan_sum(const int* __restrict__ deg, int* __restrict__ bsum, int n){
  __shared__ int s4[4];
  int i = blockIdx.x*256 + threadIdx.x;
  int v = (i < n) ? deg[i] : 0;
  #pragma unroll
  for (int o = 32; o; o >>= 1) v += __shfl_down(v, o, 64);
  if ((threadIdx.x & 63) == 0) s4[threadIdx.x >> 6] = v;
  __syncthreads();
  if (threadIdx.x == 0) bsum[blockIdx.x] = s4[0]+s4[1]+s4[2]+s4[3];
}

__global__ void scan_blocksums(int* __restrict__ bsum, int nb){
  __shared__ int s[512];
  int t = threadIdx.x;
  s[t] = (t < nb) ? bsum[t] : 0;
  __syncthreads();
  for (int o = 1; o < 512; o <<= 1){
    int v = s[t];
    int u = (t >= o) ? s[t-o] : 0;
    __syncthreads();
    s[t] = v + u;
    __syncthreads();
  }
  if (t < nb) bsum[t] = t ? s[t-1] : 0;
}

__global__ void scan_final(const int* __restrict__ deg, const int* __restrict__ boff,
    int* __restrict__ rp, int* __restrict__ cur, int n, int E)
{
  __shared__ int wsum[4];
  int i = blockIdx.x*256 + threadIdx.x;
  int lane = threadIdx.x & 63, wv = threadIdx.x >> 6;
  int v = (i < n) ? deg[i] : 0;
  int inc = v;
  #pragma unroll
  for (int o = 1; o < 64; o <<= 1){
    int u = __shfl_up(inc, o, 64);
    if (lane >= o) inc += u;
  }
  if (lane == 63) wsum[wv] = inc;
  __syncthreads();
  int woff = boff[blockIdx.x];
  for (int wq = 0; wq < wv; ++wq) woff += wsum[wq];
  int excl = woff + inc - v;
  if (i < n){ rp[i] = excl; cur[i] = excl; }
  if (blockIdx.x == 0 && threadIdx.x == 0) rp[n] = E;
}

__global__ void scatter_k(const int* __restrict__ dstv, int* __restrict__ cur,
                          int* __restrict__ eids, int E){
  int e = blockIdx.x*256 + threadIdx.x;
  if (e < E){
    int p = atomicAdd(&cur[dstv[e]], 1);
    eids[p] = e;
  }
}

// ============ fused segment softmax + aggregation (one wave per dst node) ============
// Writes packed hi/lo h' for the next layer's MFMA GEMM.
__global__ __launch_bounds__(256) void gat_agg(const int* __restrict__ srcv,
    const int* __restrict__ eids, const int* __restrict__ rp,
    const float* __restrict__ asn, const float* __restrict__ adn,
    const float* __restrict__ hs, const float* __restrict__ bias,
    uint32_t* __restrict__ outp, int Nn)
{
  const int lane = threadIdx.x & 63;
  const int wv = threadIdx.x >> 6;
  const int d = blockIdx.x*4 + wv;
  if (d >= Nn) return;
  const int lo = rp[d], hi = rp[d+1];
  const int deg = hi - lo;
  float acc0 = 0.f, acc1 = 0.f;
  if (deg > 0){
    const float ad = adn[d];
    if (deg <= 64){
      int sid = 0; float lg = -1e30f;
      if (lane < deg){
        int eid = eids[lo + lane];
        sid = srcv[eid];
        lg = lrelu(asn[sid] + ad);
      }
      float m = lg;
      #pragma unroll
      for (int o = 32; o; o >>= 1) m = fmaxf(m, __shfl_xor(m, o, 64));
      float p = (lane < deg) ? __expf(lg - m) : 0.f;
      float s = p;
      #pragma unroll
      for (int o = 32; o; o >>= 1) s += __shfl_xor(s, o, 64);
      float alpha = p * (1.f / (s + 1e-16f));
      // batched gather: 8 loads in flight before use
      for (int base = 0; base < deg; base += 8){
        int nb = deg - base; nb = nb > 8 ? 8 : nb;
        float2 v[8]; float al[8];
        #pragma unroll
        for (int i = 0; i < 8; ++i){
          if (i < nb){
            int sd_ = __shfl(sid, base + i, 64);
            al[i] = __shfl(alpha, base + i, 64);
            v[i] = *(const float2*)(hs + (size_t)sd_*128 + lane*2);
          } else { al[i] = 0.f; v[i] = make_float2(0.f, 0.f); }
        }
        #pragma unroll
        for (int i = 0; i < 8; ++i){
          acc0 = fmaf(al[i], v[i].x, acc0);
          acc1 = fmaf(al[i], v[i].y, acc1);
        }
      }
    } else {
      float m = -1e30f;
      for (int e = lane; e < deg; e += 64){
        int sid = srcv[eids[lo+e]];
        m = fmaxf(m, lrelu(asn[sid] + ad));
      }
      #pragma unroll
      for (int o = 32; o; o >>= 1) m = fmaxf(m, __shfl_xor(m, o, 64));
      float s = 0.f;
      for (int e = lane; e < deg; e += 64){
        int sid = srcv[eids[lo+e]];
        s += __expf(lrelu(asn[sid] + ad) - m);
      }
      #pragma unroll
      for (int o = 32; o; o >>= 1) s += __shfl_xor(s, o, 64);
      float inv = 1.f / (s + 1e-16f);
      for (int e = 0; e < deg; ++e){
        int sid = srcv[eids[lo+e]];
        float a = __expf(lrelu(asn[sid] + ad) - m) * inv;
        float2 v = *(const float2*)(hs + (size_t)sid*128 + lane*2);
        acc0 = fmaf(a, v.x, acc0);
        acc1 = fmaf(a, v.y, acc1);
      }
    }
  }
  float2 bb = *(const float2*)(bias + lane*2);
  uint2 o;
  o.x = pack_hl(elu1(acc0 + bb.x));
  o.y = pack_hl(elu1(acc1 + bb.y));
  *(uint2*)(outp + (size_t)d*128 + lane*2) = o;
}

// ============ graph pooling (packed in, packed out) ============
__global__ __launch_bounds__(128) void pool_relu(const uint32_t* __restrict__ hp,
    const int* __restrict__ batch, uint32_t* __restrict__ pooledp, int Nn)
{
  const int g = blockIdx.x;
  const int c = threadIdx.x;
  __shared__ int sb[2];
  if (c < 2) sb[c] = lower_bound_i(batch, Nn, g + c);
  __syncthreads();
  const int lo = sb[0], hi = sb[1];
  float s = 0.f;
  for (int i = lo; i < hi; ++i) s += unpack_hl(hp[(size_t)i*128 + c]);
  pooledp[(size_t)g*128 + c] = pack_hl(fmaxf(s, 0.f));
}

// ============ molecular GAT aggregate + final linear (fused) ============
__global__ __launch_bounds__(128) void mol_agg(const float* __restrict__ as2,
    const float* __restrict__ ad2, const float* __restrict__ hs2,
    const int* __restrict__ batch, const float* __restrict__ bias,
    const float* __restrict__ W2, const float* __restrict__ b2,
    float* __restrict__ out, int Nn)
{
  const int g = blockIdx.x;
  const int c = threadIdx.x;
  __shared__ int sb[2];
  __shared__ float red[2];
  if (c < 2) sb[c] = lower_bound_i(batch, Nn, g + c);
  __syncthreads();
  const int lo = sb[0], hi = sb[1];
  const float ad = ad2[g];

  float mt = -1e30f;
  for (int i = lo + c; i < hi; i += 128) mt = fmaxf(mt, lrelu(as2[i] + ad));
  #pragma unroll
  for (int o = 32; o; o >>= 1) mt = fmaxf(mt, __shfl_xor(mt, o, 64));
  if ((c & 63) == 0) red[c >> 6] = mt;
  __syncthreads();
  const float m = fmaxf(red[0], red[1]);

  float st = 0.f;
  for (int i = lo + c; i < hi; i += 128) st += __expf(lrelu(as2[i] + ad) - m);
  #pragma unroll
  for (int o = 32; o; o >>= 1) st += __shfl_xor(st, o, 64);
  __syncthreads();
  if ((c & 63) == 0) red[c >> 6] = st;
  __syncthreads();
  const float inv = 1.f / (red[0] + red[1] + 1e-16f);

  float acc = 0.f;
  for (int i = lo; i < hi; ++i){
    float wgt = __expf(lrelu(as2[i] + ad) - m) * inv;
    acc = fmaf(wgt, hs2[(size_t)i*128 + c], acc);
  }
  float v = elu1(acc + bias[c]);

  float r = v * W2[c];
  #pragma unroll
  for (int o = 32; o; o >>= 1) r += __shfl_xor(r, o, 64);
  __syncthreads();
  if ((c & 63) == 0) red[c >> 6] = r;
  __syncthreads();
  if (c == 0) out[g] = red[0] + red[1] + b2[0];
}

extern "C" void kernel_launch(void* const* d_in, const int* in_sizes, int n_in,
                              void* d_out, int out_size, void* d_ws, size_t ws_size,
                              hipStream_t stream)
{
  const float* x      = (const float*)d_in[0];
  const int*   ei     = (const int*)  d_in[1];
  const int*   batch  = (const int*)  d_in[2];
  const float* W1     = (const float*)d_in[3];
  const float* b1     = (const float*)d_in[4];
  const float* gW     = (const float*)d_in[5];
  const float* g_asrc = (const float*)d_in[6];
  const float* g_adst = (const float*)d_in[7];
  const float* g_b    = (const float*)d_in[8];
  const float* mW     = (const float*)d_in[9];
  const float* m_asrc = (const float*)d_in[10];
  const float* m_adst = (const float*)d_in[11];
  const float* m_b    = (const float*)d_in[12];
  const float* W2     = (const float*)d_in[13];
  const float* b2     = (const float*)d_in[14];

  const int Nn = in_sizes[0] / 64;            // 100000
  const int E  = in_sizes[1] / 2;             // 400000
  const int G  = out_size;                    // 5000
  const int NL = in_sizes[5] / (128*128);     // 3
  const int* srcv = ei;
  const int* dstv = ei + E;

  char* w = (char*)d_ws;
  uint32_t* hPk   = (uint32_t*)w; w += (size_t)Nn*128*4;
  float*    hs    = (float*)w;    w += (size_t)Nn*128*4;   // xPk aliases its head
  uint32_t* xPk   = (uint32_t*)hs;
  uint32_t* poolP = (uint32_t*)w; w += (size_t)G*128*4;
  float* asN      = (float*)w; w += (size_t)Nn*4;
  float* adN      = (float*)w; w += (size_t)Nn*4;
  int*   deg      = (int*)w;   w += (size_t)Nn*4;
  int*   rp       = (int*)w;   w += (size_t)(Nn+64)*4;
  int*   cur      = (int*)w;   w += (size_t)Nn*4;
  int*   eids     = (int*)w;   w += (size_t)E*4;
  int*   bsum     = (int*)w;   w += 4096;
  unsigned short* w1h = (unsigned short*)w; w += 64*128*2;
  unsigned short* w1l = (unsigned short*)w; w += 64*128*2;
  unsigned short* gwh = (unsigned short*)w; w += (size_t)NL*128*128*2;
  unsigned short* gwl = (unsigned short*)w; w += (size_t)NL*128*128*2;
  unsigned short* mwh = (unsigned short*)w; w += 128*128*2;
  unsigned short* mwl = (unsigned short*)w; w += 128*128*2;

  const int nscan = (Nn + 255)/256;
  const int nrt = (Nn + 127)/128;   // gemm row-tiles
  const int grt = (G + 127)/128;

  // ---- CSR build ----
  hipMemsetAsync(deg, 0, (size_t)Nn*4, stream);
  hist_k<<<(E+255)/256, 256, 0, stream>>>(dstv, deg, E);
  scan_sum<<<nscan, 256, 0, stream>>>(deg, bsum, Nn);
  scan_blocksums<<<1, 512, 0, stream>>>(bsum, nscan);
  scan_final<<<nscan, 256, 0, stream>>>(deg, bsum, rp, cur, Nn, E);
  scatter_k<<<(E+255)/256, 256, 0, stream>>>(dstv, cur, eids, E);

  // ---- prep: x and weights to bf16 hi/lo ----
  xprep<<<((Nn*64/4)+255)/256, 256, 0, stream>>>(x, xPk, Nn*64/4);
  wprep<<<((64*128)+255)/256, 256, 0, stream>>>(W1, w1h, w1l, 64, 64*128);
  wprep<<<((NL*128*128)+255)/256, 256, 0, stream>>>(gW, gwh, gwl, 128, NL*128*128);
  wprep<<<((128*128)+255)/256, 256, 0, stream>>>(mW, mwh, mwl, 128, 128*128);

  // ---- lin1 + leaky_relu -> packed h ----
  gemm_mfma<2, true, true, false, false, false><<<nrt, 256, 0, stream>>>(
      xPk, w1h, w1l, b1, nullptr, nullptr, nullptr, hPk, nullptr, nullptr, Nn);

  // ---- 3 GAT layers ----
  for (int l = 0; l < NL; ++l){
    gemm_mfma<4, false, false, true, true, true><<<nrt, 256, 0, stream>>>(
        hPk, gwh + (size_t)l*128*128, gwl + (size_t)l*128*128, nullptr,
        g_asrc + l*128, g_adst + l*128, hs, nullptr, asN, adN, Nn);
    gat_agg<<<(Nn+3)/4, 256, 0, stream>>>(srcv, eids, rp, asN, adN, hs, g_b + l*128, hPk, Nn);
  }

  // ---- readout ----
  pool_relu<<<G, 128, 0, stream>>>(hPk, batch, poolP, Nn);
  gemm_mfma<4, false, false, true, true, false><<<nrt, 256, 0, stream>>>(
      hPk, mwh, mwl, nullptr, m_asrc, nullptr, hs, nullptr, asN, nullptr, Nn);   // hs2 + as2
  gemm_mfma<4, false, false, false, true, false><<<grt, 256, 0, stream>>>(
      poolP, mwh, mwl, nullptr, m_adst, nullptr, nullptr, nullptr, adN, nullptr, G); // ad2
  mol_agg<<<G, 128, 0, stream>>>(asN, adN, hs, batch, m_b, W2, b2, (float*)d_out, Nn);
}

// Round 4
// 539.746 us; speedup vs baseline: 1.0432x; 1.0432x over previous
//
#include <hip/hip_runtime.h>
#include <math.h>
#include <stdint.h>

#define DEV __device__ __forceinline__

using f32x4  = __attribute__((ext_vector_type(4))) float;
using short8 = __attribute__((ext_vector_type(8))) short;

DEV float lrelu(float x){ return x > 0.f ? x : 0.01f*x; }
DEV float elu1(float x){ return x > 0.f ? x : __expf(x)-1.f; }

DEV uint32_t bf16_rne(float x){
  uint32_t b = __float_as_uint(x);
  return (b + 0x7fffu + ((b >> 16) & 1u)) >> 16;
}
// pack f32 -> (hi bf16 | lo bf16), value ~= hi + lo to ~16 mantissa bits
DEV uint32_t pack_hl(float x){
  uint32_t hi = bf16_rne(x);
  float lo = x - __uint_as_float(hi << 16);
  return (hi << 16) | bf16_rne(lo);
}
DEV float unpack_hl(uint32_t u){
  return __uint_as_float(u & 0xffff0000u) + __uint_as_float(u << 16);
}

DEV int lower_bound_i(const int* __restrict__ a, int n, int key){
  int lo = 0, hi = n;
  while (lo < hi){ int mid = (lo+hi)>>1; if (a[mid] < key) lo = mid+1; else hi = mid; }
  return lo;
}

// ============ input prep: f32 -> packed hi/lo ============
__global__ void xprep(const float* __restrict__ x, uint32_t* __restrict__ xp, int n4){
  int i = blockIdx.x*256 + threadIdx.x;
  if (i >= n4) return;
  float4 v = ((const float4*)x)[i];
  uint4 o;
  o.x = pack_hl(v.x); o.y = pack_hl(v.y); o.z = pack_hl(v.z); o.w = pack_hl(v.w);
  ((uint4*)xp)[i] = o;
}

// ============ weight prep: W[K][128] f32 -> Wt_hi/Wt_lo [128][K] bf16 ============
__global__ void wprep(const float* __restrict__ W, unsigned short* __restrict__ Hi,
                      unsigned short* __restrict__ Lo, int K, int tot){
  int idx = blockIdx.x*256 + threadIdx.x;
  if (idx >= tot) return;
  int kn = K*128;
  int mat = idx / kn;
  int rem = idx - mat*kn;
  int k = rem >> 7;
  int n = rem & 127;
  float v = W[idx];
  uint32_t hi = bf16_rne(v);
  float lo = v - __uint_as_float(hi << 16);
  size_t o = (size_t)mat*kn + (size_t)n*K + k;
  Hi[o] = (unsigned short)hi;
  Lo[o] = (unsigned short)bf16_rne(lo);
}

// ============ MFMA GEMM: C[M,128] = A[M,K] @ W[K,128], bf16x2 triple scheme ============
// Block 256 = 4 waves; block tile = 32 rows x 128 cols; wave = 32 rows x 32 cols.
// A and B fragments both streamed 2-deep (no resident panel) -> ~120 VGPR,
// 4 waves/SIMD. Epilogue bounces acc through padded LDS for float4 stores.
// mfma_f32_16x16x32_bf16 C/D: col=lane&15, row=(lane>>4)*4+reg (m89-verified).
template<int KC, bool BIAS, bool PACK_OUT, bool F32_OUT, bool DOTA, bool DOTB>
__global__ __launch_bounds__(256, 4) void gemm_mfma(
    const uint32_t* __restrict__ Apk, const unsigned short* __restrict__ Wt_hi,
    const unsigned short* __restrict__ Wt_lo, const float* __restrict__ bias,
    const float* __restrict__ va, const float* __restrict__ vb,
    float* __restrict__ Cf, uint32_t* __restrict__ Cp,
    float* __restrict__ outa, float* __restrict__ outb, int M)
{
  constexpr int K = KC*32;
  const int tid = threadIdx.x;
  const int lane = tid & 63;
  const int wv = tid >> 6;
  const int ml = lane & 15;
  const int kg = lane >> 4;
  const int R0 = blockIdx.x * 32;

  __shared__ float sC[4][32][36];    // padded: conflict-free b128 readback
  __shared__ float sd[4][32][2];

  const unsigned short* bhp[2];
  const unsigned short* blp[2];
  #pragma unroll
  for (int nt = 0; nt < 2; ++nt){
    int n = wv*32 + nt*16 + ml;
    bhp[nt] = Wt_hi + (size_t)n*K + kg*8;
    blp[nt] = Wt_lo + (size_t)n*K + kg*8;
  }
  const uint32_t* arow[2];
  #pragma unroll
  for (int mt = 0; mt < 2; ++mt){
    int r = R0 + mt*16 + ml; r = r < M ? r : M-1;
    arow[mt] = Apk + (size_t)r*K + kg*8;
  }

  f32x4 acc[2][2];
  #pragma unroll
  for (int mt = 0; mt < 2; ++mt)
    #pragma unroll
    for (int nt = 0; nt < 2; ++nt)
      acc[mt][nt] = (f32x4){0.f,0.f,0.f,0.f};

  uint4 aC[2][2]; short8 bhC[2], blC[2];
  #pragma unroll
  for (int mt = 0; mt < 2; ++mt){
    aC[mt][0] = *(const uint4*)(arow[mt]);
    aC[mt][1] = *(const uint4*)(arow[mt] + 4);
  }
  #pragma unroll
  for (int nt = 0; nt < 2; ++nt){
    bhC[nt] = *(const short8*)(bhp[nt]);
    blC[nt] = *(const short8*)(blp[nt]);
  }

  #pragma unroll
  for (int kc = 0; kc < KC; ++kc){
    uint4 aN[2][2]; short8 bhN[2], blN[2];
    if (kc + 1 < KC){
      #pragma unroll
      for (int mt = 0; mt < 2; ++mt){
        aN[mt][0] = *(const uint4*)(arow[mt] + (kc+1)*32);
        aN[mt][1] = *(const uint4*)(arow[mt] + (kc+1)*32 + 4);
      }
      #pragma unroll
      for (int nt = 0; nt < 2; ++nt){
        bhN[nt] = *(const short8*)(bhp[nt] + (kc+1)*32);
        blN[nt] = *(const short8*)(blp[nt] + (kc+1)*32);
      }
    }
    #pragma unroll
    for (int mt = 0; mt < 2; ++mt){
      union { uint32_t u[4]; short8 s; } H, L;
      H.u[0] = __builtin_amdgcn_perm(aC[mt][0].y, aC[mt][0].x, 0x07060302u);
      H.u[1] = __builtin_amdgcn_perm(aC[mt][0].w, aC[mt][0].z, 0x07060302u);
      H.u[2] = __builtin_amdgcn_perm(aC[mt][1].y, aC[mt][1].x, 0x07060302u);
      H.u[3] = __builtin_amdgcn_perm(aC[mt][1].w, aC[mt][1].z, 0x07060302u);
      L.u[0] = __builtin_amdgcn_perm(aC[mt][0].y, aC[mt][0].x, 0x05040100u);
      L.u[1] = __builtin_amdgcn_perm(aC[mt][0].w, aC[mt][0].z, 0x05040100u);
      L.u[2] = __builtin_amdgcn_perm(aC[mt][1].y, aC[mt][1].x, 0x05040100u);
      L.u[3] = __builtin_amdgcn_perm(aC[mt][1].w, aC[mt][1].z, 0x05040100u);
      #pragma unroll
      for (int nt = 0; nt < 2; ++nt){
        acc[mt][nt] = __builtin_amdgcn_mfma_f32_16x16x32_bf16(H.s, bhC[nt], acc[mt][nt], 0, 0, 0);
        acc[mt][nt] = __builtin_amdgcn_mfma_f32_16x16x32_bf16(H.s, blC[nt], acc[mt][nt], 0, 0, 0);
        acc[mt][nt] = __builtin_amdgcn_mfma_f32_16x16x32_bf16(L.s, bhC[nt], acc[mt][nt], 0, 0, 0);
      }
    }
    if (kc + 1 < KC){
      #pragma unroll
      for (int mt = 0; mt < 2; ++mt){ aC[mt][0] = aN[mt][0]; aC[mt][1] = aN[mt][1]; }
      #pragma unroll
      for (int nt = 0; nt < 2; ++nt){ bhC[nt] = bhN[nt]; blC[nt] = blN[nt]; }
    }
  }

  // ---- fused attention dots (from regs, cross-wave LDS reduce) ----
  if constexpr (DOTA || DOTB){
    float vaL[2] = {0.f,0.f}, vbL[2] = {0.f,0.f};
    if constexpr (DOTA){ vaL[0] = va[wv*32 + ml]; vaL[1] = va[wv*32 + 16 + ml]; }
    if constexpr (DOTB){ vbL[0] = vb[wv*32 + ml]; vbL[1] = vb[wv*32 + 16 + ml]; }
    #pragma unroll
    for (int mt = 0; mt < 2; ++mt){
      #pragma unroll
      for (int r = 0; r < 4; ++r){
        float pa = 0.f, pb = 0.f;
        #pragma unroll
        for (int nt = 0; nt < 2; ++nt){
          float v = acc[mt][nt][r];
          if constexpr (DOTA) pa = fmaf(v, vaL[nt], pa);
          if constexpr (DOTB) pb = fmaf(v, vbL[nt], pb);
        }
        #pragma unroll
        for (int o = 8; o; o >>= 1){
          if constexpr (DOTA) pa += __shfl_xor(pa, o, 64);
          if constexpr (DOTB) pb += __shfl_xor(pb, o, 64);
        }
        if (ml == 0){
          int rl = mt*16 + kg*4 + r;
          sd[wv][rl][0] = pa;
          sd[wv][rl][1] = pb;
        }
      }
    }
    __syncthreads();
    if (tid < 32){
      int row = R0 + tid;
      if (row < M){
        if constexpr (DOTA)
          outa[row] = sd[0][tid][0] + sd[1][tid][0] + sd[2][tid][0] + sd[3][tid][0];
        if constexpr (DOTB)
          outb[row] = sd[0][tid][1] + sd[1][tid][1] + sd[2][tid][1] + sd[3][tid][1];
      }
    }
  }

  // ---- C store via LDS bounce (coalesced float4/uint4) ----
  float bv[2];
  if constexpr (BIAS){
    bv[0] = bias[wv*32 + ml];
    bv[1] = bias[wv*32 + 16 + ml];
  }
  #pragma unroll
  for (int mt = 0; mt < 2; ++mt){
    #pragma unroll
    for (int nt = 0; nt < 2; ++nt){
      #pragma unroll
      for (int r = 0; r < 4; ++r){
        float v = acc[mt][nt][r];
        if constexpr (BIAS) v = lrelu(v + bv[nt]);
        sC[wv][mt*16 + kg*4 + r][nt*16 + ml] = v;
      }
    }
  }
  __syncthreads();
  #pragma unroll
  for (int p = 0; p < 4; ++p){
    int c = p*64 + lane;
    int row = c >> 3;
    int c4 = (c & 7) * 4;
    int grow = R0 + row;
    if (grow < M){
      float4 v = *(const float4*)&sC[wv][row][c4];
      int gcol = wv*32 + c4;
      if constexpr (F32_OUT)
        *(float4*)(Cf + (size_t)grow*128 + gcol) = v;
      if constexpr (PACK_OUT){
        uint4 o;
        o.x = pack_hl(v.x); o.y = pack_hl(v.y); o.z = pack_hl(v.z); o.w = pack_hl(v.w);
        *(uint4*)(Cp + (size_t)grow*128 + gcol) = o;
      }
    }
  }
}

// ============ CSR build ============
__global__ void hist_k(const int* __restrict__ dstv, int* __restrict__ deg, int E){
  int e = blockIdx.x*256 + threadIdx.x;
  if (e < E) atomicAdd(&deg[dstv[e]], 1);
}

__global__ void scan_sum(const int* __restrict__ deg, int* __restrict__ bsum, int n){
  __shared__ int s4[4];
  int i = blockIdx.x*256 + threadIdx.x;
  int v = (i < n) ? deg[i] : 0;
  #pragma unroll
  for (int o = 32; o; o >>= 1) v += __shfl_down(v, o, 64);
  if ((threadIdx.x & 63) == 0) s4[threadIdx.x >> 6] = v;
  __syncthreads();
  if (threadIdx.x == 0) bsum[blockIdx.x] = s4[0]+s4[1]+s4[2]+s4[3];
}

__global__ void scan_blocksums(int* __restrict__ bsum, int nb){
  __shared__ int s[512];
  int t = threadIdx.x;
  s[t] = (t < nb) ? bsum[t] : 0;
  __syncthreads();
  for (int o = 1; o < 512; o <<= 1){
    int v = s[t];
    int u = (t >= o) ? s[t-o] : 0;
    __syncthreads();
    s[t] = v + u;
    __syncthreads();
  }
  if (t < nb) bsum[t] = t ? s[t-1] : 0;
}

__global__ void scan_final(const int* __restrict__ deg, const int* __restrict__ boff,
    int* __restrict__ rp, int* __restrict__ cur, int n, int E)
{
  __shared__ int wsum[4];
  int i = blockIdx.x*256 + threadIdx.x;
  int lane = threadIdx.x & 63, wv = threadIdx.x >> 6;
  int v = (i < n) ? deg[i] : 0;
  int inc = v;
  #pragma unroll
  for (int o = 1; o < 64; o <<= 1){
    int u = __shfl_up(inc, o, 64);
    if (lane >= o) inc += u;
  }
  if (lane == 63) wsum[wv] = inc;
  __syncthreads();
  int woff = boff[blockIdx.x];
  for (int wq = 0; wq < wv; ++wq) woff += wsum[wq];
  int excl = woff + inc - v;
  if (i < n){ rp[i] = excl; cur[i] = excl; }
  if (blockIdx.x == 0 && threadIdx.x == 0) rp[n] = E;
}

__global__ void scatter_k(const int* __restrict__ dstv, int* __restrict__ cur,
                          int* __restrict__ eids, int E){
  int e = blockIdx.x*256 + threadIdx.x;
  if (e < E){
    int p = atomicAdd(&cur[dstv[e]], 1);
    eids[p] = e;
  }
}

// ============ fused segment softmax + aggregation (one wave per dst node) ============
__global__ __launch_bounds__(256) void gat_agg(const int* __restrict__ srcv,
    const int* __restrict__ eids, const int* __restrict__ rp,
    const float* __restrict__ asn, const float* __restrict__ adn,
    const float* __restrict__ hs, const float* __restrict__ bias,
    uint32_t* __restrict__ outp, int Nn)
{
  const int lane = threadIdx.x & 63;
  const int wv = threadIdx.x >> 6;
  const int d = blockIdx.x*4 + wv;
  if (d >= Nn) return;
  const int lo = rp[d], hi = rp[d+1];
  const int deg = hi - lo;
  float acc0 = 0.f, acc1 = 0.f;
  if (deg > 0){
    const float ad = adn[d];
    if (deg <= 64){
      int sid = 0; float lg = -1e30f;
      if (lane < deg){
        int eid = eids[lo + lane];
        sid = srcv[eid];
        lg = lrelu(asn[sid] + ad);
      }
      float m = lg;
      #pragma unroll
      for (int o = 32; o; o >>= 1) m = fmaxf(m, __shfl_xor(m, o, 64));
      float p = (lane < deg) ? __expf(lg - m) : 0.f;
      float s = p;
      #pragma unroll
      for (int o = 32; o; o >>= 1) s += __shfl_xor(s, o, 64);
      float alpha = p * (1.f / (s + 1e-16f));
      for (int base = 0; base < deg; base += 8){
        int nb = deg - base; nb = nb > 8 ? 8 : nb;
        float2 v[8]; float al[8];
        #pragma unroll
        for (int i = 0; i < 8; ++i){
          if (i < nb){
            int sd_ = __shfl(sid, base + i, 64);
            al[i] = __shfl(alpha, base + i, 64);
            v[i] = *(const float2*)(hs + (size_t)sd_*128 + lane*2);
          } else { al[i] = 0.f; v[i] = make_float2(0.f, 0.f); }
        }
        #pragma unroll
        for (int i = 0; i < 8; ++i){
          acc0 = fmaf(al[i], v[i].x, acc0);
          acc1 = fmaf(al[i], v[i].y, acc1);
        }
      }
    } else {
      float m = -1e30f;
      for (int e = lane; e < deg; e += 64){
        int sid = srcv[eids[lo+e]];
        m = fmaxf(m, lrelu(asn[sid] + ad));
      }
      #pragma unroll
      for (int o = 32; o; o >>= 1) m = fmaxf(m, __shfl_xor(m, o, 64));
      float s = 0.f;
      for (int e = lane; e < deg; e += 64){
        int sid = srcv[eids[lo+e]];
        s += __expf(lrelu(asn[sid] + ad) - m);
      }
      #pragma unroll
      for (int o = 32; o; o >>= 1) s += __shfl_xor(s, o, 64);
      float inv = 1.f / (s + 1e-16f);
      for (int e = 0; e < deg; ++e){
        int sid = srcv[eids[lo+e]];
        float a = __expf(lrelu(asn[sid] + ad) - m) * inv;
        float2 v = *(const float2*)(hs + (size_t)sid*128 + lane*2);
        acc0 = fmaf(a, v.x, acc0);
        acc1 = fmaf(a, v.y, acc1);
      }
    }
  }
  float2 bb = *(const float2*)(bias + lane*2);
  uint2 o;
  o.x = pack_hl(elu1(acc0 + bb.x));
  o.y = pack_hl(elu1(acc1 + bb.y));
  *(uint2*)(outp + (size_t)d*128 + lane*2) = o;
}

// ============ graph pooling (packed in, packed out) ============
__global__ __launch_bounds__(128) void pool_relu(const uint32_t* __restrict__ hp,
    const int* __restrict__ batch, uint32_t* __restrict__ pooledp, int Nn)
{
  const int g = blockIdx.x;
  const int c = threadIdx.x;
  __shared__ int sb[2];
  if (c < 2) sb[c] = lower_bound_i(batch, Nn, g + c);
  __syncthreads();
  const int lo = sb[0], hi = sb[1];
  float s = 0.f;
  for (int i = lo; i < hi; ++i) s += unpack_hl(hp[(size_t)i*128 + c]);
  pooledp[(size_t)g*128 + c] = pack_hl(fmaxf(s, 0.f));
}

// ============ molecular GAT aggregate + final linear (fused) ============
__global__ __launch_bounds__(128) void mol_agg(const float* __restrict__ as2,
    const float* __restrict__ ad2, const float* __restrict__ hs2,
    const int* __restrict__ batch, const float* __restrict__ bias,
    const float* __restrict__ W2, const float* __restrict__ b2,
    float* __restrict__ out, int Nn)
{
  const int g = blockIdx.x;
  const int c = threadIdx.x;
  __shared__ int sb[2];
  __shared__ float red[2];
  if (c < 2) sb[c] = lower_bound_i(batch, Nn, g + c);
  __syncthreads();
  const int lo = sb[0], hi = sb[1];
  const float ad = ad2[g];

  float mt = -1e30f;
  for (int i = lo + c; i < hi; i += 128) mt = fmaxf(mt, lrelu(as2[i] + ad));
  #pragma unroll
  for (int o = 32; o; o >>= 1) mt = fmaxf(mt, __shfl_xor(mt, o, 64));
  if ((c & 63) == 0) red[c >> 6] = mt;
  __syncthreads();
  const float m = fmaxf(red[0], red[1]);

  float st = 0.f;
  for (int i = lo + c; i < hi; i += 128) st += __expf(lrelu(as2[i] + ad) - m);
  #pragma unroll
  for (int o = 32; o; o >>= 1) st += __shfl_xor(st, o, 64);
  __syncthreads();
  if ((c & 63) == 0) red[c >> 6] = st;
  __syncthreads();
  const float inv = 1.f / (red[0] + red[1] + 1e-16f);

  float acc = 0.f;
  for (int i = lo; i < hi; ++i){
    float wgt = __expf(lrelu(as2[i] + ad) - m) * inv;
    acc = fmaf(wgt, hs2[(size_t)i*128 + c], acc);
  }
  float v = elu1(acc + bias[c]);

  float r = v * W2[c];
  #pragma unroll
  for (int o = 32; o; o >>= 1) r += __shfl_xor(r, o, 64);
  __syncthreads();
  if ((c & 63) == 0) red[c >> 6] = r;
  __syncthreads();
  if (c == 0) out[g] = red[0] + red[1] + b2[0];
}

extern "C" void kernel_launch(void* const* d_in, const int* in_sizes, int n_in,
                              void* d_out, int out_size, void* d_ws, size_t ws_size,
                              hipStream_t stream)
{
  const float* x      = (const float*)d_in[0];
  const int*   ei     = (const int*)  d_in[1];
  const int*   batch  = (const int*)  d_in[2];
  const float* W1     = (const float*)d_in[3];
  const float* b1     = (const float*)d_in[4];
  const float* gW     = (const float*)d_in[5];
  const float* g_asrc = (const float*)d_in[6];
  const float* g_adst = (const float*)d_in[7];
  const float* g_b    = (const float*)d_in[8];
  const float* mW     = (const float*)d_in[9];
  const float* m_asrc = (const float*)d_in[10];
  const float* m_adst = (const float*)d_in[11];
  const float* m_b    = (const float*)d_in[12];
  const float* W2     = (const float*)d_in[13];
  const float* b2     = (const float*)d_in[14];

  const int Nn = in_sizes[0] / 64;            // 100000
  const int E  = in_sizes[1] / 2;             // 400000
  const int G  = out_size;                    // 5000
  const int NL = in_sizes[5] / (128*128);     // 3
  const int* srcv = ei;
  const int* dstv = ei + E;

  char* w = (char*)d_ws;
  uint32_t* hPk   = (uint32_t*)w; w += (size_t)Nn*128*4;
  float*    hs    = (float*)w;    w += (size_t)Nn*128*4;   // xPk aliases its head
  uint32_t* xPk   = (uint32_t*)hs;
  uint32_t* poolP = (uint32_t*)w; w += (size_t)G*128*4;
  float* asN      = (float*)w; w += (size_t)Nn*4;
  float* adN      = (float*)w; w += (size_t)Nn*4;
  int*   deg      = (int*)w;   w += (size_t)Nn*4;
  int*   rp       = (int*)w;   w += (size_t)(Nn+64)*4;
  int*   cur      = (int*)w;   w += (size_t)Nn*4;
  int*   eids     = (int*)w;   w += (size_t)E*4;
  int*   bsum     = (int*)w;   w += 4096;
  unsigned short* w1h = (unsigned short*)w; w += 64*128*2;
  unsigned short* w1l = (unsigned short*)w; w += 64*128*2;
  unsigned short* gwh = (unsigned short*)w; w += (size_t)NL*128*128*2;
  unsigned short* gwl = (unsigned short*)w; w += (size_t)NL*128*128*2;
  unsigned short* mwh = (unsigned short*)w; w += 128*128*2;
  unsigned short* mwl = (unsigned short*)w; w += 128*128*2;

  const int nscan = (Nn + 255)/256;
  const int nrt = (Nn + 31)/32;    // gemm row-tiles (32 rows/block)
  const int grt = (G + 31)/32;

  // ---- CSR build ----
  hipMemsetAsync(deg, 0, (size_t)Nn*4, stream);
  hist_k<<<(E+255)/256, 256, 0, stream>>>(dstv, deg, E);
  scan_sum<<<nscan, 256, 0, stream>>>(deg, bsum, Nn);
  scan_blocksums<<<1, 512, 0, stream>>>(bsum, nscan);
  scan_final<<<nscan, 256, 0, stream>>>(deg, bsum, rp, cur, Nn, E);
  scatter_k<<<(E+255)/256, 256, 0, stream>>>(dstv, cur, eids, E);

  // ---- prep: x and weights to bf16 hi/lo ----
  xprep<<<((Nn*64/4)+255)/256, 256, 0, stream>>>(x, xPk, Nn*64/4);
  wprep<<<((64*128)+255)/256, 256, 0, stream>>>(W1, w1h, w1l, 64, 64*128);
  wprep<<<((NL*128*128)+255)/256, 256, 0, stream>>>(gW, gwh, gwl, 128, NL*128*128);
  wprep<<<((128*128)+255)/256, 256, 0, stream>>>(mW, mwh, mwl, 128, 128*128);

  // ---- lin1 + leaky_relu -> packed h ----
  gemm_mfma<2, true, true, false, false, false><<<nrt, 256, 0, stream>>>(
      xPk, w1h, w1l, b1, nullptr, nullptr, nullptr, hPk, nullptr, nullptr, Nn);

  // ---- 3 GAT layers ----
  for (int l = 0; l < NL; ++l){
    gemm_mfma<4, false, false, true, true, true><<<nrt, 256, 0, stream>>>(
        hPk, gwh + (size_t)l*128*128, gwl + (size_t)l*128*128, nullptr,
        g_asrc + l*128, g_adst + l*128, hs, nullptr, asN, adN, Nn);
    gat_agg<<<(Nn+3)/4, 256, 0, stream>>>(srcv, eids, rp, asN, adN, hs, g_b + l*128, hPk, Nn);
  }

  // ---- readout ----
  pool_relu<<<G, 128, 0, stream>>>(hPk, batch, poolP, Nn);
  gemm_mfma<4, false, false, true, true, false><<<nrt, 256, 0, stream>>>(
      hPk, mwh, mwl, nullptr, m_asrc, nullptr, hs, nullptr, asN, nullptr, Nn);   // hs2 + as2
  gemm_mfma<4, false, false, false, true, false><<<grt, 256, 0, stream>>>(
      poolP, mwh, mwl, nullptr, m_adst, nullptr, nullptr, nullptr, adN, nullptr, G); // ad2
  mol_agg<<<G, 128, 0, stream>>>(asN, adN, hs, batch, m_b, W2, b2, (float*)d_out, Nn);
}

// Round 5
// 471.019 us; speedup vs baseline: 1.1954x; 1.1459x over previous
//
#include <hip/hip_runtime.h>
#include <hip/hip_fp16.h>
#include <math.h>
#include <stdint.h>

#define DEV __device__ __forceinline__

using f32x4  = __attribute__((ext_vector_type(4))) float;
using short8 = __attribute__((ext_vector_type(8))) short;

DEV float lrelu(float x){ return x > 0.f ? x : 0.01f*x; }
DEV float elu1(float x){ return x > 0.f ? x : __expf(x)-1.f; }

DEV uint32_t bf16_rne(float x){
  uint32_t b = __float_as_uint(x);
  return (b + 0x7fffu + ((b >> 16) & 1u)) >> 16;
}
// pack f32 -> (hi bf16 | lo bf16), value ~= hi + lo to ~16 mantissa bits
DEV uint32_t pack_hl(float x){
  uint32_t hi = bf16_rne(x);
  float lo = x - __uint_as_float(hi << 16);
  return (hi << 16) | bf16_rne(lo);
}
DEV float unpack_hl(uint32_t u){
  return __uint_as_float(u & 0xffff0000u) + __uint_as_float(u << 16);
}

DEV int lower_bound_i(const int* __restrict__ a, int n, int key){
  int lo = 0, hi = n;
  while (lo < hi){ int mid = (lo+hi)>>1; if (a[mid] < key) lo = mid+1; else hi = mid; }
  return lo;
}

// ============ input prep: f32 -> packed hi/lo ============
__global__ void xprep(const float* __restrict__ x, uint32_t* __restrict__ xp, int n4){
  int i = blockIdx.x*256 + threadIdx.x;
  if (i >= n4) return;
  float4 v = ((const float4*)x)[i];
  uint4 o;
  o.x = pack_hl(v.x); o.y = pack_hl(v.y); o.z = pack_hl(v.z); o.w = pack_hl(v.w);
  ((uint4*)xp)[i] = o;
}

// ============ weight prep: W[K][128] f32 -> Wt_hi/Wt_lo [128][K] bf16 ============
__global__ void wprep(const float* __restrict__ W, unsigned short* __restrict__ Hi,
                      unsigned short* __restrict__ Lo, int K, int tot){
  int idx = blockIdx.x*256 + threadIdx.x;
  if (idx >= tot) return;
  int kn = K*128;
  int mat = idx / kn;
  int rem = idx - mat*kn;
  int k = rem >> 7;
  int n = rem & 127;
  float v = W[idx];
  uint32_t hi = bf16_rne(v);
  float lo = v - __uint_as_float(hi << 16);
  size_t o = (size_t)mat*kn + (size_t)n*K + k;
  Hi[o] = (unsigned short)hi;
  Lo[o] = (unsigned short)bf16_rne(lo);
}

// ============ MFMA GEMM: C[M,128] = A[M,K] @ W[K,128], bf16x2 triple scheme ============
// Block 256 = 4 waves; block tile = 64 rows x 128 cols; wave = 64 rows x 32 cols.
// A/B fragments streamed 2-deep. Epilogue bounces acc through padded LDS.
// OUTMODE: 0 = none (dots only), 1 = pack_hl(lrelu(v+bias)), 2 = fp16 raw, 3 = f32 raw.
// mfma_f32_16x16x32_bf16 C/D: col=lane&15, row=(lane>>4)*4+reg (m89-verified).
template<int KC, int OUTMODE, bool DOTA, bool DOTB>
__global__ __launch_bounds__(256, 3) void gemm_mfma(
    const uint32_t* __restrict__ Apk, const unsigned short* __restrict__ Wt_hi,
    const unsigned short* __restrict__ Wt_lo, const float* __restrict__ bias,
    const float* __restrict__ va, const float* __restrict__ vb,
    float* __restrict__ Cf, __half2* __restrict__ Ch, uint32_t* __restrict__ Cp,
    float* __restrict__ outa, float* __restrict__ outb, int M)
{
  constexpr int K = KC*32;
  const int tid = threadIdx.x;
  const int lane = tid & 63;
  const int wv = tid >> 6;
  const int ml = lane & 15;
  const int kg = lane >> 4;
  const int R0 = blockIdx.x * 64;

  __shared__ float sC[4][64][36];
  __shared__ float sd[4][64][2];

  const unsigned short* bhp[2];
  const unsigned short* blp[2];
  #pragma unroll
  for (int nt = 0; nt < 2; ++nt){
    int n = wv*32 + nt*16 + ml;
    bhp[nt] = Wt_hi + (size_t)n*K + kg*8;
    blp[nt] = Wt_lo + (size_t)n*K + kg*8;
  }
  const uint32_t* arow[4];
  #pragma unroll
  for (int mt = 0; mt < 4; ++mt){
    int r = R0 + mt*16 + ml; r = r < M ? r : M-1;
    arow[mt] = Apk + (size_t)r*K + kg*8;
  }

  f32x4 acc[4][2];
  #pragma unroll
  for (int mt = 0; mt < 4; ++mt)
    #pragma unroll
    for (int nt = 0; nt < 2; ++nt)
      acc[mt][nt] = (f32x4){0.f,0.f,0.f,0.f};

  uint4 aC[4][2]; short8 bhC[2], blC[2];
  #pragma unroll
  for (int mt = 0; mt < 4; ++mt){
    aC[mt][0] = *(const uint4*)(arow[mt]);
    aC[mt][1] = *(const uint4*)(arow[mt] + 4);
  }
  #pragma unroll
  for (int nt = 0; nt < 2; ++nt){
    bhC[nt] = *(const short8*)(bhp[nt]);
    blC[nt] = *(const short8*)(blp[nt]);
  }

  #pragma unroll
  for (int kc = 0; kc < KC; ++kc){
    uint4 aN[4][2]; short8 bhN[2], blN[2];
    if (kc + 1 < KC){
      #pragma unroll
      for (int mt = 0; mt < 4; ++mt){
        aN[mt][0] = *(const uint4*)(arow[mt] + (kc+1)*32);
        aN[mt][1] = *(const uint4*)(arow[mt] + (kc+1)*32 + 4);
      }
      #pragma unroll
      for (int nt = 0; nt < 2; ++nt){
        bhN[nt] = *(const short8*)(bhp[nt] + (kc+1)*32);
        blN[nt] = *(const short8*)(blp[nt] + (kc+1)*32);
      }
    }
    #pragma unroll
    for (int mt = 0; mt < 4; ++mt){
      union { uint32_t u[4]; short8 s; } H, L;
      H.u[0] = __builtin_amdgcn_perm(aC[mt][0].y, aC[mt][0].x, 0x07060302u);
      H.u[1] = __builtin_amdgcn_perm(aC[mt][0].w, aC[mt][0].z, 0x07060302u);
      H.u[2] = __builtin_amdgcn_perm(aC[mt][1].y, aC[mt][1].x, 0x07060302u);
      H.u[3] = __builtin_amdgcn_perm(aC[mt][1].w, aC[mt][1].z, 0x07060302u);
      L.u[0] = __builtin_amdgcn_perm(aC[mt][0].y, aC[mt][0].x, 0x05040100u);
      L.u[1] = __builtin_amdgcn_perm(aC[mt][0].w, aC[mt][0].z, 0x05040100u);
      L.u[2] = __builtin_amdgcn_perm(aC[mt][1].y, aC[mt][1].x, 0x05040100u);
      L.u[3] = __builtin_amdgcn_perm(aC[mt][1].w, aC[mt][1].z, 0x05040100u);
      #pragma unroll
      for (int nt = 0; nt < 2; ++nt){
        acc[mt][nt] = __builtin_amdgcn_mfma_f32_16x16x32_bf16(H.s, bhC[nt], acc[mt][nt], 0, 0, 0);
        acc[mt][nt] = __builtin_amdgcn_mfma_f32_16x16x32_bf16(H.s, blC[nt], acc[mt][nt], 0, 0, 0);
        acc[mt][nt] = __builtin_amdgcn_mfma_f32_16x16x32_bf16(L.s, bhC[nt], acc[mt][nt], 0, 0, 0);
      }
    }
    if (kc + 1 < KC){
      #pragma unroll
      for (int mt = 0; mt < 4; ++mt){ aC[mt][0] = aN[mt][0]; aC[mt][1] = aN[mt][1]; }
      #pragma unroll
      for (int nt = 0; nt < 2; ++nt){ bhC[nt] = bhN[nt]; blC[nt] = blN[nt]; }
    }
  }

  // ---- fused attention dots (raw acc = hs), cross-wave LDS reduce ----
  if constexpr (DOTA || DOTB){
    float vaL[2] = {0.f,0.f}, vbL[2] = {0.f,0.f};
    if constexpr (DOTA){ vaL[0] = va[wv*32 + ml]; vaL[1] = va[wv*32 + 16 + ml]; }
    if constexpr (DOTB){ vbL[0] = vb[wv*32 + ml]; vbL[1] = vb[wv*32 + 16 + ml]; }
    #pragma unroll
    for (int mt = 0; mt < 4; ++mt){
      #pragma unroll
      for (int r = 0; r < 4; ++r){
        float pa = 0.f, pb = 0.f;
        #pragma unroll
        for (int nt = 0; nt < 2; ++nt){
          float v = acc[mt][nt][r];
          if constexpr (DOTA) pa = fmaf(v, vaL[nt], pa);
          if constexpr (DOTB) pb = fmaf(v, vbL[nt], pb);
        }
        #pragma unroll
        for (int o = 8; o; o >>= 1){
          if constexpr (DOTA) pa += __shfl_xor(pa, o, 64);
          if constexpr (DOTB) pb += __shfl_xor(pb, o, 64);
        }
        if (ml == 0){
          int rl = mt*16 + kg*4 + r;
          sd[wv][rl][0] = pa;
          sd[wv][rl][1] = pb;
        }
      }
    }
    __syncthreads();
    if (tid < 64){
      int row = R0 + tid;
      if (row < M){
        if constexpr (DOTA)
          outa[row] = sd[0][tid][0] + sd[1][tid][0] + sd[2][tid][0] + sd[3][tid][0];
        if constexpr (DOTB)
          outb[row] = sd[0][tid][1] + sd[1][tid][1] + sd[2][tid][1] + sd[3][tid][1];
      }
    }
  }

  // ---- C store via LDS bounce ----
  if constexpr (OUTMODE != 0){
    float bv[2];
    if constexpr (OUTMODE == 1){
      bv[0] = bias[wv*32 + ml];
      bv[1] = bias[wv*32 + 16 + ml];
    }
    if constexpr (DOTA || DOTB) __syncthreads();   // sd/sC phases
    #pragma unroll
    for (int mt = 0; mt < 4; ++mt){
      #pragma unroll
      for (int nt = 0; nt < 2; ++nt){
        #pragma unroll
        for (int r = 0; r < 4; ++r){
          float v = acc[mt][nt][r];
          if constexpr (OUTMODE == 1) v = lrelu(v + bv[nt]);
          sC[wv][mt*16 + kg*4 + r][nt*16 + ml] = v;
        }
      }
    }
    __syncthreads();
    #pragma unroll
    for (int p = 0; p < 8; ++p){
      int row = p*8 + (lane >> 3);
      int c4 = (lane & 7) * 4;
      int grow = R0 + row;
      if (grow < M){
        float4 v = *(const float4*)&sC[wv][row][c4];
        int gcol = wv*32 + c4;
        if constexpr (OUTMODE == 1){
          uint4 o;
          o.x = pack_hl(v.x); o.y = pack_hl(v.y); o.z = pack_hl(v.z); o.w = pack_hl(v.w);
          *(uint4*)(Cp + (size_t)grow*128 + gcol) = o;
        }
        if constexpr (OUTMODE == 2){
          __half2 h0 = __floats2half2_rn(v.x, v.y);
          __half2 h1 = __floats2half2_rn(v.z, v.w);
          uint2 o;
          o.x = *(uint32_t*)&h0; o.y = *(uint32_t*)&h1;
          *(uint2*)(Ch + (size_t)grow*64 + (gcol >> 1)) = o;
        }
        if constexpr (OUTMODE == 3)
          *(float4*)(Cf + (size_t)grow*128 + gcol) = v;
      }
    }
  }
}

// ============ CSR build ============
__global__ void hist_k(const int* __restrict__ dstv, int* __restrict__ deg, int E){
  int e = blockIdx.x*256 + threadIdx.x;
  if (e < E) atomicAdd(&deg[dstv[e]], 1);
}

__global__ void scan_sum(const int* __restrict__ deg, int* __restrict__ bsum, int n){
  __shared__ int s4[4];
  int i = blockIdx.x*256 + threadIdx.x;
  int v = (i < n) ? deg[i] : 0;
  #pragma unroll
  for (int o = 32; o; o >>= 1) v += __shfl_down(v, o, 64);
  if ((threadIdx.x & 63) == 0) s4[threadIdx.x >> 6] = v;
  __syncthreads();
  if (threadIdx.x == 0) bsum[blockIdx.x] = s4[0]+s4[1]+s4[2]+s4[3];
}

__global__ void scan_blocksums(int* __restrict__ bsum, int nb){
  __shared__ int s[512];
  int t = threadIdx.x;
  s[t] = (t < nb) ? bsum[t] : 0;
  __syncthreads();
  for (int o = 1; o < 512; o <<= 1){
    int v = s[t];
    int u = (t >= o) ? s[t-o] : 0;
    __syncthreads();
    s[t] = v + u;
    __syncthreads();
  }
  if (t < nb) bsum[t] = t ? s[t-1] : 0;
}

__global__ void scan_final(const int* __restrict__ deg, const int* __restrict__ boff,
    int* __restrict__ rp, int* __restrict__ cur, int n, int E)
{
  __shared__ int wsum[4];
  int i = blockIdx.x*256 + threadIdx.x;
  int lane = threadIdx.x & 63, wv = threadIdx.x >> 6;
  int v = (i < n) ? deg[i] : 0;
  int inc = v;
  #pragma unroll
  for (int o = 1; o < 64; o <<= 1){
    int u = __shfl_up(inc, o, 64);
    if (lane >= o) inc += u;
  }
  if (lane == 63) wsum[wv] = inc;
  __syncthreads();
  int woff = boff[blockIdx.x];
  for (int wq = 0; wq < wv; ++wq) woff += wsum[wq];
  int excl = woff + inc - v;
  if (i < n){ rp[i] = excl; cur[i] = excl; }
  if (blockIdx.x == 0 && threadIdx.x == 0) rp[n] = E;
}

// scatter: store SOURCE node id directly (removes indirection in gat_agg)
__global__ void scatter_k(const int* __restrict__ srcv, const int* __restrict__ dstv,
                          int* __restrict__ cur, int* __restrict__ ssorted, int E){
  int e = blockIdx.x*256 + threadIdx.x;
  if (e < E){
    int p = atomicAdd(&cur[dstv[e]], 1);
    ssorted[p] = srcv[e];
  }
}

// ============ fused segment softmax + aggregation (one wave per dst node) ============
// Gathers fp16 hs rows (256 B/row); writes packed hi/lo h' for the next GEMM.
__global__ __launch_bounds__(256) void gat_agg(const int* __restrict__ ssorted,
    const int* __restrict__ rp,
    const float* __restrict__ asn, const float* __restrict__ adn,
    const __half2* __restrict__ hs16, const float* __restrict__ bias,
    uint32_t* __restrict__ outp, int Nn)
{
  const int lane = threadIdx.x & 63;
  const int wv = threadIdx.x >> 6;
  const int d = blockIdx.x*4 + wv;
  if (d >= Nn) return;
  const int lo = rp[d], hi = rp[d+1];
  const int deg = hi - lo;
  float acc0 = 0.f, acc1 = 0.f;
  if (deg > 0){
    const float ad = adn[d];
    if (deg <= 64){
      int sid = 0; float lg = -1e30f;
      if (lane < deg){
        sid = ssorted[lo + lane];
        lg = lrelu(asn[sid] + ad);
      }
      float m = lg;
      #pragma unroll
      for (int o = 32; o; o >>= 1) m = fmaxf(m, __shfl_xor(m, o, 64));
      float p = (lane < deg) ? __expf(lg - m) : 0.f;
      float s = p;
      #pragma unroll
      for (int o = 32; o; o >>= 1) s += __shfl_xor(s, o, 64);
      float alpha = p * (1.f / (s + 1e-16f));
      for (int base = 0; base < deg; base += 8){
        int nb = deg - base; nb = nb > 8 ? 8 : nb;
        __half2 v[8]; float al[8];
        #pragma unroll
        for (int i = 0; i < 8; ++i){
          if (i < nb){
            int sd_ = __shfl(sid, base + i, 64);
            al[i] = __shfl(alpha, base + i, 64);
            v[i] = hs16[(size_t)sd_*64 + lane];
          } else { al[i] = 0.f; v[i] = __half2(); }
        }
        #pragma unroll
        for (int i = 0; i < 8; ++i){
          float2 f = __half22float2(v[i]);
          acc0 = fmaf(al[i], f.x, acc0);
          acc1 = fmaf(al[i], f.y, acc1);
        }
      }
    } else {
      float m = -1e30f;
      for (int e = lane; e < deg; e += 64){
        int sid = ssorted[lo+e];
        m = fmaxf(m, lrelu(asn[sid] + ad));
      }
      #pragma unroll
      for (int o = 32; o; o >>= 1) m = fmaxf(m, __shfl_xor(m, o, 64));
      float s = 0.f;
      for (int e = lane; e < deg; e += 64){
        int sid = ssorted[lo+e];
        s += __expf(lrelu(asn[sid] + ad) - m);
      }
      #pragma unroll
      for (int o = 32; o; o >>= 1) s += __shfl_xor(s, o, 64);
      float inv = 1.f / (s + 1e-16f);
      for (int e = 0; e < deg; ++e){
        int sid = ssorted[lo+e];
        float a = __expf(lrelu(asn[sid] + ad) - m) * inv;
        float2 f = __half22float2(hs16[(size_t)sid*64 + lane]);
        acc0 = fmaf(a, f.x, acc0);
        acc1 = fmaf(a, f.y, acc1);
      }
    }
  }
  float2 bb = *(const float2*)(bias + lane*2);
  uint2 o;
  o.x = pack_hl(elu1(acc0 + bb.x));
  o.y = pack_hl(elu1(acc1 + bb.y));
  *(uint2*)(outp + (size_t)d*128 + lane*2) = o;
}

// ============ graph pooling (packed in, packed out) ============
__global__ __launch_bounds__(128) void pool_relu(const uint32_t* __restrict__ hp,
    const int* __restrict__ batch, uint32_t* __restrict__ pooledp, int Nn)
{
  const int g = blockIdx.x;
  const int c = threadIdx.x;
  __shared__ int sb[2];
  if (c < 2) sb[c] = lower_bound_i(batch, Nn, g + c);
  __syncthreads();
  const int lo = sb[0], hi = sb[1];
  float s = 0.f;
  for (int i = lo; i < hi; ++i) s += unpack_hl(hp[(size_t)i*128 + c]);
  pooledp[(size_t)g*128 + c] = pack_hl(fmaxf(s, 0.f));
}

// ============ molecular GAT aggregate + final linear (fused) ============
__global__ __launch_bounds__(128) void mol_agg(const float* __restrict__ as2,
    const float* __restrict__ ad2, const float* __restrict__ hs2,
    const int* __restrict__ batch, const float* __restrict__ bias,
    const float* __restrict__ W2, const float* __restrict__ b2,
    float* __restrict__ out, int Nn)
{
  const int g = blockIdx.x;
  const int c = threadIdx.x;
  __shared__ int sb[2];
  __shared__ float red[2];
  if (c < 2) sb[c] = lower_bound_i(batch, Nn, g + c);
  __syncthreads();
  const int lo = sb[0], hi = sb[1];
  const float ad = ad2[g];

  float mt = -1e30f;
  for (int i = lo + c; i < hi; i += 128) mt = fmaxf(mt, lrelu(as2[i] + ad));
  #pragma unroll
  for (int o = 32; o; o >>= 1) mt = fmaxf(mt, __shfl_xor(mt, o, 64));
  if ((c & 63) == 0) red[c >> 6] = mt;
  __syncthreads();
  const float m = fmaxf(red[0], red[1]);

  float st = 0.f;
  for (int i = lo + c; i < hi; i += 128) st += __expf(lrelu(as2[i] + ad) - m);
  #pragma unroll
  for (int o = 32; o; o >>= 1) st += __shfl_xor(st, o, 64);
  __syncthreads();
  if ((c & 63) == 0) red[c >> 6] = st;
  __syncthreads();
  const float inv = 1.f / (red[0] + red[1] + 1e-16f);

  float acc = 0.f;
  for (int i = lo; i < hi; ++i){
    float wgt = __expf(lrelu(as2[i] + ad) - m) * inv;
    acc = fmaf(wgt, hs2[(size_t)i*128 + c], acc);
  }
  float v = elu1(acc + bias[c]);

  float r = v * W2[c];
  #pragma unroll
  for (int o = 32; o; o >>= 1) r += __shfl_xor(r, o, 64);
  __syncthreads();
  if ((c & 63) == 0) red[c >> 6] = r;
  __syncthreads();
  if (c == 0) out[g] = red[0] + red[1] + b2[0];
}

extern "C" void kernel_launch(void* const* d_in, const int* in_sizes, int n_in,
                              void* d_out, int out_size, void* d_ws, size_t ws_size,
                              hipStream_t stream)
{
  const float* x      = (const float*)d_in[0];
  const int*   ei     = (const int*)  d_in[1];
  const int*   batch  = (const int*)  d_in[2];
  const float* W1     = (const float*)d_in[3];
  const float* b1     = (const float*)d_in[4];
  const float* gW     = (const float*)d_in[5];
  const float* g_asrc = (const float*)d_in[6];
  const float* g_adst = (const float*)d_in[7];
  const float* g_b    = (const float*)d_in[8];
  const float* mW     = (const float*)d_in[9];
  const float* m_asrc = (const float*)d_in[10];
  const float* m_adst = (const float*)d_in[11];
  const float* m_b    = (const float*)d_in[12];
  const float* W2     = (const float*)d_in[13];
  const float* b2     = (const float*)d_in[14];

  const int Nn = in_sizes[0] / 64;            // 100000
  const int E  = in_sizes[1] / 2;             // 400000
  const int G  = out_size;                    // 5000
  const int NL = in_sizes[5] / (128*128);     // 3
  const int* srcv = ei;
  const int* dstv = ei + E;

  char* w = (char*)d_ws;
  uint32_t* hPk   = (uint32_t*)w; w += (size_t)Nn*128*4;
  // region R: xPk (lin1 phase) / hs16 (GAT phase) / hsF (mol phase) — time-disjoint
  char* R = w; w += (size_t)Nn*128*4;
  uint32_t* xPk  = (uint32_t*)R;
  __half2*  hs16 = (__half2*)R;
  float*    hsF  = (float*)R;
  uint32_t* poolP = (uint32_t*)w; w += (size_t)G*128*4;
  float* asN      = (float*)w; w += (size_t)Nn*4;
  float* adN      = (float*)w; w += (size_t)Nn*4;
  int*   deg      = (int*)w;   w += (size_t)Nn*4;
  int*   rp       = (int*)w;   w += (size_t)(Nn+64)*4;
  int*   cur      = (int*)w;   w += (size_t)Nn*4;
  int*   ssorted  = (int*)w;   w += (size_t)E*4;
  int*   bsum     = (int*)w;   w += 4096;
  unsigned short* w1h = (unsigned short*)w; w += 64*128*2;
  unsigned short* w1l = (unsigned short*)w; w += 64*128*2;
  unsigned short* gwh = (unsigned short*)w; w += (size_t)NL*128*128*2;
  unsigned short* gwl = (unsigned short*)w; w += (size_t)NL*128*128*2;
  unsigned short* mwh = (unsigned short*)w; w += 128*128*2;
  unsigned short* mwl = (unsigned short*)w; w += 128*128*2;

  const int nscan = (Nn + 255)/256;
  const int nrt = (Nn + 63)/64;    // gemm row-tiles (64 rows/block)
  const int grt = (G + 63)/64;

  // ---- CSR build ----
  hipMemsetAsync(deg, 0, (size_t)Nn*4, stream);
  hist_k<<<(E+255)/256, 256, 0, stream>>>(dstv, deg, E);
  scan_sum<<<nscan, 256, 0, stream>>>(deg, bsum, Nn);
  scan_blocksums<<<1, 512, 0, stream>>>(bsum, nscan);
  scan_final<<<nscan, 256, 0, stream>>>(deg, bsum, rp, cur, Nn, E);
  scatter_k<<<(E+255)/256, 256, 0, stream>>>(srcv, dstv, cur, ssorted, E);

  // ---- prep: x and weights ----
  xprep<<<((Nn*64/4)+255)/256, 256, 0, stream>>>(x, xPk, Nn*64/4);
  wprep<<<((64*128)+255)/256, 256, 0, stream>>>(W1, w1h, w1l, 64, 64*128);
  wprep<<<((NL*128*128)+255)/256, 256, 0, stream>>>(gW, gwh, gwl, 128, NL*128*128);
  wprep<<<((128*128)+255)/256, 256, 0, stream>>>(mW, mwh, mwl, 128, 128*128);

  // ---- lin1 + leaky_relu -> packed h ----
  gemm_mfma<2, 1, false, false><<<nrt, 256, 0, stream>>>(
      xPk, w1h, w1l, b1, nullptr, nullptr, nullptr, nullptr, hPk, nullptr, nullptr, Nn);

  // ---- 3 GAT layers ----
  for (int l = 0; l < NL; ++l){
    gemm_mfma<4, 2, true, true><<<nrt, 256, 0, stream>>>(
        hPk, gwh + (size_t)l*128*128, gwl + (size_t)l*128*128, nullptr,
        g_asrc + l*128, g_adst + l*128, nullptr, hs16, nullptr, asN, adN, Nn);
    gat_agg<<<(Nn+3)/4, 256, 0, stream>>>(ssorted, rp, asN, adN, hs16, g_b + l*128, hPk, Nn);
  }

  // ---- readout ----
  pool_relu<<<G, 128, 0, stream>>>(hPk, batch, poolP, Nn);
  gemm_mfma<4, 3, true, false><<<nrt, 256, 0, stream>>>(
      hPk, mwh, mwl, nullptr, m_asrc, nullptr, hsF, nullptr, nullptr, asN, nullptr, Nn);  // hs2 + as2
  gemm_mfma<4, 0, true, false><<<grt, 256, 0, stream>>>(
      poolP, mwh, mwl, nullptr, m_adst, nullptr, nullptr, nullptr, nullptr, adN, nullptr, G); // ad2
  mol_agg<<<G, 128, 0, stream>>>(asN, adN, hsF, batch, m_b, W2, b2, (float*)d_out, Nn);
}

// Round 6
// 388.914 us; speedup vs baseline: 1.4478x; 1.2111x over previous
//
#include <hip/hip_runtime.h>
#include <hip/hip_fp16.h>
#include <math.h>
#include <stdint.h>

#define DEV __device__ __forceinline__

using f32x4  = __attribute__((ext_vector_type(4))) float;
using short8 = __attribute__((ext_vector_type(8))) short;

DEV float lrelu(float x){ return x > 0.f ? x : 0.01f*x; }
DEV float elu1(float x){ return x > 0.f ? x : __expf(x)-1.f; }

DEV uint32_t bf16_rne(float x){
  uint32_t b = __float_as_uint(x);
  return (b + 0x7fffu + ((b >> 16) & 1u)) >> 16;
}
// pack f32 -> (hi bf16 | lo bf16), value ~= hi + lo to ~16 mantissa bits
DEV uint32_t pack_hl(float x){
  uint32_t hi = bf16_rne(x);
  float lo = x - __uint_as_float(hi << 16);
  return (hi << 16) | bf16_rne(lo);
}
DEV float unpack_hl(uint32_t u){
  return __uint_as_float(u & 0xffff0000u) + __uint_as_float(u << 16);
}

DEV int lower_bound_i(const int* __restrict__ a, int n, int key){
  int lo = 0, hi = n;
  while (lo < hi){ int mid = (lo+hi)>>1; if (a[mid] < key) lo = mid+1; else hi = mid; }
  return lo;
}

// ============ input prep: f32 -> packed hi/lo ============
__global__ void xprep(const float* __restrict__ x, uint32_t* __restrict__ xp, int n4){
  int i = blockIdx.x*256 + threadIdx.x;
  if (i >= n4) return;
  float4 v = ((const float4*)x)[i];
  uint4 o;
  o.x = pack_hl(v.x); o.y = pack_hl(v.y); o.z = pack_hl(v.z); o.w = pack_hl(v.w);
  ((uint4*)xp)[i] = o;
}

// ============ weight prep: W[K][128] f32 -> Wt_hi/Wt_lo [128][K] bf16 ============
__global__ void wprep(const float* __restrict__ W, unsigned short* __restrict__ Hi,
                      unsigned short* __restrict__ Lo, int K, int tot){
  int idx = blockIdx.x*256 + threadIdx.x;
  if (idx >= tot) return;
  int kn = K*128;
  int mat = idx / kn;
  int rem = idx - mat*kn;
  int k = rem >> 7;
  int n = rem & 127;
  float v = W[idx];
  uint32_t hi = bf16_rne(v);
  float lo = v - __uint_as_float(hi << 16);
  size_t o = (size_t)mat*kn + (size_t)n*K + k;
  Hi[o] = (unsigned short)hi;
  Lo[o] = (unsigned short)bf16_rne(lo);
}

// ============ MFMA GEMM: C[M,128] = A[M,K] @ W[K,128], bf16x2 triple scheme ============
// Block 256 = 4 waves; tile 64 rows x 128 cols; wave = 64 rows x 32 cols.
// A staged in LDS via global_load_lds (width=16), dbuf chunks of 64x32 words,
// XOR-swizzled (byte ^= (row&7)<<4) with inverse swizzle on the global source
// (rule 21: linear dest + pre-swz source + swz read). B prefetched 1 chunk ahead.
// OUTMODE: 0 none (dots only), 1 pack_hl(lrelu(v+bias)), 2 fp16 raw, 3 f32 raw.
// mfma_f32_16x16x32_bf16 C/D: col=lane&15, row=(lane>>4)*4+reg (m89-verified).
template<int KC, int OUTMODE, bool DOTA, bool DOTB>
__global__ __launch_bounds__(256, 3) void gemm_mfma(
    const uint32_t* __restrict__ Apk, const unsigned short* __restrict__ Wt_hi,
    const unsigned short* __restrict__ Wt_lo, const float* __restrict__ bias,
    const float* __restrict__ va, const float* __restrict__ vb,
    float* __restrict__ Cf, __half2* __restrict__ Ch, uint32_t* __restrict__ Cp,
    float* __restrict__ outa, float* __restrict__ outb, int M)
{
  constexpr int K = KC*32;
  const int tid = threadIdx.x;
  const int lane = tid & 63;
  const int wv = tid >> 6;
  const int ml = lane & 15;
  const int kg = lane >> 4;
  const int R0 = blockIdx.x * 64;

  __shared__ uint32_t sA[2][2048];   // 2 x 8 KB A chunks (64 rows x 32 words)
  __shared__ float sC[4][32][36];    // per-wave-private epilogue bounce
  __shared__ float sd[4][64][2];

  const unsigned short* bhp[2];
  const unsigned short* blp[2];
  #pragma unroll
  for (int nt = 0; nt < 2; ++nt){
    int n = wv*32 + nt*16 + ml;
    bhp[nt] = Wt_hi + (size_t)n*K + kg*8;
    blp[nt] = Wt_lo + (size_t)n*K + kg*8;
  }

  // async stage chunk c into sA[c&1]; LDS dest linear (wave-uniform base + lane*16),
  // global source pre-swizzled so that a swizzled ds_read sees logical data.
  auto STAGE = [&](int c){
    #pragma unroll
    for (int r = 0; r < 2; ++r){
      int o = r*4096 + wv*1024 + lane*16;        // linear LDS byte offset
      int row = o >> 7;
      int wb = o & 127;
      int gr = R0 + row; gr = gr < M ? gr : M-1;
      int kb = wb ^ ((row & 7) << 4);            // inverse swizzle on source
      const char* src = (const char*)(Apk + (size_t)gr*K + c*32) + kb;
      char* dst = (char*)(&sA[c & 1][0]) + wv*1024 + r*4096;  // wave-uniform
      __builtin_amdgcn_global_load_lds(
          (const __attribute__((address_space(1))) void*)src,
          (__attribute__((address_space(3))) void*)dst, 16, 0, 0);
    }
  };

  f32x4 acc[4][2];
  #pragma unroll
  for (int mt = 0; mt < 4; ++mt)
    #pragma unroll
    for (int nt = 0; nt < 2; ++nt)
      acc[mt][nt] = (f32x4){0.f,0.f,0.f,0.f};

  STAGE(0);
  short8 bhC[2], blC[2];
  #pragma unroll
  for (int nt = 0; nt < 2; ++nt){
    bhC[nt] = *(const short8*)(bhp[nt]);
    blC[nt] = *(const short8*)(blp[nt]);
  }
  __syncthreads();   // drains vmcnt (staging + B loads)

  #pragma unroll
  for (int c = 0; c < KC; ++c){
    short8 bhN[2], blN[2];
    if (c + 1 < KC){
      STAGE(c + 1);
      #pragma unroll
      for (int nt = 0; nt < 2; ++nt){
        bhN[nt] = *(const short8*)(bhp[nt] + (c+1)*32);
        blN[nt] = *(const short8*)(blp[nt] + (c+1)*32);
      }
    }
    const char* buf = (const char*)&sA[c & 1][0];
    #pragma unroll
    for (int mt = 0; mt < 4; ++mt){
      int row = mt*16 + ml;
      int ba = row*128 + ((kg*32) ^ ((ml & 7) << 4));   // swizzled read addr
      uint4 a0 = *(const uint4*)(buf + ba);
      uint4 a1 = *(const uint4*)(buf + (ba ^ 16));
      union { uint32_t u[4]; short8 s; } H, L;
      H.u[0] = __builtin_amdgcn_perm(a0.y, a0.x, 0x07060302u);
      H.u[1] = __builtin_amdgcn_perm(a0.w, a0.z, 0x07060302u);
      H.u[2] = __builtin_amdgcn_perm(a1.y, a1.x, 0x07060302u);
      H.u[3] = __builtin_amdgcn_perm(a1.w, a1.z, 0x07060302u);
      L.u[0] = __builtin_amdgcn_perm(a0.y, a0.x, 0x05040100u);
      L.u[1] = __builtin_amdgcn_perm(a0.w, a0.z, 0x05040100u);
      L.u[2] = __builtin_amdgcn_perm(a1.y, a1.x, 0x05040100u);
      L.u[3] = __builtin_amdgcn_perm(a1.w, a1.z, 0x05040100u);
      #pragma unroll
      for (int nt = 0; nt < 2; ++nt){
        acc[mt][nt] = __builtin_amdgcn_mfma_f32_16x16x32_bf16(H.s, bhC[nt], acc[mt][nt], 0, 0, 0);
        acc[mt][nt] = __builtin_amdgcn_mfma_f32_16x16x32_bf16(H.s, blC[nt], acc[mt][nt], 0, 0, 0);
        acc[mt][nt] = __builtin_amdgcn_mfma_f32_16x16x32_bf16(L.s, bhC[nt], acc[mt][nt], 0, 0, 0);
      }
    }
    __syncthreads();   // staging of c+1 complete; all reads of sA[c&1] done
    if (c + 1 < KC){
      #pragma unroll
      for (int nt = 0; nt < 2; ++nt){ bhC[nt] = bhN[nt]; blC[nt] = blN[nt]; }
    }
  }

  // ---- fused attention dots (raw acc = hs), cross-wave LDS reduce ----
  if constexpr (DOTA || DOTB){
    float vaL[2] = {0.f,0.f}, vbL[2] = {0.f,0.f};
    if constexpr (DOTA){ vaL[0] = va[wv*32 + ml]; vaL[1] = va[wv*32 + 16 + ml]; }
    if constexpr (DOTB){ vbL[0] = vb[wv*32 + ml]; vbL[1] = vb[wv*32 + 16 + ml]; }
    #pragma unroll
    for (int mt = 0; mt < 4; ++mt){
      #pragma unroll
      for (int r = 0; r < 4; ++r){
        float pa = 0.f, pb = 0.f;
        #pragma unroll
        for (int nt = 0; nt < 2; ++nt){
          float v = acc[mt][nt][r];
          if constexpr (DOTA) pa = fmaf(v, vaL[nt], pa);
          if constexpr (DOTB) pb = fmaf(v, vbL[nt], pb);
        }
        #pragma unroll
        for (int o = 8; o; o >>= 1){
          if constexpr (DOTA) pa += __shfl_xor(pa, o, 64);
          if constexpr (DOTB) pb += __shfl_xor(pb, o, 64);
        }
        if (ml == 0){
          int rl = mt*16 + kg*4 + r;
          sd[wv][rl][0] = pa;
          sd[wv][rl][1] = pb;
        }
      }
    }
    __syncthreads();
    if (tid < 64){
      int row = R0 + tid;
      if (row < M){
        if constexpr (DOTA)
          outa[row] = sd[0][tid][0] + sd[1][tid][0] + sd[2][tid][0] + sd[3][tid][0];
        if constexpr (DOTB)
          outb[row] = sd[0][tid][1] + sd[1][tid][1] + sd[2][tid][1] + sd[3][tid][1];
      }
    }
  }

  // ---- C store via per-wave-private LDS bounce, 2 passes of 32 rows ----
  if constexpr (OUTMODE != 0){
    float bv[2];
    if constexpr (OUTMODE == 1){
      bv[0] = bias[wv*32 + ml];
      bv[1] = bias[wv*32 + 16 + ml];
    }
    #pragma unroll
    for (int p = 0; p < 2; ++p){
      #pragma unroll
      for (int mh = 0; mh < 2; ++mh){
        int mt = p*2 + mh;
        #pragma unroll
        for (int nt = 0; nt < 2; ++nt){
          #pragma unroll
          for (int r = 0; r < 4; ++r){
            float v = acc[mt][nt][r];
            if constexpr (OUTMODE == 1) v = lrelu(v + bv[nt]);
            sC[wv][mh*16 + kg*4 + r][nt*16 + ml] = v;
          }
        }
      }
      #pragma unroll
      for (int j = 0; j < 4; ++j){
        int row_l = j*8 + (lane >> 3);
        int c4 = (lane & 7) * 4;
        int grow = R0 + p*32 + row_l;
        if (grow < M){
          float4 v = *(const float4*)&sC[wv][row_l][c4];
          int gcol = wv*32 + c4;
          if constexpr (OUTMODE == 1){
            uint4 o;
            o.x = pack_hl(v.x); o.y = pack_hl(v.y); o.z = pack_hl(v.z); o.w = pack_hl(v.w);
            *(uint4*)(Cp + (size_t)grow*128 + gcol) = o;
          }
          if constexpr (OUTMODE == 2){
            __half2 h0 = __floats2half2_rn(v.x, v.y);
            __half2 h1 = __floats2half2_rn(v.z, v.w);
            uint2 o;
            o.x = *(uint32_t*)&h0; o.y = *(uint32_t*)&h1;
            *(uint2*)(Ch + (size_t)grow*64 + (gcol >> 1)) = o;
          }
          if constexpr (OUTMODE == 3)
            *(float4*)(Cf + (size_t)grow*128 + gcol) = v;
        }
      }
    }
  }
}

// ============ CSR build ============
__global__ void hist_k(const int* __restrict__ dstv, int* __restrict__ deg, int E){
  int e = blockIdx.x*256 + threadIdx.x;
  if (e < E) atomicAdd(&deg[dstv[e]], 1);
}

__global__ void scan_sum(const int* __restrict__ deg, int* __restrict__ bsum, int n){
  __shared__ int s4[4];
  int i = blockIdx.x*256 + threadIdx.x;
  int v = (i < n) ? deg[i] : 0;
  #pragma unroll
  for (int o = 32; o; o >>= 1) v += __shfl_down(v, o, 64);
  if ((threadIdx.x & 63) == 0) s4[threadIdx.x >> 6] = v;
  __syncthreads();
  if (threadIdx.x == 0) bsum[blockIdx.x] = s4[0]+s4[1]+s4[2]+s4[3];
}

__global__ void scan_blocksums(int* __restrict__ bsum, int nb){
  __shared__ int s[512];
  int t = threadIdx.x;
  s[t] = (t < nb) ? bsum[t] : 0;
  __syncthreads();
  for (int o = 1; o < 512; o <<= 1){
    int v = s[t];
    int u = (t >= o) ? s[t-o] : 0;
    __syncthreads();
    s[t] = v + u;
    __syncthreads();
  }
  if (t < nb) bsum[t] = t ? s[t-1] : 0;
}

__global__ void scan_final(const int* __restrict__ deg, const int* __restrict__ boff,
    int* __restrict__ rp, int* __restrict__ cur, int n, int E)
{
  __shared__ int wsum[4];
  int i = blockIdx.x*256 + threadIdx.x;
  int lane = threadIdx.x & 63, wv = threadIdx.x >> 6;
  int v = (i < n) ? deg[i] : 0;
  int inc = v;
  #pragma unroll
  for (int o = 1; o < 64; o <<= 1){
    int u = __shfl_up(inc, o, 64);
    if (lane >= o) inc += u;
  }
  if (lane == 63) wsum[wv] = inc;
  __syncthreads();
  int woff = boff[blockIdx.x];
  for (int wq = 0; wq < wv; ++wq) woff += wsum[wq];
  int excl = woff + inc - v;
  if (i < n){ rp[i] = excl; cur[i] = excl; }
  if (blockIdx.x == 0 && threadIdx.x == 0) rp[n] = E;
}

// scatter: store SOURCE node id directly (removes indirection in gat_agg)
__global__ void scatter_k(const int* __restrict__ srcv, const int* __restrict__ dstv,
                          int* __restrict__ cur, int* __restrict__ ssorted, int E){
  int e = blockIdx.x*256 + threadIdx.x;
  if (e < E){
    int p = atomicAdd(&cur[dstv[e]], 1);
    ssorted[p] = srcv[e];
  }
}

// ============ fused segment softmax + aggregation (one wave per dst node) ============
// Gathers fp16 hs rows (256 B/row); writes packed hi/lo h' for the next GEMM.
__global__ __launch_bounds__(256) void gat_agg(const int* __restrict__ ssorted,
    const int* __restrict__ rp,
    const float* __restrict__ asn, const float* __restrict__ adn,
    const __half2* __restrict__ hs16, const float* __restrict__ bias,
    uint32_t* __restrict__ outp, int Nn)
{
  const int lane = threadIdx.x & 63;
  const int wv = threadIdx.x >> 6;
  const int d = blockIdx.x*4 + wv;
  if (d >= Nn) return;
  const int lo = rp[d], hi = rp[d+1];
  const int deg = hi - lo;
  float acc0 = 0.f, acc1 = 0.f;
  if (deg > 0){
    const float ad = adn[d];
    if (deg <= 64){
      int sid = 0; float lg = -1e30f;
      if (lane < deg){
        sid = ssorted[lo + lane];
        lg = lrelu(asn[sid] + ad);
      }
      float m = lg;
      #pragma unroll
      for (int o = 32; o; o >>= 1) m = fmaxf(m, __shfl_xor(m, o, 64));
      float p = (lane < deg) ? __expf(lg - m) : 0.f;
      float s = p;
      #pragma unroll
      for (int o = 32; o; o >>= 1) s += __shfl_xor(s, o, 64);
      float alpha = p * (1.f / (s + 1e-16f));
      for (int base = 0; base < deg; base += 8){
        int nb = deg - base; nb = nb > 8 ? 8 : nb;
        __half2 v[8]; float al[8];
        #pragma unroll
        for (int i = 0; i < 8; ++i){
          if (i < nb){
            int sd_ = __shfl(sid, base + i, 64);
            al[i] = __shfl(alpha, base + i, 64);
            v[i] = hs16[(size_t)sd_*64 + lane];
          } else { al[i] = 0.f; v[i] = __half2(); }
        }
        #pragma unroll
        for (int i = 0; i < 8; ++i){
          float2 f = __half22float2(v[i]);
          acc0 = fmaf(al[i], f.x, acc0);
          acc1 = fmaf(al[i], f.y, acc1);
        }
      }
    } else {
      float m = -1e30f;
      for (int e = lane; e < deg; e += 64){
        int sid = ssorted[lo+e];
        m = fmaxf(m, lrelu(asn[sid] + ad));
      }
      #pragma unroll
      for (int o = 32; o; o >>= 1) m = fmaxf(m, __shfl_xor(m, o, 64));
      float s = 0.f;
      for (int e = lane; e < deg; e += 64){
        int sid = ssorted[lo+e];
        s += __expf(lrelu(asn[sid] + ad) - m);
      }
      #pragma unroll
      for (int o = 32; o; o >>= 1) s += __shfl_xor(s, o, 64);
      float inv = 1.f / (s + 1e-16f);
      for (int e = 0; e < deg; ++e){
        int sid = ssorted[lo+e];
        float a = __expf(lrelu(asn[sid] + ad) - m) * inv;
        float2 f = __half22float2(hs16[(size_t)sid*64 + lane]);
        acc0 = fmaf(a, f.x, acc0);
        acc1 = fmaf(a, f.y, acc1);
      }
    }
  }
  float2 bb = *(const float2*)(bias + lane*2);
  uint2 o;
  o.x = pack_hl(elu1(acc0 + bb.x));
  o.y = pack_hl(elu1(acc1 + bb.y));
  *(uint2*)(outp + (size_t)d*128 + lane*2) = o;
}

// ============ graph pooling (packed in, packed out) ============
__global__ __launch_bounds__(128) void pool_relu(const uint32_t* __restrict__ hp,
    const int* __restrict__ batch, uint32_t* __restrict__ pooledp, int Nn)
{
  const int g = blockIdx.x;
  const int c = threadIdx.x;
  __shared__ int sb[2];
  if (c < 2) sb[c] = lower_bound_i(batch, Nn, g + c);
  __syncthreads();
  const int lo = sb[0], hi = sb[1];
  float s = 0.f;
  for (int i = lo; i < hi; ++i) s += unpack_hl(hp[(size_t)i*128 + c]);
  pooledp[(size_t)g*128 + c] = pack_hl(fmaxf(s, 0.f));
}

// ============ molecular GAT aggregate + final linear (fused) ============
__global__ __launch_bounds__(128) void mol_agg(const float* __restrict__ as2,
    const float* __restrict__ ad2, const float* __restrict__ hs2,
    const int* __restrict__ batch, const float* __restrict__ bias,
    const float* __restrict__ W2, const float* __restrict__ b2,
    float* __restrict__ out, int Nn)
{
  const int g = blockIdx.x;
  const int c = threadIdx.x;
  __shared__ int sb[2];
  __shared__ float red[2];
  if (c < 2) sb[c] = lower_bound_i(batch, Nn, g + c);
  __syncthreads();
  const int lo = sb[0], hi = sb[1];
  const float ad = ad2[g];

  float mt = -1e30f;
  for (int i = lo + c; i < hi; i += 128) mt = fmaxf(mt, lrelu(as2[i] + ad));
  #pragma unroll
  for (int o = 32; o; o >>= 1) mt = fmaxf(mt, __shfl_xor(mt, o, 64));
  if ((c & 63) == 0) red[c >> 6] = mt;
  __syncthreads();
  const float m = fmaxf(red[0], red[1]);

  float st = 0.f;
  for (int i = lo + c; i < hi; i += 128) st += __expf(lrelu(as2[i] + ad) - m);
  #pragma unroll
  for (int o = 32; o; o >>= 1) st += __shfl_xor(st, o, 64);
  __syncthreads();
  if ((c & 63) == 0) red[c >> 6] = st;
  __syncthreads();
  const float inv = 1.f / (red[0] + red[1] + 1e-16f);

  float acc = 0.f;
  for (int i = lo; i < hi; ++i){
    float wgt = __expf(lrelu(as2[i] + ad) - m) * inv;
    acc = fmaf(wgt, hs2[(size_t)i*128 + c], acc);
  }
  float v = elu1(acc + bias[c]);

  float r = v * W2[c];
  #pragma unroll
  for (int o = 32; o; o >>= 1) r += __shfl_xor(r, o, 64);
  __syncthreads();
  if ((c & 63) == 0) red[c >> 6] = r;
  __syncthreads();
  if (c == 0) out[g] = red[0] + red[1] + b2[0];
}

extern "C" void kernel_launch(void* const* d_in, const int* in_sizes, int n_in,
                              void* d_out, int out_size, void* d_ws, size_t ws_size,
                              hipStream_t stream)
{
  const float* x      = (const float*)d_in[0];
  const int*   ei     = (const int*)  d_in[1];
  const int*   batch  = (const int*)  d_in[2];
  const float* W1     = (const float*)d_in[3];
  const float* b1     = (const float*)d_in[4];
  const float* gW     = (const float*)d_in[5];
  const float* g_asrc = (const float*)d_in[6];
  const float* g_adst = (const float*)d_in[7];
  const float* g_b    = (const float*)d_in[8];
  const float* mW     = (const float*)d_in[9];
  const float* m_asrc = (const float*)d_in[10];
  const float* m_adst = (const float*)d_in[11];
  const float* m_b    = (const float*)d_in[12];
  const float* W2     = (const float*)d_in[13];
  const float* b2     = (const float*)d_in[14];

  const int Nn = in_sizes[0] / 64;            // 100000
  const int E  = in_sizes[1] / 2;             // 400000
  const int G  = out_size;                    // 5000
  const int NL = in_sizes[5] / (128*128);     // 3
  const int* srcv = ei;
  const int* dstv = ei + E;

  char* w = (char*)d_ws;
  uint32_t* hPk   = (uint32_t*)w; w += (size_t)Nn*128*4;
  // region R: xPk (lin1 phase) / hs16 (GAT phase) / hsF (mol phase) — time-disjoint
  char* R = w; w += (size_t)Nn*128*4;
  uint32_t* xPk  = (uint32_t*)R;
  __half2*  hs16 = (__half2*)R;
  float*    hsF  = (float*)R;
  uint32_t* poolP = (uint32_t*)w; w += (size_t)G*128*4;
  float* asN      = (float*)w; w += (size_t)Nn*4;
  float* adN      = (float*)w; w += (size_t)Nn*4;
  int*   deg      = (int*)w;   w += (size_t)Nn*4;
  int*   rp       = (int*)w;   w += (size_t)(Nn+64)*4;
  int*   cur      = (int*)w;   w += (size_t)Nn*4;
  int*   ssorted  = (int*)w;   w += (size_t)E*4;
  int*   bsum     = (int*)w;   w += 4096;
  unsigned short* w1h = (unsigned short*)w; w += 64*128*2;
  unsigned short* w1l = (unsigned short*)w; w += 64*128*2;
  unsigned short* gwh = (unsigned short*)w; w += (size_t)NL*128*128*2;
  unsigned short* gwl = (unsigned short*)w; w += (size_t)NL*128*128*2;
  unsigned short* mwh = (unsigned short*)w; w += 128*128*2;
  unsigned short* mwl = (unsigned short*)w; w += 128*128*2;

  const int nscan = (Nn + 255)/256;
  const int nrt = (Nn + 63)/64;    // gemm row-tiles (64 rows/block)
  const int grt = (G + 63)/64;

  // ---- CSR build ----
  hipMemsetAsync(deg, 0, (size_t)Nn*4, stream);
  hist_k<<<(E+255)/256, 256, 0, stream>>>(dstv, deg, E);
  scan_sum<<<nscan, 256, 0, stream>>>(deg, bsum, Nn);
  scan_blocksums<<<1, 512, 0, stream>>>(bsum, nscan);
  scan_final<<<nscan, 256, 0, stream>>>(deg, bsum, rp, cur, Nn, E);
  scatter_k<<<(E+255)/256, 256, 0, stream>>>(srcv, dstv, cur, ssorted, E);

  // ---- prep: x and weights ----
  xprep<<<((Nn*64/4)+255)/256, 256, 0, stream>>>(x, xPk, Nn*64/4);
  wprep<<<((64*128)+255)/256, 256, 0, stream>>>(W1, w1h, w1l, 64, 64*128);
  wprep<<<((NL*128*128)+255)/256, 256, 0, stream>>>(gW, gwh, gwl, 128, NL*128*128);
  wprep<<<((128*128)+255)/256, 256, 0, stream>>>(mW, mwh, mwl, 128, 128*128);

  // ---- lin1 + leaky_relu -> packed h ----
  gemm_mfma<2, 1, false, false><<<nrt, 256, 0, stream>>>(
      xPk, w1h, w1l, b1, nullptr, nullptr, nullptr, nullptr, hPk, nullptr, nullptr, Nn);

  // ---- 3 GAT layers ----
  for (int l = 0; l < NL; ++l){
    gemm_mfma<4, 2, true, true><<<nrt, 256, 0, stream>>>(
        hPk, gwh + (size_t)l*128*128, gwl + (size_t)l*128*128, nullptr,
        g_asrc + l*128, g_adst + l*128, nullptr, hs16, nullptr, asN, adN, Nn);
    gat_agg<<<(Nn+3)/4, 256, 0, stream>>>(ssorted, rp, asN, adN, hs16, g_b + l*128, hPk, Nn);
  }

  // ---- readout ----
  pool_relu<<<G, 128, 0, stream>>>(hPk, batch, poolP, Nn);
  gemm_mfma<4, 3, true, false><<<nrt, 256, 0, stream>>>(
      hPk, mwh, mwl, nullptr, m_asrc, nullptr, hsF, nullptr, nullptr, asN, nullptr, Nn);  // hs2 + as2
  gemm_mfma<4, 0, true, false><<<grt, 256, 0, stream>>>(
      poolP, mwh, mwl, nullptr, m_adst, nullptr, nullptr, nullptr, nullptr, adN, nullptr, G); // ad2
  mol_agg<<<G, 128, 0, stream>>>(asN, adN, hsF, batch, m_b, W2, b2, (float*)d_out, Nn);
}

// Round 7
// 363.039 us; speedup vs baseline: 1.5510x; 1.0713x over previous
//
#include <hip/hip_runtime.h>
#include <hip/hip_fp16.h>
#include <math.h>
#include <stdint.h>

#define DEV __device__ __forceinline__

using f32x4 = __attribute__((ext_vector_type(4))) float;
using half8 = __attribute__((ext_vector_type(8))) _Float16;
typedef union { uint4 u; half8 h; } u4h8;

DEV float lrelu(float x){ return x > 0.f ? x : 0.01f*x; }
DEV float elu1(float x){ return x > 0.f ? x : __expf(x)-1.f; }

DEV int lower_bound_i(const int* __restrict__ a, int n, int key){
  int lo = 0, hi = n;
  while (lo < hi){ int mid = (lo+hi)>>1; if (a[mid] < key) lo = mid+1; else hi = mid; }
  return lo;
}

// ============ input prep: f32 -> fp16 ============
__global__ void xprep(const float* __restrict__ x, unsigned short* __restrict__ xh, int n4){
  int i = blockIdx.x*256 + threadIdx.x;
  if (i >= n4) return;
  float4 v = ((const float4*)x)[i];
  __half2 h0 = __floats2half2_rn(v.x, v.y);
  __half2 h1 = __floats2half2_rn(v.z, v.w);
  uint2 o;
  o.x = *(uint32_t*)&h0; o.y = *(uint32_t*)&h1;
  *(uint2*)(xh + (size_t)i*4) = o;
}

// ============ weight prep: W[K][128] f32 -> Wt_hi/Wt_lo(f16, lo scaled by 1024) [128][K] ============
__global__ void wprep(const float* __restrict__ W, unsigned short* __restrict__ Hi,
                      unsigned short* __restrict__ Lo, int K, int tot){
  int idx = blockIdx.x*256 + threadIdx.x;
  if (idx >= tot) return;
  int kn = K*128;
  int mat = idx / kn;
  int rem = idx - mat*kn;
  int k = rem >> 7;
  int n = rem & 127;
  float v = W[idx];
  __half h = __float2half_rn(v);
  float lo = (v - __half2float(h)) * 1024.f;
  size_t o = (size_t)mat*kn + (size_t)n*K + k;
  Hi[o] = __half_as_ushort(h);
  Lo[o] = __half_as_ushort(__float2half_rn(lo));
}

// ============ MFMA GEMM: C[M,128] = A[M,K] @ W[K,128], f16 dual-acc scheme ============
// Block 256 = 4 waves; tile 64 rows x 128 cols; wave = 64 rows x 32 cols.
// A fp16 staged in LDS via global_load_lds (16B), dbuf 4KB chunks (64 rows x 32 k).
// XOR swizzle on the 16B k-slot (t = kg ^ ((row>>1)&3)); inverse folded into the
// global source address (linear dest + pre-swz source + swz read).
// acc = A@Whi + (A@Wlo)/1024 combined at epilogue (W effectively exact).
// OUTMODE: 0 none (dots only), 1 fp16 lrelu(v+bias), 2 fp16 raw.
template<int KC, int OUTMODE, bool DOTA, bool DOTB>
__global__ __launch_bounds__(256, 3) void gemm_mfma(
    const unsigned short* __restrict__ Ah, const unsigned short* __restrict__ Wt_hi,
    const unsigned short* __restrict__ Wt_lo, const float* __restrict__ bias,
    const float* __restrict__ va, const float* __restrict__ vb,
    unsigned short* __restrict__ Ch,
    float* __restrict__ outa, float* __restrict__ outb, int M)
{
  constexpr int K = KC*32;
  const int tid = threadIdx.x;
  const int lane = tid & 63;
  const int wv = tid >> 6;
  const int ml = lane & 15;
  const int kg = lane >> 4;
  const int R0 = blockIdx.x * 64;

  __shared__ uint32_t sA[2][1024];   // 2 x 4 KB fp16 A chunks (64 rows x 32 k)
  __shared__ float sC[4][32][36];
  __shared__ float sd[4][64][2];

  const unsigned short* bhp[2];
  const unsigned short* blp[2];
  #pragma unroll
  for (int nt = 0; nt < 2; ++nt){
    int n = wv*32 + nt*16 + ml;
    bhp[nt] = Wt_hi + (size_t)n*K + kg*8;
    blp[nt] = Wt_lo + (size_t)n*K + kg*8;
  }

  auto STAGE = [&](int c){
    int o = tid*16;                    // linear LDS byte offset in chunk (0..4095)
    int row = o >> 6;                  // 64B per row
    int t = (o >> 4) & 3;              // 16B k-slot
    int gr = R0 + row; gr = gr < M ? gr : M-1;
    int j = t ^ ((row >> 1) & 3);      // inverse swizzle on source
    const char* src = (const char*)(Ah + (size_t)gr*K + c*32) + j*16;
    char* dst = (char*)(&sA[c & 1][0]) + wv*1024;   // wave-uniform base
    __builtin_amdgcn_global_load_lds(
        (const __attribute__((address_space(1))) void*)src,
        (__attribute__((address_space(3))) void*)dst, 16, 0, 0);
  };

  f32x4 accH[4][2], accL[4][2];
  #pragma unroll
  for (int mt = 0; mt < 4; ++mt)
    #pragma unroll
    for (int nt = 0; nt < 2; ++nt){
      accH[mt][nt] = (f32x4){0.f,0.f,0.f,0.f};
      accL[mt][nt] = (f32x4){0.f,0.f,0.f,0.f};
    }

  STAGE(0);
  u4h8 bhC[2], blC[2];
  #pragma unroll
  for (int nt = 0; nt < 2; ++nt){
    bhC[nt].u = *(const uint4*)(bhp[nt]);
    blC[nt].u = *(const uint4*)(blp[nt]);
  }
  __syncthreads();

  #pragma unroll
  for (int c = 0; c < KC; ++c){
    u4h8 bhN[2], blN[2];
    if (c + 1 < KC){
      STAGE(c + 1);
      #pragma unroll
      for (int nt = 0; nt < 2; ++nt){
        bhN[nt].u = *(const uint4*)(bhp[nt] + (c+1)*32);
        blN[nt].u = *(const uint4*)(blp[nt] + (c+1)*32);
      }
    }
    const char* buf = (const char*)&sA[c & 1][0];
    #pragma unroll
    for (int mt = 0; mt < 4; ++mt){
      int row = mt*16 + ml;
      int ba = row*64 + ((kg ^ ((row >> 1) & 3)) * 16);   // swizzled read
      u4h8 A_;
      A_.u = *(const uint4*)(buf + ba);
      #pragma unroll
      for (int nt = 0; nt < 2; ++nt){
        accH[mt][nt] = __builtin_amdgcn_mfma_f32_16x16x32_f16(A_.h, bhC[nt].h, accH[mt][nt], 0, 0, 0);
        accL[mt][nt] = __builtin_amdgcn_mfma_f32_16x16x32_f16(A_.h, blC[nt].h, accL[mt][nt], 0, 0, 0);
      }
    }
    __syncthreads();
    if (c + 1 < KC){
      #pragma unroll
      for (int nt = 0; nt < 2; ++nt){ bhC[nt] = bhN[nt]; blC[nt] = blN[nt]; }
    }
  }

  // combine hi + lo/1024
  #pragma unroll
  for (int mt = 0; mt < 4; ++mt)
    #pragma unroll
    for (int nt = 0; nt < 2; ++nt)
      accH[mt][nt] = accH[mt][nt] + accL[mt][nt] * 9.765625e-4f;

  // ---- fused attention dots, cross-wave LDS reduce ----
  if constexpr (DOTA || DOTB){
    float vaL[2] = {0.f,0.f}, vbL[2] = {0.f,0.f};
    if constexpr (DOTA){ vaL[0] = va[wv*32 + ml]; vaL[1] = va[wv*32 + 16 + ml]; }
    if constexpr (DOTB){ vbL[0] = vb[wv*32 + ml]; vbL[1] = vb[wv*32 + 16 + ml]; }
    #pragma unroll
    for (int mt = 0; mt < 4; ++mt){
      #pragma unroll
      for (int r = 0; r < 4; ++r){
        float pa = 0.f, pb = 0.f;
        #pragma unroll
        for (int nt = 0; nt < 2; ++nt){
          float v = accH[mt][nt][r];
          if constexpr (DOTA) pa = fmaf(v, vaL[nt], pa);
          if constexpr (DOTB) pb = fmaf(v, vbL[nt], pb);
        }
        #pragma unroll
        for (int o = 8; o; o >>= 1){
          if constexpr (DOTA) pa += __shfl_xor(pa, o, 64);
          if constexpr (DOTB) pb += __shfl_xor(pb, o, 64);
        }
        if (ml == 0){
          int rl = mt*16 + kg*4 + r;
          sd[wv][rl][0] = pa;
          sd[wv][rl][1] = pb;
        }
      }
    }
    __syncthreads();
    if (tid < 64){
      int row = R0 + tid;
      if (row < M){
        if constexpr (DOTA)
          outa[row] = sd[0][tid][0] + sd[1][tid][0] + sd[2][tid][0] + sd[3][tid][0];
        if constexpr (DOTB)
          outb[row] = sd[0][tid][1] + sd[1][tid][1] + sd[2][tid][1] + sd[3][tid][1];
      }
    }
  }

  // ---- C store (fp16) via per-wave-private LDS bounce ----
  if constexpr (OUTMODE != 0){
    float bv[2];
    if constexpr (OUTMODE == 1){
      bv[0] = bias[wv*32 + ml];
      bv[1] = bias[wv*32 + 16 + ml];
    }
    #pragma unroll
    for (int p = 0; p < 2; ++p){
      #pragma unroll
      for (int mh = 0; mh < 2; ++mh){
        int mt = p*2 + mh;
        #pragma unroll
        for (int nt = 0; nt < 2; ++nt){
          #pragma unroll
          for (int r = 0; r < 4; ++r){
            float v = accH[mt][nt][r];
            if constexpr (OUTMODE == 1) v = lrelu(v + bv[nt]);
            sC[wv][mh*16 + kg*4 + r][nt*16 + ml] = v;
          }
        }
      }
      #pragma unroll
      for (int j = 0; j < 4; ++j){
        int row_l = j*8 + (lane >> 3);
        int c4 = (lane & 7) * 4;
        int grow = R0 + p*32 + row_l;
        if (grow < M){
          float4 v = *(const float4*)&sC[wv][row_l][c4];
          int gcol = wv*32 + c4;
          __half2 h0 = __floats2half2_rn(v.x, v.y);
          __half2 h1 = __floats2half2_rn(v.z, v.w);
          uint2 o;
          o.x = *(uint32_t*)&h0; o.y = *(uint32_t*)&h1;
          *(uint2*)(Ch + (size_t)grow*128 + gcol) = o;
        }
      }
    }
  }
}

// ============ CSR build ============
__global__ void hist_k(const int* __restrict__ dstv, int* __restrict__ deg, int E){
  int e = blockIdx.x*256 + threadIdx.x;
  if (e < E) atomicAdd(&deg[dstv[e]], 1);
}

__global__ void scan_sum(const int* __restrict__ deg, int* __restrict__ bsum, int n){
  __shared__ int s4[4];
  int i = blockIdx.x*256 + threadIdx.x;
  int v = (i < n) ? deg[i] : 0;
  #pragma unroll
  for (int o = 32; o; o >>= 1) v += __shfl_down(v, o, 64);
  if ((threadIdx.x & 63) == 0) s4[threadIdx.x >> 6] = v;
  __syncthreads();
  if (threadIdx.x == 0) bsum[blockIdx.x] = s4[0]+s4[1]+s4[2]+s4[3];
}

__global__ void scan_blocksums(int* __restrict__ bsum, int nb){
  __shared__ int s[512];
  int t = threadIdx.x;
  s[t] = (t < nb) ? bsum[t] : 0;
  __syncthreads();
  for (int o = 1; o < 512; o <<= 1){
    int v = s[t];
    int u = (t >= o) ? s[t-o] : 0;
    __syncthreads();
    s[t] = v + u;
    __syncthreads();
  }
  if (t < nb) bsum[t] = t ? s[t-1] : 0;
}

__global__ void scan_final(const int* __restrict__ deg, const int* __restrict__ boff,
    int* __restrict__ rp, int* __restrict__ cur, int n, int E)
{
  __shared__ int wsum[4];
  int i = blockIdx.x*256 + threadIdx.x;
  int lane = threadIdx.x & 63, wv = threadIdx.x >> 6;
  int v = (i < n) ? deg[i] : 0;
  int inc = v;
  #pragma unroll
  for (int o = 1; o < 64; o <<= 1){
    int u = __shfl_up(inc, o, 64);
    if (lane >= o) inc += u;
  }
  if (lane == 63) wsum[wv] = inc;
  __syncthreads();
  int woff = boff[blockIdx.x];
  for (int wq = 0; wq < wv; ++wq) woff += wsum[wq];
  int excl = woff + inc - v;
  if (i < n){ rp[i] = excl; cur[i] = excl; }
  if (blockIdx.x == 0 && threadIdx.x == 0) rp[n] = E;
}

__global__ void scatter_k(const int* __restrict__ srcv, const int* __restrict__ dstv,
                          int* __restrict__ cur, int* __restrict__ ssorted, int E){
  int e = blockIdx.x*256 + threadIdx.x;
  if (e < E){
    int p = atomicAdd(&cur[dstv[e]], 1);
    ssorted[p] = srcv[e];
  }
}

// ============ fused segment softmax + aggregation (one wave per dst node) ============
// fp16 in (hs), fp16 out (h'). Predication-free inner loop: alpha==0 for lanes>=deg.
__global__ __launch_bounds__(256) void gat_agg(const int* __restrict__ ssorted,
    const int* __restrict__ rp,
    const float* __restrict__ asn, const float* __restrict__ adn,
    const __half2* __restrict__ hs16, const float* __restrict__ bias,
    __half2* __restrict__ outp, int Nn)
{
  const int lane = threadIdx.x & 63;
  const int wv = threadIdx.x >> 6;
  const int d = blockIdx.x*4 + wv;
  if (d >= Nn) return;
  const int lo = rp[d], hi = rp[d+1];
  const int deg = hi - lo;
  float acc0 = 0.f, acc1 = 0.f;
  if (deg > 0){
    const float ad = adn[d];
    if (deg <= 64){
      int sid = 0; float lg = -1e30f;
      if (lane < deg){
        sid = ssorted[lo + lane];
        lg = lrelu(asn[sid] + ad);
      }
      float m = lg, s;
      if (deg <= 8){
        #pragma unroll
        for (int o = 4; o; o >>= 1) m = fmaxf(m, __shfl_xor(m, o, 64));
        float p = (lane < deg) ? __expf(lg - m) : 0.f;
        s = p;
        #pragma unroll
        for (int o = 4; o; o >>= 1) s += __shfl_xor(s, o, 64);
        float alpha = p * (1.f / (s + 1e-16f));
        float al[8]; __half2 v[8];
        #pragma unroll
        for (int i = 0; i < 8; ++i){
          al[i] = __shfl(alpha, i, 64);
          int sd_ = __shfl(sid, i, 64);
          v[i] = hs16[(size_t)sd_*64 + lane];
        }
        #pragma unroll
        for (int i = 0; i < 8; ++i){
          float2 f = __half22float2(v[i]);
          acc0 = fmaf(al[i], f.x, acc0);
          acc1 = fmaf(al[i], f.y, acc1);
        }
      } else {
        #pragma unroll
        for (int o = 32; o; o >>= 1) m = fmaxf(m, __shfl_xor(m, o, 64));
        float p = (lane < deg) ? __expf(lg - m) : 0.f;
        s = p;
        #pragma unroll
        for (int o = 32; o; o >>= 1) s += __shfl_xor(s, o, 64);
        float alpha = p * (1.f / (s + 1e-16f));
        for (int base = 0; base < deg; base += 8){
          float al[8]; __half2 v[8];
          #pragma unroll
          for (int i = 0; i < 8; ++i){
            int e = base + i;                 // <= 63 always
            al[i] = __shfl(alpha, e, 64);     // 0 for e >= deg
            int sd_ = __shfl(sid, e, 64);     // 0 for e >= deg (harmless)
            v[i] = hs16[(size_t)sd_*64 + lane];
          }
          #pragma unroll
          for (int i = 0; i < 8; ++i){
            float2 f = __half22float2(v[i]);
            acc0 = fmaf(al[i], f.x, acc0);
            acc1 = fmaf(al[i], f.y, acc1);
          }
        }
      }
    } else {
      float m = -1e30f;
      for (int e = lane; e < deg; e += 64){
        int sid = ssorted[lo+e];
        m = fmaxf(m, lrelu(asn[sid] + ad));
      }
      #pragma unroll
      for (int o = 32; o; o >>= 1) m = fmaxf(m, __shfl_xor(m, o, 64));
      float s = 0.f;
      for (int e = lane; e < deg; e += 64){
        int sid = ssorted[lo+e];
        s += __expf(lrelu(asn[sid] + ad) - m);
      }
      #pragma unroll
      for (int o = 32; o; o >>= 1) s += __shfl_xor(s, o, 64);
      float inv = 1.f / (s + 1e-16f);
      for (int e = 0; e < deg; ++e){
        int sid = ssorted[lo+e];
        float a = __expf(lrelu(asn[sid] + ad) - m) * inv;
        float2 f = __half22float2(hs16[(size_t)sid*64 + lane]);
        acc0 = fmaf(a, f.x, acc0);
        acc1 = fmaf(a, f.y, acc1);
      }
    }
  }
  float2 bb = *(const float2*)(bias + lane*2);
  outp[(size_t)d*64 + lane] = __floats2half2_rn(elu1(acc0 + bb.x), elu1(acc1 + bb.y));
}

// ============ graph pooling (fp16 in, fp16 out) ============
__global__ __launch_bounds__(128) void pool_relu(const unsigned short* __restrict__ h16,
    const int* __restrict__ batch, unsigned short* __restrict__ pooled, int Nn)
{
  const int g = blockIdx.x;
  const int c = threadIdx.x;
  __shared__ int sb[2];
  if (c < 2) sb[c] = lower_bound_i(batch, Nn, g + c);
  __syncthreads();
  const int lo = sb[0], hi = sb[1];
  float s = 0.f;
  for (int i = lo; i < hi; ++i)
    s += __half2float(__ushort_as_half(h16[(size_t)i*128 + c]));
  pooled[(size_t)g*128 + c] = __half_as_ushort(__float2half_rn(fmaxf(s, 0.f)));
}

// ============ molecular GAT aggregate + final linear (fused) ============
__global__ __launch_bounds__(128) void mol_agg(const float* __restrict__ as2,
    const float* __restrict__ ad2, const unsigned short* __restrict__ hs2,
    const int* __restrict__ batch, const float* __restrict__ bias,
    const float* __restrict__ W2, const float* __restrict__ b2,
    float* __restrict__ out, int Nn)
{
  const int g = blockIdx.x;
  const int c = threadIdx.x;
  __shared__ int sb[2];
  __shared__ float red[2];
  if (c < 2) sb[c] = lower_bound_i(batch, Nn, g + c);
  __syncthreads();
  const int lo = sb[0], hi = sb[1];
  const float ad = ad2[g];

  float mt = -1e30f;
  for (int i = lo + c; i < hi; i += 128) mt = fmaxf(mt, lrelu(as2[i] + ad));
  #pragma unroll
  for (int o = 32; o; o >>= 1) mt = fmaxf(mt, __shfl_xor(mt, o, 64));
  if ((c & 63) == 0) red[c >> 6] = mt;
  __syncthreads();
  const float m = fmaxf(red[0], red[1]);

  float st = 0.f;
  for (int i = lo + c; i < hi; i += 128) st += __expf(lrelu(as2[i] + ad) - m);
  #pragma unroll
  for (int o = 32; o; o >>= 1) st += __shfl_xor(st, o, 64);
  __syncthreads();
  if ((c & 63) == 0) red[c >> 6] = st;
  __syncthreads();
  const float inv = 1.f / (red[0] + red[1] + 1e-16f);

  float acc = 0.f;
  for (int i = lo; i < hi; ++i){
    float wgt = __expf(lrelu(as2[i] + ad) - m) * inv;
    acc = fmaf(wgt, __half2float(__ushort_as_half(hs2[(size_t)i*128 + c])), acc);
  }
  float v = elu1(acc + bias[c]);

  float r = v * W2[c];
  #pragma unroll
  for (int o = 32; o; o >>= 1) r += __shfl_xor(r, o, 64);
  __syncthreads();
  if ((c & 63) == 0) red[c >> 6] = r;
  __syncthreads();
  if (c == 0) out[g] = red[0] + red[1] + b2[0];
}

extern "C" void kernel_launch(void* const* d_in, const int* in_sizes, int n_in,
                              void* d_out, int out_size, void* d_ws, size_t ws_size,
                              hipStream_t stream)
{
  const float* x      = (const float*)d_in[0];
  const int*   ei     = (const int*)  d_in[1];
  const int*   batch  = (const int*)  d_in[2];
  const float* W1     = (const float*)d_in[3];
  const float* b1     = (const float*)d_in[4];
  const float* gW     = (const float*)d_in[5];
  const float* g_asrc = (const float*)d_in[6];
  const float* g_adst = (const float*)d_in[7];
  const float* g_b    = (const float*)d_in[8];
  const float* mW     = (const float*)d_in[9];
  const float* m_asrc = (const float*)d_in[10];
  const float* m_adst = (const float*)d_in[11];
  const float* m_b    = (const float*)d_in[12];
  const float* W2     = (const float*)d_in[13];
  const float* b2     = (const float*)d_in[14];

  const int Nn = in_sizes[0] / 64;            // 100000
  const int E  = in_sizes[1] / 2;             // 400000
  const int G  = out_size;                    // 5000
  const int NL = in_sizes[5] / (128*128);     // 3
  const int* srcv = ei;
  const int* dstv = ei + E;

  char* w = (char*)d_ws;
  unsigned short* h16  = (unsigned short*)w; w += (size_t)Nn*128*2;
  // region R: xh (lin1) / hs16 (GAT layers) / hs2 (mol) — time-disjoint
  char* R = w; w += (size_t)Nn*128*2;
  unsigned short* xh  = (unsigned short*)R;
  unsigned short* hsR = (unsigned short*)R;
  unsigned short* poolh = (unsigned short*)w; w += (size_t)G*128*2;
  float* asN      = (float*)w; w += (size_t)Nn*4;
  float* adN      = (float*)w; w += (size_t)Nn*4;
  int*   deg      = (int*)w;   w += (size_t)Nn*4;
  int*   rp       = (int*)w;   w += (size_t)(Nn+64)*4;
  int*   cur      = (int*)w;   w += (size_t)Nn*4;
  int*   ssorted  = (int*)w;   w += (size_t)E*4;
  int*   bsum     = (int*)w;   w += 4096;
  unsigned short* w1h = (unsigned short*)w; w += 64*128*2;
  unsigned short* w1l = (unsigned short*)w; w += 64*128*2;
  unsigned short* gwh = (unsigned short*)w; w += (size_t)NL*128*128*2;
  unsigned short* gwl = (unsigned short*)w; w += (size_t)NL*128*128*2;
  unsigned short* mwh = (unsigned short*)w; w += 128*128*2;
  unsigned short* mwl = (unsigned short*)w; w += 128*128*2;

  const int nscan = (Nn + 255)/256;
  const int nrt = (Nn + 63)/64;
  const int grt = (G + 63)/64;

  // ---- CSR build ----
  hipMemsetAsync(deg, 0, (size_t)Nn*4, stream);
  hist_k<<<(E+255)/256, 256, 0, stream>>>(dstv, deg, E);
  scan_sum<<<nscan, 256, 0, stream>>>(deg, bsum, Nn);
  scan_blocksums<<<1, 512, 0, stream>>>(bsum, nscan);
  scan_final<<<nscan, 256, 0, stream>>>(deg, bsum, rp, cur, Nn, E);
  scatter_k<<<(E+255)/256, 256, 0, stream>>>(srcv, dstv, cur, ssorted, E);

  // ---- prep ----
  xprep<<<((Nn*64/4)+255)/256, 256, 0, stream>>>(x, xh, Nn*64/4);
  wprep<<<((64*128)+255)/256, 256, 0, stream>>>(W1, w1h, w1l, 64, 64*128);
  wprep<<<((NL*128*128)+255)/256, 256, 0, stream>>>(gW, gwh, gwl, 128, NL*128*128);
  wprep<<<((128*128)+255)/256, 256, 0, stream>>>(mW, mwh, mwl, 128, 128*128);

  // ---- lin1 + leaky_relu -> fp16 h ----
  gemm_mfma<2, 1, false, false><<<nrt, 256, 0, stream>>>(
      xh, w1h, w1l, b1, nullptr, nullptr, h16, nullptr, nullptr, Nn);

  // ---- 3 GAT layers ----
  for (int l = 0; l < NL; ++l){
    gemm_mfma<4, 2, true, true><<<nrt, 256, 0, stream>>>(
        h16, gwh + (size_t)l*128*128, gwl + (size_t)l*128*128, nullptr,
        g_asrc + l*128, g_adst + l*128, hsR, asN, adN, Nn);
    gat_agg<<<(Nn+3)/4, 256, 0, stream>>>(ssorted, rp, asN, adN,
        (const __half2*)hsR, g_b + l*128, (__half2*)h16, Nn);
  }

  // ---- readout ----
  pool_relu<<<G, 128, 0, stream>>>(h16, batch, poolh, Nn);
  gemm_mfma<4, 2, true, false><<<nrt, 256, 0, stream>>>(
      h16, mwh, mwl, nullptr, m_asrc, nullptr, hsR, asN, nullptr, Nn);   // hs2 + as2
  gemm_mfma<4, 0, true, false><<<grt, 256, 0, stream>>>(
      poolh, mwh, mwl, nullptr, m_adst, nullptr, nullptr, adN, nullptr, G); // ad2
  mol_agg<<<G, 128, 0, stream>>>(asN, adN, hsR, batch, m_b, W2, b2, (float*)d_out, Nn);
}

// Round 8
// 347.689 us; speedup vs baseline: 1.6194x; 1.0441x over previous
//
#include <hip/hip_runtime.h>
#include <hip/hip_fp16.h>
#include <math.h>
#include <stdint.h>

#define DEV __device__ __forceinline__

using f32x4 = __attribute__((ext_vector_type(4))) float;
using half8 = __attribute__((ext_vector_type(8))) _Float16;
typedef union { uint4 u; half8 h; } u4h8;

DEV float lrelu(float x){ return x > 0.f ? x : 0.01f*x; }
DEV float elu1(float x){ return x > 0.f ? x : __expf(x)-1.f; }

DEV int lower_bound_i(const int* __restrict__ a, int n, int key){
  int lo = 0, hi = n;
  while (lo < hi){ int mid = (lo+hi)>>1; if (a[mid] < key) lo = mid+1; else hi = mid; }
  return lo;
}

// ============ weight prep: W[K][128] f32 -> Wt_hi/Wt_lo(f16, lo x1024) [128][K] ============
__global__ void wprep(const float* __restrict__ W, unsigned short* __restrict__ Hi,
                      unsigned short* __restrict__ Lo, int K, int tot){
  int idx = blockIdx.x*256 + threadIdx.x;
  if (idx >= tot) return;
  int kn = K*128;
  int mat = idx / kn;
  int rem = idx - mat*kn;
  int k = rem >> 7;
  int n = rem & 127;
  float v = W[idx];
  __half h = __float2half_rn(v);
  float lo = (v - __half2float(h)) * 1024.f;
  size_t o = (size_t)mat*kn + (size_t)n*K + k;
  Hi[o] = __half_as_ushort(h);
  Lo[o] = __half_as_ushort(__float2half_rn(lo));
}

// ============ lin1 GEMM: h = lrelu(x[M,64] @ W1 + b1) -> fp16; x f32 converted in-kernel ============
__global__ __launch_bounds__(256, 3) void gemm_lin1(
    const float* __restrict__ X, const unsigned short* __restrict__ Wt_hi,
    const unsigned short* __restrict__ Wt_lo, const float* __restrict__ bias,
    unsigned short* __restrict__ Ch, int M)
{
  const int tid = threadIdx.x;
  const int lane = tid & 63;
  const int wv = tid >> 6;
  const int ml = lane & 15;
  const int kg = lane >> 4;
  const int R0 = blockIdx.x * 64;

  __shared__ uint32_t sA[2][1024];   // 2 subchunks [64 rows][32 k] fp16, swizzled
  __shared__ float sC[4][32][36];

  const unsigned short* bhp[2];
  const unsigned short* blp[2];
  #pragma unroll
  for (int nt = 0; nt < 2; ++nt){
    int n = wv*32 + nt*16 + ml;
    bhp[nt] = Wt_hi + (size_t)n*64 + kg*8;
    blp[nt] = Wt_lo + (size_t)n*64 + kg*8;
  }

  // stage + convert: thread t -> row t>>2, k-quarter t&3 (16 k)
  {
    int row = tid >> 2, kq = tid & 3;
    int gr = R0 + row; gr = gr < M ? gr : M-1;
    const float4* xp = (const float4*)(X + (size_t)gr*64 + kq*16);
    int sub = kq >> 1;
    #pragma unroll
    for (int i = 0; i < 4; ++i){
      float4 v = xp[i];
      __half2 h0 = __floats2half2_rn(v.x, v.y);
      __half2 h1 = __floats2half2_rn(v.z, v.w);
      int slot = (kq & 1)*2 + (i >> 1);
      int slot_s = slot ^ ((row >> 1) & 3);
      int byte = row*64 + slot_s*16 + (i & 1)*8;
      *(uint2*)((char*)&sA[sub][0] + byte) = make_uint2(*(uint32_t*)&h0, *(uint32_t*)&h1);
    }
  }
  __syncthreads();

  f32x4 accH[4][2], accL[4][2];
  #pragma unroll
  for (int mt = 0; mt < 4; ++mt)
    #pragma unroll
    for (int nt = 0; nt < 2; ++nt){
      accH[mt][nt] = (f32x4){0.f,0.f,0.f,0.f};
      accL[mt][nt] = (f32x4){0.f,0.f,0.f,0.f};
    }

  #pragma unroll
  for (int sc = 0; sc < 2; ++sc){
    u4h8 bh[2], bl[2];
    #pragma unroll
    for (int nt = 0; nt < 2; ++nt){
      bh[nt].u = *(const uint4*)(bhp[nt] + sc*32);
      bl[nt].u = *(const uint4*)(blp[nt] + sc*32);
    }
    const char* buf = (const char*)&sA[sc][0];
    #pragma unroll
    for (int mt = 0; mt < 4; ++mt){
      int row = mt*16 + ml;
      int ba = row*64 + ((kg ^ ((row >> 1) & 3)) * 16);
      u4h8 A_;
      A_.u = *(const uint4*)(buf + ba);
      #pragma unroll
      for (int nt = 0; nt < 2; ++nt){
        accH[mt][nt] = __builtin_amdgcn_mfma_f32_16x16x32_f16(A_.h, bh[nt].h, accH[mt][nt], 0, 0, 0);
        accL[mt][nt] = __builtin_amdgcn_mfma_f32_16x16x32_f16(A_.h, bl[nt].h, accL[mt][nt], 0, 0, 0);
      }
    }
  }

  float bv[2] = { bias[wv*32 + ml], bias[wv*32 + 16 + ml] };
  #pragma unroll
  for (int p = 0; p < 2; ++p){
    #pragma unroll
    for (int mh = 0; mh < 2; ++mh){
      int mt = p*2 + mh;
      #pragma unroll
      for (int nt = 0; nt < 2; ++nt){
        #pragma unroll
        for (int r = 0; r < 4; ++r){
          float v = accH[mt][nt][r] + accL[mt][nt][r] * 9.765625e-4f;
          v = lrelu(v + bv[nt]);
          sC[wv][mh*16 + kg*4 + r][nt*16 + ml] = v;
        }
      }
    }
    __syncthreads();
    #pragma unroll
    for (int j = 0; j < 4; ++j){
      int row_l = j*8 + (lane >> 3);
      int c4 = (lane & 7) * 4;
      int grow = R0 + p*32 + row_l;
      if (grow < M){
        float4 v = *(const float4*)&sC[wv][row_l][c4];
        int gcol = wv*32 + c4;
        __half2 h0 = __floats2half2_rn(v.x, v.y);
        __half2 h1 = __floats2half2_rn(v.z, v.w);
        *(uint2*)(Ch + (size_t)grow*128 + gcol) = make_uint2(*(uint32_t*)&h0, *(uint32_t*)&h1);
      }
    }
    __syncthreads();
  }
}

// ============ main MFMA GEMM: C[M,128] = A[M,128] @ W, f16 dual-acc ============
// K=128 in 2 chunks of 64 (2 x 4KB subchunks each) -> 2 barriers total.
// A staged via global_load_lds(16B); swizzle t^((row>>1)&3) pre-applied on source.
// OUTMODE: 0 none, 2 fp16 raw. Fused dots: outa = C . va, outb = C . vb.
template<int OUTMODE, bool DOTA, bool DOTB>
__global__ __launch_bounds__(256, 3) void gemm_mfma(
    const unsigned short* __restrict__ Ah, const unsigned short* __restrict__ Wt_hi,
    const unsigned short* __restrict__ Wt_lo,
    const float* __restrict__ va, const float* __restrict__ vb,
    unsigned short* __restrict__ Ch,
    float* __restrict__ outa, float* __restrict__ outb, int M)
{
  constexpr int K = 128;
  const int tid = threadIdx.x;
  const int lane = tid & 63;
  const int wv = tid >> 6;
  const int ml = lane & 15;
  const int kg = lane >> 4;
  const int R0 = blockIdx.x * 64;

  __shared__ uint32_t sA[4][1024];   // 4 subchunks of 4KB (2 chunks of 64k, dbuf)
  __shared__ float sC[4][32][36];
  __shared__ float sd[4][64][2];

  const unsigned short* bhp[2];
  const unsigned short* blp[2];
  #pragma unroll
  for (int nt = 0; nt < 2; ++nt){
    int n = wv*32 + nt*16 + ml;
    bhp[nt] = Wt_hi + (size_t)n*K + kg*8;
    blp[nt] = Wt_lo + (size_t)n*K + kg*8;
  }

  auto STAGE = [&](int ch){
    #pragma unroll
    for (int j = 0; j < 2; ++j){
      int sc = ch*2 + j;
      int o = tid*16;
      int row = o >> 6;
      int t = (o >> 4) & 3;
      int gr = R0 + row; gr = gr < M ? gr : M-1;
      int jj = t ^ ((row >> 1) & 3);
      const char* src = (const char*)(Ah + (size_t)gr*K + sc*32 + jj*8);
      char* dst = (char*)(&sA[(ch & 1)*2 + j][0]) + wv*1024;
      __builtin_amdgcn_global_load_lds(
          (const __attribute__((address_space(1))) void*)src,
          (__attribute__((address_space(3))) void*)dst, 16, 0, 0);
    }
  };

  f32x4 accH[4][2], accL[4][2];
  #pragma unroll
  for (int mt = 0; mt < 4; ++mt)
    #pragma unroll
    for (int nt = 0; nt < 2; ++nt){
      accH[mt][nt] = (f32x4){0.f,0.f,0.f,0.f};
      accL[mt][nt] = (f32x4){0.f,0.f,0.f,0.f};
    }

  STAGE(0);
  u4h8 bh[2][2], bl[2][2];    // [ksub][nt]
  #pragma unroll
  for (int j = 0; j < 2; ++j)
    #pragma unroll
    for (int nt = 0; nt < 2; ++nt){
      bh[j][nt].u = *(const uint4*)(bhp[nt] + j*32);
      bl[j][nt].u = *(const uint4*)(blp[nt] + j*32);
    }
  __syncthreads();

  #pragma unroll
  for (int ch = 0; ch < 2; ++ch){
    u4h8 bhN[2][2], blN[2][2];
    if (ch == 0){
      STAGE(1);
      #pragma unroll
      for (int j = 0; j < 2; ++j)
        #pragma unroll
        for (int nt = 0; nt < 2; ++nt){
          bhN[j][nt].u = *(const uint4*)(bhp[nt] + (2 + j)*32);
          blN[j][nt].u = *(const uint4*)(blp[nt] + (2 + j)*32);
        }
    }
    #pragma unroll
    for (int js = 0; js < 2; ++js){
      const char* buf = (const char*)&sA[(ch & 1)*2 + js][0];
      #pragma unroll
      for (int mt = 0; mt < 4; ++mt){
        int row = mt*16 + ml;
        int ba = row*64 + ((kg ^ ((row >> 1) & 3)) * 16);
        u4h8 A_;
        A_.u = *(const uint4*)(buf + ba);
        #pragma unroll
        for (int nt = 0; nt < 2; ++nt){
          accH[mt][nt] = __builtin_amdgcn_mfma_f32_16x16x32_f16(A_.h, bh[js][nt].h, accH[mt][nt], 0, 0, 0);
          accL[mt][nt] = __builtin_amdgcn_mfma_f32_16x16x32_f16(A_.h, bl[js][nt].h, accL[mt][nt], 0, 0, 0);
        }
      }
    }
    __syncthreads();
    if (ch == 0){
      #pragma unroll
      for (int j = 0; j < 2; ++j)
        #pragma unroll
        for (int nt = 0; nt < 2; ++nt){ bh[j][nt] = bhN[j][nt]; bl[j][nt] = blN[j][nt]; }
    }
  }

  // combine hi + lo/1024
  #pragma unroll
  for (int mt = 0; mt < 4; ++mt)
    #pragma unroll
    for (int nt = 0; nt < 2; ++nt)
      accH[mt][nt] = accH[mt][nt] + accL[mt][nt] * 9.765625e-4f;

  if constexpr (DOTA || DOTB){
    float vaL[2] = {0.f,0.f}, vbL[2] = {0.f,0.f};
    if constexpr (DOTA){ vaL[0] = va[wv*32 + ml]; vaL[1] = va[wv*32 + 16 + ml]; }
    if constexpr (DOTB){ vbL[0] = vb[wv*32 + ml]; vbL[1] = vb[wv*32 + 16 + ml]; }
    #pragma unroll
    for (int mt = 0; mt < 4; ++mt){
      #pragma unroll
      for (int r = 0; r < 4; ++r){
        float pa = 0.f, pb = 0.f;
        #pragma unroll
        for (int nt = 0; nt < 2; ++nt){
          float v = accH[mt][nt][r];
          if constexpr (DOTA) pa = fmaf(v, vaL[nt], pa);
          if constexpr (DOTB) pb = fmaf(v, vbL[nt], pb);
        }
        #pragma unroll
        for (int o = 8; o; o >>= 1){
          if constexpr (DOTA) pa += __shfl_xor(pa, o, 64);
          if constexpr (DOTB) pb += __shfl_xor(pb, o, 64);
        }
        if (ml == 0){
          int rl = mt*16 + kg*4 + r;
          sd[wv][rl][0] = pa;
          sd[wv][rl][1] = pb;
        }
      }
    }
    __syncthreads();
    if (tid < 64){
      int row = R0 + tid;
      if (row < M){
        if constexpr (DOTA)
          outa[row] = sd[0][tid][0] + sd[1][tid][0] + sd[2][tid][0] + sd[3][tid][0];
        if constexpr (DOTB)
          outb[row] = sd[0][tid][1] + sd[1][tid][1] + sd[2][tid][1] + sd[3][tid][1];
      }
    }
  }

  if constexpr (OUTMODE == 2){
    if constexpr (DOTA || DOTB) __syncthreads();
    #pragma unroll
    for (int p = 0; p < 2; ++p){
      #pragma unroll
      for (int mh = 0; mh < 2; ++mh){
        int mt = p*2 + mh;
        #pragma unroll
        for (int nt = 0; nt < 2; ++nt){
          #pragma unroll
          for (int r = 0; r < 4; ++r)
            sC[wv][mh*16 + kg*4 + r][nt*16 + ml] = accH[mt][nt][r];
        }
      }
      __syncthreads();
      #pragma unroll
      for (int j = 0; j < 4; ++j){
        int row_l = j*8 + (lane >> 3);
        int c4 = (lane & 7) * 4;
        int grow = R0 + p*32 + row_l;
        if (grow < M){
          float4 v = *(const float4*)&sC[wv][row_l][c4];
          int gcol = wv*32 + c4;
          __half2 h0 = __floats2half2_rn(v.x, v.y);
          __half2 h1 = __floats2half2_rn(v.z, v.w);
          *(uint2*)(Ch + (size_t)grow*128 + gcol) = make_uint2(*(uint32_t*)&h0, *(uint32_t*)&h1);
        }
      }
      __syncthreads();
    }
  }
}

// ============ CSR build ============
__global__ void hist_k(const int* __restrict__ dstv, int* __restrict__ deg, int E){
  int e = blockIdx.x*256 + threadIdx.x;
  if (e < E) atomicAdd(&deg[dstv[e]], 1);
}

__global__ void scan_sum(const int* __restrict__ deg, int* __restrict__ bsum, int n){
  __shared__ int s4[4];
  int i = blockIdx.x*256 + threadIdx.x;
  int v = (i < n) ? deg[i] : 0;
  #pragma unroll
  for (int o = 32; o; o >>= 1) v += __shfl_down(v, o, 64);
  if ((threadIdx.x & 63) == 0) s4[threadIdx.x >> 6] = v;
  __syncthreads();
  if (threadIdx.x == 0) bsum[blockIdx.x] = s4[0]+s4[1]+s4[2]+s4[3];
}

__global__ void scan_blocksums(int* __restrict__ bsum, int nb){
  __shared__ int s[512];
  int t = threadIdx.x;
  s[t] = (t < nb) ? bsum[t] : 0;
  __syncthreads();
  for (int o = 1; o < 512; o <<= 1){
    int v = s[t];
    int u = (t >= o) ? s[t-o] : 0;
    __syncthreads();
    s[t] = v + u;
    __syncthreads();
  }
  if (t < nb) bsum[t] = t ? s[t-1] : 0;
}

__global__ void scan_final(const int* __restrict__ deg, const int* __restrict__ boff,
    int* __restrict__ rp, int* __restrict__ cur, int n, int E)
{
  __shared__ int wsum[4];
  int i = blockIdx.x*256 + threadIdx.x;
  int lane = threadIdx.x & 63, wv = threadIdx.x >> 6;
  int v = (i < n) ? deg[i] : 0;
  int inc = v;
  #pragma unroll
  for (int o = 1; o < 64; o <<= 1){
    int u = __shfl_up(inc, o, 64);
    if (lane >= o) inc += u;
  }
  if (lane == 63) wsum[wv] = inc;
  __syncthreads();
  int woff = boff[blockIdx.x];
  for (int wq = 0; wq < wv; ++wq) woff += wsum[wq];
  int excl = woff + inc - v;
  if (i < n){ rp[i] = excl; cur[i] = excl; }
  if (blockIdx.x == 0 && threadIdx.x == 0) rp[n] = E;
}

__global__ void scatter_k(const int* __restrict__ srcv, const int* __restrict__ dstv,
                          int* __restrict__ cur, int* __restrict__ ssorted, int E){
  int e = blockIdx.x*256 + threadIdx.x;
  if (e < E){
    int p = atomicAdd(&cur[dstv[e]], 1);
    ssorted[p] = srcv[e];
  }
}

// ============ fused segment softmax + aggregation (one wave per dst node) ============
// readlane-based gather: alpha/sid broadcast via SGPR (no ds_bpermute), SGPR-base loads.
DEV void gstep(const __half2* __restrict__ hs16, int lane, float alpha, int sid, int i,
               float& a0, float& a1){
  float al = __uint_as_float(__builtin_amdgcn_readlane(__float_as_uint(alpha), i));
  int sd = __builtin_amdgcn_readlane(sid, i);
  float2 f = __half22float2(hs16[(size_t)sd*64 + lane]);
  a0 = fmaf(al, f.x, a0);
  a1 = fmaf(al, f.y, a1);
}

__global__ __launch_bounds__(256) void gat_agg(const int* __restrict__ ssorted,
    const int* __restrict__ rp,
    const float* __restrict__ asn, const float* __restrict__ adn,
    const __half2* __restrict__ hs16, const float* __restrict__ bias,
    __half2* __restrict__ outp, int Nn)
{
  const int lane = threadIdx.x & 63;
  const int wv = threadIdx.x >> 6;
  const int d = blockIdx.x*4 + wv;
  if (d >= Nn) return;
  const int lo = rp[d], hi = rp[d+1];
  const int deg = hi - lo;
  float acc0 = 0.f, acc1 = 0.f;
  if (deg > 0){
    const float ad = adn[d];
    if (deg <= 64){
      int sid = 0; float lg = -1e30f;
      if (lane < deg){
        sid = ssorted[lo + lane];
        lg = lrelu(asn[sid] + ad);
      }
      float m = lg;
      if (deg <= 8){
        if (deg > 4) m = fmaxf(m, __shfl_xor(m, 4, 64));
        m = fmaxf(m, __shfl_xor(m, 2, 64));
        m = fmaxf(m, __shfl_xor(m, 1, 64));
        float p = (lane < deg) ? __expf(lg - m) : 0.f;
        float s = p;
        if (deg > 4) s += __shfl_xor(s, 4, 64);
        s += __shfl_xor(s, 2, 64);
        s += __shfl_xor(s, 1, 64);
        float alpha = p * (1.f / (s + 1e-16f));
        gstep(hs16, lane, alpha, sid, 0, acc0, acc1);
        gstep(hs16, lane, alpha, sid, 1, acc0, acc1);
        gstep(hs16, lane, alpha, sid, 2, acc0, acc1);
        gstep(hs16, lane, alpha, sid, 3, acc0, acc1);
        if (deg > 4){
          gstep(hs16, lane, alpha, sid, 4, acc0, acc1);
          gstep(hs16, lane, alpha, sid, 5, acc0, acc1);
          gstep(hs16, lane, alpha, sid, 6, acc0, acc1);
          gstep(hs16, lane, alpha, sid, 7, acc0, acc1);
        }
      } else {
        #pragma unroll
        for (int o = 32; o; o >>= 1) m = fmaxf(m, __shfl_xor(m, o, 64));
        float p = (lane < deg) ? __expf(lg - m) : 0.f;
        float s = p;
        #pragma unroll
        for (int o = 32; o; o >>= 1) s += __shfl_xor(s, o, 64);
        float alpha = p * (1.f / (s + 1e-16f));
        for (int base = 0; base < deg; base += 8){
          #pragma unroll
          for (int i = 0; i < 8; ++i)
            gstep(hs16, lane, alpha, sid, base + i, acc0, acc1);
        }
      }
    } else {
      float m = -1e30f;
      for (int e = lane; e < deg; e += 64){
        int sid = ssorted[lo+e];
        m = fmaxf(m, lrelu(asn[sid] + ad));
      }
      #pragma unroll
      for (int o = 32; o; o >>= 1) m = fmaxf(m, __shfl_xor(m, o, 64));
      float s = 0.f;
      for (int e = lane; e < deg; e += 64){
        int sid = ssorted[lo+e];
        s += __expf(lrelu(asn[sid] + ad) - m);
      }
      #pragma unroll
      for (int o = 32; o; o >>= 1) s += __shfl_xor(s, o, 64);
      float inv = 1.f / (s + 1e-16f);
      for (int e = 0; e < deg; ++e){
        int sid = ssorted[lo+e];
        float a = __expf(lrelu(asn[sid] + ad) - m) * inv;
        float2 f = __half22float2(hs16[(size_t)sid*64 + lane]);
        acc0 = fmaf(a, f.x, acc0);
        acc1 = fmaf(a, f.y, acc1);
      }
    }
  }
  float2 bb = *(const float2*)(bias + lane*2);
  outp[(size_t)d*64 + lane] = __floats2half2_rn(elu1(acc0 + bb.x), elu1(acc1 + bb.y));
}

// ============ graph pooling: fp16 rows -> fp16 pooled rows (written into h16 tail) ============
__global__ __launch_bounds__(128) void pool_relu(const unsigned short* __restrict__ h16,
    const int* __restrict__ batch, unsigned short* __restrict__ ptail, int Nn)
{
  const int g = blockIdx.x;
  const int c = threadIdx.x;
  __shared__ int sb[2];
  if (c < 2) sb[c] = lower_bound_i(batch, Nn, g + c);
  __syncthreads();
  const int lo = sb[0], hi = sb[1];
  float s = 0.f;
  for (int i = lo; i < hi; ++i)
    s += __half2float(__ushort_as_half(h16[(size_t)i*128 + c]));
  ptail[(size_t)g*128 + c] = __half_as_ushort(__float2half_rn(fmaxf(s, 0.f)));
}

// ============ molecular GAT aggregate + final linear (fused) ============
__global__ __launch_bounds__(128) void mol_agg(const float* __restrict__ as2,
    const float* __restrict__ ad2, const unsigned short* __restrict__ hs2,
    const int* __restrict__ batch, const float* __restrict__ bias,
    const float* __restrict__ W2, const float* __restrict__ b2,
    float* __restrict__ out, int Nn)
{
  const int g = blockIdx.x;
  const int c = threadIdx.x;
  __shared__ int sb[2];
  __shared__ float red[2];
  if (c < 2) sb[c] = lower_bound_i(batch, Nn, g + c);
  __syncthreads();
  const int lo = sb[0], hi = sb[1];
  const float ad = ad2[g];

  float mt = -1e30f;
  for (int i = lo + c; i < hi; i += 128) mt = fmaxf(mt, lrelu(as2[i] + ad));
  #pragma unroll
  for (int o = 32; o; o >>= 1) mt = fmaxf(mt, __shfl_xor(mt, o, 64));
  if ((c & 63) == 0) red[c >> 6] = mt;
  __syncthreads();
  const float m = fmaxf(red[0], red[1]);

  float st = 0.f;
  for (int i = lo + c; i < hi; i += 128) st += __expf(lrelu(as2[i] + ad) - m);
  #pragma unroll
  for (int o = 32; o; o >>= 1) st += __shfl_xor(st, o, 64);
  __syncthreads();
  if ((c & 63) == 0) red[c >> 6] = st;
  __syncthreads();
  const float inv = 1.f / (red[0] + red[1] + 1e-16f);

  float acc = 0.f;
  for (int i = lo; i < hi; ++i){
    float wgt = __expf(lrelu(as2[i] + ad) - m) * inv;
    acc = fmaf(wgt, __half2float(__ushort_as_half(hs2[(size_t)i*128 + c])), acc);
  }
  float v = elu1(acc + bias[c]);

  float r = v * W2[c];
  #pragma unroll
  for (int o = 32; o; o >>= 1) r += __shfl_xor(r, o, 64);
  __syncthreads();
  if ((c & 63) == 0) red[c >> 6] = r;
  __syncthreads();
  if (c == 0) out[g] = red[0] + red[1] + b2[0];
}

extern "C" void kernel_launch(void* const* d_in, const int* in_sizes, int n_in,
                              void* d_out, int out_size, void* d_ws, size_t ws_size,
                              hipStream_t stream)
{
  const float* x      = (const float*)d_in[0];
  const int*   ei     = (const int*)  d_in[1];
  const int*   batch  = (const int*)  d_in[2];
  const float* W1     = (const float*)d_in[3];
  const float* b1     = (const float*)d_in[4];
  const float* gW     = (const float*)d_in[5];
  const float* g_asrc = (const float*)d_in[6];
  const float* g_adst = (const float*)d_in[7];
  const float* g_b    = (const float*)d_in[8];
  const float* mW     = (const float*)d_in[9];
  const float* m_asrc = (const float*)d_in[10];
  const float* m_adst = (const float*)d_in[11];
  const float* m_b    = (const float*)d_in[12];
  const float* W2     = (const float*)d_in[13];
  const float* b2     = (const float*)d_in[14];

  const int Nn = in_sizes[0] / 64;            // 100000
  const int E  = in_sizes[1] / 2;             // 400000
  const int G  = out_size;                    // 5000
  const int NL = in_sizes[5] / (128*128);     // 3
  const int M2 = Nn + G;                      // merged readout rows
  const int* srcv = ei;
  const int* dstv = ei + E;

  char* w = (char*)d_ws;
  unsigned short* h16 = (unsigned short*)w; w += (size_t)(M2+64)*128*2;  // h + pooled tail
  unsigned short* hsR = (unsigned short*)w; w += (size_t)(M2+64)*128*2;  // per-layer hs / hs2+hd2
  float* asO      = (float*)w; w += (size_t)(M2+64)*4;
  float* adO      = (float*)w; w += (size_t)(M2+64)*4;
  int*   deg      = (int*)w;   w += (size_t)Nn*4;
  int*   rp       = (int*)w;   w += (size_t)(Nn+64)*4;
  int*   cur      = (int*)w;   w += (size_t)Nn*4;
  int*   ssorted  = (int*)w;   w += (size_t)E*4;
  int*   bsum     = (int*)w;   w += 4096;
  unsigned short* w1h = (unsigned short*)w; w += 64*128*2;
  unsigned short* w1l = (unsigned short*)w; w += 64*128*2;
  unsigned short* gwh = (unsigned short*)w; w += (size_t)NL*128*128*2;
  unsigned short* gwl = (unsigned short*)w; w += (size_t)NL*128*128*2;
  unsigned short* mwh = (unsigned short*)w; w += 128*128*2;
  unsigned short* mwl = (unsigned short*)w; w += 128*128*2;

  const int nscan = (Nn + 255)/256;
  const int nrt = (Nn + 63)/64;
  const int mrt = (M2 + 63)/64;

  // ---- CSR build ----
  hipMemsetAsync(deg, 0, (size_t)Nn*4, stream);
  hist_k<<<(E+255)/256, 256, 0, stream>>>(dstv, deg, E);
  scan_sum<<<nscan, 256, 0, stream>>>(deg, bsum, Nn);
  scan_blocksums<<<1, 512, 0, stream>>>(bsum, nscan);
  scan_final<<<nscan, 256, 0, stream>>>(deg, bsum, rp, cur, Nn, E);
  scatter_k<<<(E+255)/256, 256, 0, stream>>>(srcv, dstv, cur, ssorted, E);

  // ---- weight prep ----
  wprep<<<((64*128)+255)/256, 256, 0, stream>>>(W1, w1h, w1l, 64, 64*128);
  wprep<<<((NL*128*128)+255)/256, 256, 0, stream>>>(gW, gwh, gwl, 128, NL*128*128);
  wprep<<<((128*128)+255)/256, 256, 0, stream>>>(mW, mwh, mwl, 128, 128*128);

  // ---- lin1 (f32 in, fp16 out, fused convert) ----
  gemm_lin1<<<nrt, 256, 0, stream>>>(x, w1h, w1l, b1, h16, Nn);

  // ---- 3 GAT layers ----
  for (int l = 0; l < NL; ++l){
    gemm_mfma<2, true, true><<<nrt, 256, 0, stream>>>(
        h16, gwh + (size_t)l*128*128, gwl + (size_t)l*128*128,
        g_asrc + l*128, g_adst + l*128, hsR, asO, adO, Nn);
    gat_agg<<<(Nn+3)/4, 256, 0, stream>>>(ssorted, rp, asO, adO,
        (const __half2*)hsR, g_b + l*128, (__half2*)h16, Nn);
  }

  // ---- readout: pool into h16 tail, one merged GEMM (hs2+as2 / hd2+ad2) ----
  pool_relu<<<G, 128, 0, stream>>>(h16, batch, h16 + (size_t)Nn*128, Nn);
  gemm_mfma<2, true, true><<<mrt, 256, 0, stream>>>(
      h16, mwh, mwl, m_asrc, m_adst, hsR, asO, adO, M2);
  mol_agg<<<G, 128, 0, stream>>>(asO, adO + Nn, hsR, batch, m_b, W2, b2, (float*)d_out, Nn);
}

// Round 9
// 318.086 us; speedup vs baseline: 1.7701x; 1.0931x over previous
//
#include <hip/hip_runtime.h>
#include <hip/hip_fp16.h>
#include <math.h>
#include <stdint.h>

#define DEV __device__ __forceinline__

using f32x4 = __attribute__((ext_vector_type(4))) float;
using half8 = __attribute__((ext_vector_type(8))) _Float16;
typedef union { uint4 u; half8 h; } u4h8;

DEV float lrelu(float x){ return x > 0.f ? x : 0.01f*x; }
DEV float elu1(float x){ return x > 0.f ? x : __expf(x)-1.f; }

DEV int lower_bound_i(const int* __restrict__ a, int n, int key){
  int lo = 0, hi = n;
  while (lo < hi){ int mid = (lo+hi)>>1; if (a[mid] < key) lo = mid+1; else hi = mid; }
  return lo;
}

// ============ combined prep: all weight splits + zero CSR/scan state ============
DEV void wsplit(float v, unsigned short* __restrict__ H, unsigned short* __restrict__ L, size_t o){
  __half h = __float2half_rn(v);
  float lo = (v - __half2float(h)) * 1024.f;
  H[o] = __half_as_ushort(h);
  L[o] = __half_as_ushort(__float2half_rn(lo));
}

__global__ void wprep_all(const float* __restrict__ W1, const float* __restrict__ gW,
    const float* __restrict__ mW,
    unsigned short* __restrict__ w1h, unsigned short* __restrict__ w1l,
    unsigned short* __restrict__ gwh, unsigned short* __restrict__ gwl,
    unsigned short* __restrict__ mwh, unsigned short* __restrict__ mwl,
    int* __restrict__ deg, unsigned long long* __restrict__ bstat,
    int* __restrict__ bctr, int Nn, int nG, int nscan)
{
  int i = blockIdx.x*256 + threadIdx.x;
  if (i < Nn) deg[i] = 0;
  if (i < nscan) bstat[i] = 0ull;
  if (i == 0) *bctr = 0;
  if (i < 8192){                       // W1 [64][128] -> [128][64]
    int k = i >> 7, n = i & 127;
    wsplit(W1[i], w1h, w1l, (size_t)n*64 + k);
  }
  if (i < nG){                         // gW [NL][128][128] -> [NL][128][128]T
    int mat = i >> 14; int rem = i & 16383;
    int k = rem >> 7, n = rem & 127;
    wsplit(gW[i], gwh, gwl, (size_t)mat*16384 + (size_t)n*128 + k);
  }
  if (i < 16384){                      // mW
    int k = i >> 7, n = i & 127;
    wsplit(mW[i], mwh, mwl, (size_t)n*128 + k);
  }
}

// ============ lin1 GEMM: h = lrelu(x[M,64] @ W1 + b1) -> fp16 (x converted in-kernel) ============
__global__ __launch_bounds__(256, 3) void gemm_lin1(
    const float* __restrict__ X, const unsigned short* __restrict__ Wt_hi,
    const unsigned short* __restrict__ Wt_lo, const float* __restrict__ bias,
    unsigned short* __restrict__ Ch, int M)
{
  const int tid = threadIdx.x;
  const int lane = tid & 63;
  const int wv = tid >> 6;
  const int ml = lane & 15;
  const int kg = lane >> 4;
  const int R0 = blockIdx.x * 64;

  __shared__ uint32_t sA[2][1024];
  __shared__ float sC[4][32][36];

  const unsigned short* bhp[2];
  const unsigned short* blp[2];
  #pragma unroll
  for (int nt = 0; nt < 2; ++nt){
    int n = wv*32 + nt*16 + ml;
    bhp[nt] = Wt_hi + (size_t)n*64 + kg*8;
    blp[nt] = Wt_lo + (size_t)n*64 + kg*8;
  }

  {
    int row = tid >> 2, kq = tid & 3;
    int gr = R0 + row; gr = gr < M ? gr : M-1;
    const float4* xp = (const float4*)(X + (size_t)gr*64 + kq*16);
    int sub = kq >> 1;
    #pragma unroll
    for (int i = 0; i < 4; ++i){
      float4 v = xp[i];
      __half2 h0 = __floats2half2_rn(v.x, v.y);
      __half2 h1 = __floats2half2_rn(v.z, v.w);
      int slot = (kq & 1)*2 + (i >> 1);
      int slot_s = slot ^ ((row >> 1) & 3);
      int byte = row*64 + slot_s*16 + (i & 1)*8;
      *(uint2*)((char*)&sA[sub][0] + byte) = make_uint2(*(uint32_t*)&h0, *(uint32_t*)&h1);
    }
  }
  __syncthreads();

  f32x4 accH[4][2], accL[4][2];
  #pragma unroll
  for (int mt = 0; mt < 4; ++mt)
    #pragma unroll
    for (int nt = 0; nt < 2; ++nt){
      accH[mt][nt] = (f32x4){0.f,0.f,0.f,0.f};
      accL[mt][nt] = (f32x4){0.f,0.f,0.f,0.f};
    }

  #pragma unroll
  for (int sc = 0; sc < 2; ++sc){
    u4h8 bh[2], bl[2];
    #pragma unroll
    for (int nt = 0; nt < 2; ++nt){
      bh[nt].u = *(const uint4*)(bhp[nt] + sc*32);
      bl[nt].u = *(const uint4*)(blp[nt] + sc*32);
    }
    const char* buf = (const char*)&sA[sc][0];
    #pragma unroll
    for (int mt = 0; mt < 4; ++mt){
      int row = mt*16 + ml;
      int ba = row*64 + ((kg ^ ((row >> 1) & 3)) * 16);
      u4h8 A_;
      A_.u = *(const uint4*)(buf + ba);
      #pragma unroll
      for (int nt = 0; nt < 2; ++nt){
        accH[mt][nt] = __builtin_amdgcn_mfma_f32_16x16x32_f16(A_.h, bh[nt].h, accH[mt][nt], 0, 0, 0);
        accL[mt][nt] = __builtin_amdgcn_mfma_f32_16x16x32_f16(A_.h, bl[nt].h, accL[mt][nt], 0, 0, 0);
      }
    }
  }

  float bv[2] = { bias[wv*32 + ml], bias[wv*32 + 16 + ml] };
  #pragma unroll
  for (int p = 0; p < 2; ++p){
    #pragma unroll
    for (int mh = 0; mh < 2; ++mh){
      int mt = p*2 + mh;
      #pragma unroll
      for (int nt = 0; nt < 2; ++nt){
        #pragma unroll
        for (int r = 0; r < 4; ++r){
          float v = accH[mt][nt][r] + accL[mt][nt][r] * 9.765625e-4f;
          v = lrelu(v + bv[nt]);
          sC[wv][mh*16 + kg*4 + r][nt*16 + ml] = v;
        }
      }
    }
    __syncthreads();
    #pragma unroll
    for (int j = 0; j < 4; ++j){
      int row_l = j*8 + (lane >> 3);
      int c4 = (lane & 7) * 4;
      int grow = R0 + p*32 + row_l;
      if (grow < M){
        float4 v = *(const float4*)&sC[wv][row_l][c4];
        int gcol = wv*32 + c4;
        __half2 h0 = __floats2half2_rn(v.x, v.y);
        __half2 h1 = __floats2half2_rn(v.z, v.w);
        *(uint2*)(Ch + (size_t)grow*128 + gcol) = make_uint2(*(uint32_t*)&h0, *(uint32_t*)&h1);
      }
    }
    __syncthreads();
  }
}

// ============ main MFMA GEMM: C[M,128] = A[M,128] @ W, f16 dual-acc ============
template<int OUTMODE, bool DOTA, bool DOTB>
__global__ __launch_bounds__(256, 3) void gemm_mfma(
    const unsigned short* __restrict__ Ah, const unsigned short* __restrict__ Wt_hi,
    const unsigned short* __restrict__ Wt_lo,
    const float* __restrict__ va, const float* __restrict__ vb,
    unsigned short* __restrict__ Ch,
    float* __restrict__ outa, float* __restrict__ outb, int M)
{
  constexpr int K = 128;
  const int tid = threadIdx.x;
  const int lane = tid & 63;
  const int wv = tid >> 6;
  const int ml = lane & 15;
  const int kg = lane >> 4;
  const int R0 = blockIdx.x * 64;

  __shared__ uint32_t sA[4][1024];
  __shared__ float sC[4][32][36];
  __shared__ float sd[4][64][2];

  const unsigned short* bhp[2];
  const unsigned short* blp[2];
  #pragma unroll
  for (int nt = 0; nt < 2; ++nt){
    int n = wv*32 + nt*16 + ml;
    bhp[nt] = Wt_hi + (size_t)n*K + kg*8;
    blp[nt] = Wt_lo + (size_t)n*K + kg*8;
  }

  auto STAGE = [&](int ch){
    #pragma unroll
    for (int j = 0; j < 2; ++j){
      int sc = ch*2 + j;
      int o = tid*16;
      int row = o >> 6;
      int t = (o >> 4) & 3;
      int gr = R0 + row; gr = gr < M ? gr : M-1;
      int jj = t ^ ((row >> 1) & 3);
      const char* src = (const char*)(Ah + (size_t)gr*K + sc*32 + jj*8);
      char* dst = (char*)(&sA[(ch & 1)*2 + j][0]) + wv*1024;
      __builtin_amdgcn_global_load_lds(
          (const __attribute__((address_space(1))) void*)src,
          (__attribute__((address_space(3))) void*)dst, 16, 0, 0);
    }
  };

  f32x4 accH[4][2], accL[4][2];
  #pragma unroll
  for (int mt = 0; mt < 4; ++mt)
    #pragma unroll
    for (int nt = 0; nt < 2; ++nt){
      accH[mt][nt] = (f32x4){0.f,0.f,0.f,0.f};
      accL[mt][nt] = (f32x4){0.f,0.f,0.f,0.f};
    }

  STAGE(0);
  u4h8 bh[2][2], bl[2][2];
  #pragma unroll
  for (int j = 0; j < 2; ++j)
    #pragma unroll
    for (int nt = 0; nt < 2; ++nt){
      bh[j][nt].u = *(const uint4*)(bhp[nt] + j*32);
      bl[j][nt].u = *(const uint4*)(blp[nt] + j*32);
    }
  __syncthreads();

  #pragma unroll
  for (int ch = 0; ch < 2; ++ch){
    u4h8 bhN[2][2], blN[2][2];
    if (ch == 0){
      STAGE(1);
      #pragma unroll
      for (int j = 0; j < 2; ++j)
        #pragma unroll
        for (int nt = 0; nt < 2; ++nt){
          bhN[j][nt].u = *(const uint4*)(bhp[nt] + (2 + j)*32);
          blN[j][nt].u = *(const uint4*)(blp[nt] + (2 + j)*32);
        }
    }
    #pragma unroll
    for (int js = 0; js < 2; ++js){
      const char* buf = (const char*)&sA[(ch & 1)*2 + js][0];
      #pragma unroll
      for (int mt = 0; mt < 4; ++mt){
        int row = mt*16 + ml;
        int ba = row*64 + ((kg ^ ((row >> 1) & 3)) * 16);
        u4h8 A_;
        A_.u = *(const uint4*)(buf + ba);
        #pragma unroll
        for (int nt = 0; nt < 2; ++nt){
          accH[mt][nt] = __builtin_amdgcn_mfma_f32_16x16x32_f16(A_.h, bh[js][nt].h, accH[mt][nt], 0, 0, 0);
          accL[mt][nt] = __builtin_amdgcn_mfma_f32_16x16x32_f16(A_.h, bl[js][nt].h, accL[mt][nt], 0, 0, 0);
        }
      }
    }
    __syncthreads();
    if (ch == 0){
      #pragma unroll
      for (int j = 0; j < 2; ++j)
        #pragma unroll
        for (int nt = 0; nt < 2; ++nt){ bh[j][nt] = bhN[j][nt]; bl[j][nt] = blN[j][nt]; }
    }
  }

  #pragma unroll
  for (int mt = 0; mt < 4; ++mt)
    #pragma unroll
    for (int nt = 0; nt < 2; ++nt)
      accH[mt][nt] = accH[mt][nt] + accL[mt][nt] * 9.765625e-4f;

  if constexpr (DOTA || DOTB){
    float vaL[2] = {0.f,0.f}, vbL[2] = {0.f,0.f};
    if constexpr (DOTA){ vaL[0] = va[wv*32 + ml]; vaL[1] = va[wv*32 + 16 + ml]; }
    if constexpr (DOTB){ vbL[0] = vb[wv*32 + ml]; vbL[1] = vb[wv*32 + 16 + ml]; }
    #pragma unroll
    for (int mt = 0; mt < 4; ++mt){
      #pragma unroll
      for (int r = 0; r < 4; ++r){
        float pa = 0.f, pb = 0.f;
        #pragma unroll
        for (int nt = 0; nt < 2; ++nt){
          float v = accH[mt][nt][r];
          if constexpr (DOTA) pa = fmaf(v, vaL[nt], pa);
          if constexpr (DOTB) pb = fmaf(v, vbL[nt], pb);
        }
        #pragma unroll
        for (int o = 8; o; o >>= 1){
          if constexpr (DOTA) pa += __shfl_xor(pa, o, 64);
          if constexpr (DOTB) pb += __shfl_xor(pb, o, 64);
        }
        if (ml == 0){
          int rl = mt*16 + kg*4 + r;
          sd[wv][rl][0] = pa;
          sd[wv][rl][1] = pb;
        }
      }
    }
    __syncthreads();
    if (tid < 64){
      int row = R0 + tid;
      if (row < M){
        if constexpr (DOTA)
          outa[row] = sd[0][tid][0] + sd[1][tid][0] + sd[2][tid][0] + sd[3][tid][0];
        if constexpr (DOTB)
          outb[row] = sd[0][tid][1] + sd[1][tid][1] + sd[2][tid][1] + sd[3][tid][1];
      }
    }
  }

  if constexpr (OUTMODE == 2){
    if constexpr (DOTA || DOTB) __syncthreads();
    #pragma unroll
    for (int p = 0; p < 2; ++p){
      #pragma unroll
      for (int mh = 0; mh < 2; ++mh){
        int mt = p*2 + mh;
        #pragma unroll
        for (int nt = 0; nt < 2; ++nt){
          #pragma unroll
          for (int r = 0; r < 4; ++r)
            sC[wv][mh*16 + kg*4 + r][nt*16 + ml] = accH[mt][nt][r];
        }
      }
      __syncthreads();
      #pragma unroll
      for (int j = 0; j < 4; ++j){
        int row_l = j*8 + (lane >> 3);
        int c4 = (lane & 7) * 4;
        int grow = R0 + p*32 + row_l;
        if (grow < M){
          float4 v = *(const float4*)&sC[wv][row_l][c4];
          int gcol = wv*32 + c4;
          __half2 h0 = __floats2half2_rn(v.x, v.y);
          __half2 h1 = __floats2half2_rn(v.z, v.w);
          *(uint2*)(Ch + (size_t)grow*128 + gcol) = make_uint2(*(uint32_t*)&h0, *(uint32_t*)&h1);
        }
      }
      __syncthreads();
    }
  }
}

// ============ CSR build ============
__global__ void hist_k(const int* __restrict__ dstv, int* __restrict__ deg, int E){
  int e = blockIdx.x*256 + threadIdx.x;
  if (e < E) atomicAdd(&deg[dstv[e]], 1);
}

// single-pass scan with decoupled lookback (ticket-ordered, all blocks resident)
__global__ void scan_onepass(const int* __restrict__ deg, int* __restrict__ rp,
    int* __restrict__ cur, unsigned long long* __restrict__ bstat,
    int* __restrict__ bctr, int n, int E)
{
  __shared__ int sbid;
  __shared__ int swsum[4];
  __shared__ int sprev;
  if (threadIdx.x == 0) sbid = atomicAdd(bctr, 1);
  __syncthreads();
  const int bid = sbid;
  int i = bid*256 + threadIdx.x;
  int lane = threadIdx.x & 63, wv = threadIdx.x >> 6;
  int v = (i < n) ? deg[i] : 0;
  int inc = v;
  #pragma unroll
  for (int o = 1; o < 64; o <<= 1){
    int u = __shfl_up(inc, o, 64);
    if (lane >= o) inc += u;
  }
  if (lane == 63) swsum[wv] = inc;
  __syncthreads();
  if (threadIdx.x == 0){
    int bsum = swsum[0]+swsum[1]+swsum[2]+swsum[3];
    atomicExch(&bstat[bid], (1ull << 62) | (unsigned long long)(unsigned)bsum);
    int prev = 0;
    for (int j = bid - 1; j >= 0; --j){
      unsigned long long s;
      do { s = atomicAdd(&bstat[j], 0ull); } while ((s >> 62) == 0);
      prev += (int)(s & 0xffffffffull);
      if ((s >> 62) == 2) break;
    }
    atomicExch(&bstat[bid], (2ull << 62) | (unsigned long long)(unsigned)(prev + bsum));
    sprev = prev;
  }
  __syncthreads();
  int woff = sprev;
  for (int wq = 0; wq < wv; ++wq) woff += swsum[wq];
  int excl = woff + inc - v;
  if (i < n){ rp[i] = excl; cur[i] = excl; }
  if (bid == 0 && threadIdx.x == 0) rp[n] = E;
}

__global__ void scatter_k(const int* __restrict__ srcv, const int* __restrict__ dstv,
                          int* __restrict__ cur, int* __restrict__ ssorted, int E){
  int e = blockIdx.x*256 + threadIdx.x;
  if (e < E){
    int p = atomicAdd(&cur[dstv[e]], 1);
    ssorted[p] = srcv[e];
  }
}

// ============ fused segment softmax + aggregation: 16-lane group per dst node ============
// 4 dst/wave, 16 dst/block. Lane covers 8 features (uint4 = 16B loads).
__global__ __launch_bounds__(256) void gat_agg(const int* __restrict__ ssorted,
    const int* __restrict__ rp,
    const float* __restrict__ asn, const float* __restrict__ adn,
    const uint4* __restrict__ hsv, const float* __restrict__ bias,
    uint4* __restrict__ outv, int Nn)
{
  const int lane = threadIdx.x & 63;
  const int wv = threadIdx.x >> 6;
  const int l16 = lane & 15;
  const int gbase = lane & 48;
  const int d = blockIdx.x*16 + wv*4 + (lane >> 4);
  const bool valid = d < Nn;
  const int dc = valid ? d : Nn-1;
  const int lo = rp[dc], hi = rp[dc+1];
  const int deg = valid ? (hi - lo) : 0;
  const float ad = adn[dc];
  float acc[8] = {0.f,0.f,0.f,0.f,0.f,0.f,0.f,0.f};

  const bool fast = (deg <= 16);
  const int fdeg = fast ? deg : 0;
  int mdeg = fdeg;
  mdeg = max(mdeg, __shfl_xor(mdeg, 16, 64));
  mdeg = max(mdeg, __shfl_xor(mdeg, 32, 64));

  int sid = 0; float lg = -1e30f;
  if (l16 < fdeg){
    sid = ssorted[lo + l16];
    lg = lrelu(asn[sid] + ad);
  }
  float m = lg;
  m = fmaxf(m, __shfl_xor(m, 8, 64));
  m = fmaxf(m, __shfl_xor(m, 4, 64));
  m = fmaxf(m, __shfl_xor(m, 2, 64));
  m = fmaxf(m, __shfl_xor(m, 1, 64));
  float p = (l16 < fdeg) ? __expf(lg - m) : 0.f;
  float s = p;
  s += __shfl_xor(s, 8, 64);
  s += __shfl_xor(s, 4, 64);
  s += __shfl_xor(s, 2, 64);
  s += __shfl_xor(s, 1, 64);
  float alpha = p * (1.f / (s + 1e-16f));

  for (int i = 0; i < mdeg; ++i){
    if (i < fdeg){                           // group-uniform predicate
      float al = __shfl(alpha, gbase + i, 64);
      int sd = __shfl(sid, gbase + i, 64);
      uint4 v = hsv[(size_t)sd*16 + l16];
      float2 f0 = __half22float2(*(__half2*)&v.x);
      float2 f1 = __half22float2(*(__half2*)&v.y);
      float2 f2 = __half22float2(*(__half2*)&v.z);
      float2 f3 = __half22float2(*(__half2*)&v.w);
      acc[0] = fmaf(al, f0.x, acc[0]); acc[1] = fmaf(al, f0.y, acc[1]);
      acc[2] = fmaf(al, f1.x, acc[2]); acc[3] = fmaf(al, f1.y, acc[3]);
      acc[4] = fmaf(al, f2.x, acc[4]); acc[5] = fmaf(al, f2.y, acc[5]);
      acc[6] = fmaf(al, f3.x, acc[6]); acc[7] = fmaf(al, f3.y, acc[7]);
    }
  }

  if (!fast){                                // rare: deg > 16
    float mg = -1e30f;
    for (int e = l16; e < deg; e += 16){
      int sd = ssorted[lo + e];
      mg = fmaxf(mg, lrelu(asn[sd] + ad));
    }
    mg = fmaxf(mg, __shfl_xor(mg, 8, 64));
    mg = fmaxf(mg, __shfl_xor(mg, 4, 64));
    mg = fmaxf(mg, __shfl_xor(mg, 2, 64));
    mg = fmaxf(mg, __shfl_xor(mg, 1, 64));
    float sg = 0.f;
    for (int e = l16; e < deg; e += 16){
      int sd = ssorted[lo + e];
      sg += __expf(lrelu(asn[sd] + ad) - mg);
    }
    sg += __shfl_xor(sg, 8, 64);
    sg += __shfl_xor(sg, 4, 64);
    sg += __shfl_xor(sg, 2, 64);
    sg += __shfl_xor(sg, 1, 64);
    float inv = 1.f / (sg + 1e-16f);
    for (int e = 0; e < deg; ++e){
      int sd = ssorted[lo + e];              // group-uniform -> broadcast
      float a = __expf(lrelu(asn[sd] + ad) - mg) * inv;
      uint4 v = hsv[(size_t)sd*16 + l16];
      float2 f0 = __half22float2(*(__half2*)&v.x);
      float2 f1 = __half22float2(*(__half2*)&v.y);
      float2 f2 = __half22float2(*(__half2*)&v.z);
      float2 f3 = __half22float2(*(__half2*)&v.w);
      acc[0] = fmaf(a, f0.x, acc[0]); acc[1] = fmaf(a, f0.y, acc[1]);
      acc[2] = fmaf(a, f1.x, acc[2]); acc[3] = fmaf(a, f1.y, acc[3]);
      acc[4] = fmaf(a, f2.x, acc[4]); acc[5] = fmaf(a, f2.y, acc[5]);
      acc[6] = fmaf(a, f3.x, acc[6]); acc[7] = fmaf(a, f3.y, acc[7]);
    }
  }

  if (valid){
    float4 b0 = ((const float4*)bias)[l16*2];
    float4 b1 = ((const float4*)bias)[l16*2 + 1];
    __half2 h0 = __floats2half2_rn(elu1(acc[0]+b0.x), elu1(acc[1]+b0.y));
    __half2 h1 = __floats2half2_rn(elu1(acc[2]+b0.z), elu1(acc[3]+b0.w));
    __half2 h2 = __floats2half2_rn(elu1(acc[4]+b1.x), elu1(acc[5]+b1.y));
    __half2 h3 = __floats2half2_rn(elu1(acc[6]+b1.z), elu1(acc[7]+b1.w));
    outv[(size_t)d*16 + l16] = make_uint4(*(uint32_t*)&h0, *(uint32_t*)&h1,
                                          *(uint32_t*)&h2, *(uint32_t*)&h3);
  }
}

// ============ graph pooling: 16-lane group per graph ============
__global__ __launch_bounds__(256) void pool_relu(const uint4* __restrict__ hv,
    const int* __restrict__ batch, uint4* __restrict__ ptail, int Nn, int G)
{
  const int lane = threadIdx.x & 63;
  const int wv = threadIdx.x >> 6;
  const int l16 = lane & 15;
  const int g = blockIdx.x*16 + wv*4 + (lane >> 4);
  if (g >= G) return;
  const int lo = lower_bound_i(batch, Nn, g);
  const int hi = lower_bound_i(batch, Nn, g + 1);
  float acc[8] = {0.f,0.f,0.f,0.f,0.f,0.f,0.f,0.f};
  for (int i = lo; i < hi; ++i){
    uint4 v = hv[(size_t)i*16 + l16];
    float2 f0 = __half22float2(*(__half2*)&v.x);
    float2 f1 = __half22float2(*(__half2*)&v.y);
    float2 f2 = __half22float2(*(__half2*)&v.z);
    float2 f3 = __half22float2(*(__half2*)&v.w);
    acc[0] += f0.x; acc[1] += f0.y; acc[2] += f1.x; acc[3] += f1.y;
    acc[4] += f2.x; acc[5] += f2.y; acc[6] += f3.x; acc[7] += f3.y;
  }
  __half2 h0 = __floats2half2_rn(fmaxf(acc[0],0.f), fmaxf(acc[1],0.f));
  __half2 h1 = __floats2half2_rn(fmaxf(acc[2],0.f), fmaxf(acc[3],0.f));
  __half2 h2 = __floats2half2_rn(fmaxf(acc[4],0.f), fmaxf(acc[5],0.f));
  __half2 h3 = __floats2half2_rn(fmaxf(acc[6],0.f), fmaxf(acc[7],0.f));
  ptail[(size_t)g*16 + l16] = make_uint4(*(uint32_t*)&h0, *(uint32_t*)&h1,
                                         *(uint32_t*)&h2, *(uint32_t*)&h3);
}

// ============ molecular GAT aggregate + final linear (fused) ============
__global__ __launch_bounds__(128) void mol_agg(const float* __restrict__ as2,
    const float* __restrict__ ad2, const unsigned short* __restrict__ hs2,
    const int* __restrict__ batch, const float* __restrict__ bias,
    const float* __restrict__ W2, const float* __restrict__ b2,
    float* __restrict__ out, int Nn)
{
  const int g = blockIdx.x;
  const int c = threadIdx.x;
  __shared__ int sb[2];
  __shared__ float red[2];
  if (c < 2) sb[c] = lower_bound_i(batch, Nn, g + c);
  __syncthreads();
  const int lo = sb[0], hi = sb[1];
  const float ad = ad2[g];

  float mt = -1e30f;
  for (int i = lo + c; i < hi; i += 128) mt = fmaxf(mt, lrelu(as2[i] + ad));
  #pragma unroll
  for (int o = 32; o; o >>= 1) mt = fmaxf(mt, __shfl_xor(mt, o, 64));
  if ((c & 63) == 0) red[c >> 6] = mt;
  __syncthreads();
  const float m = fmaxf(red[0], red[1]);

  float st = 0.f;
  for (int i = lo + c; i < hi; i += 128) st += __expf(lrelu(as2[i] + ad) - m);
  #pragma unroll
  for (int o = 32; o; o >>= 1) st += __shfl_xor(st, o, 64);
  __syncthreads();
  if ((c & 63) == 0) red[c >> 6] = st;
  __syncthreads();
  const float inv = 1.f / (red[0] + red[1] + 1e-16f);

  float acc = 0.f;
  for (int i = lo; i < hi; ++i){
    float wgt = __expf(lrelu(as2[i] + ad) - m) * inv;
    acc = fmaf(wgt, __half2float(__ushort_as_half(hs2[(size_t)i*128 + c])), acc);
  }
  float v = elu1(acc + bias[c]);

  float r = v * W2[c];
  #pragma unroll
  for (int o = 32; o; o >>= 1) r += __shfl_xor(r, o, 64);
  __syncthreads();
  if ((c & 63) == 0) red[c >> 6] = r;
  __syncthreads();
  if (c == 0) out[g] = red[0] + red[1] + b2[0];
}

extern "C" void kernel_launch(void* const* d_in, const int* in_sizes, int n_in,
                              void* d_out, int out_size, void* d_ws, size_t ws_size,
                              hipStream_t stream)
{
  const float* x      = (const float*)d_in[0];
  const int*   ei     = (const int*)  d_in[1];
  const int*   batch  = (const int*)  d_in[2];
  const float* W1     = (const float*)d_in[3];
  const float* b1     = (const float*)d_in[4];
  const float* gW     = (const float*)d_in[5];
  const float* g_asrc = (const float*)d_in[6];
  const float* g_adst = (const float*)d_in[7];
  const float* g_b    = (const float*)d_in[8];
  const float* mW     = (const float*)d_in[9];
  const float* m_asrc = (const float*)d_in[10];
  const float* m_adst = (const float*)d_in[11];
  const float* m_b    = (const float*)d_in[12];
  const float* W2     = (const float*)d_in[13];
  const float* b2     = (const float*)d_in[14];

  const int Nn = in_sizes[0] / 64;            // 100000
  const int E  = in_sizes[1] / 2;             // 400000
  const int G  = out_size;                    // 5000
  const int NL = in_sizes[5] / (128*128);     // 3
  const int M2 = Nn + G;
  const int* srcv = ei;
  const int* dstv = ei + E;

  char* w = (char*)d_ws;
  unsigned short* h16 = (unsigned short*)w; w += (size_t)(M2+64)*128*2;
  unsigned short* hsR = (unsigned short*)w; w += (size_t)(M2+64)*128*2;
  float* asO      = (float*)w; w += (size_t)(M2+64)*4;
  float* adO      = (float*)w; w += (size_t)(M2+64)*4;
  int*   deg      = (int*)w;   w += (size_t)Nn*4;
  int*   rp       = (int*)w;   w += (size_t)(Nn+64)*4;
  int*   cur      = (int*)w;   w += (size_t)Nn*4;
  int*   ssorted  = (int*)w;   w += (size_t)E*4;
  unsigned long long* bstat = (unsigned long long*)w; w += 512*8;
  int*   bctr     = (int*)w;   w += 64;
  unsigned short* w1h = (unsigned short*)w; w += 64*128*2;
  unsigned short* w1l = (unsigned short*)w; w += 64*128*2;
  unsigned short* gwh = (unsigned short*)w; w += (size_t)NL*128*128*2;
  unsigned short* gwl = (unsigned short*)w; w += (size_t)NL*128*128*2;
  unsigned short* mwh = (unsigned short*)w; w += 128*128*2;
  unsigned short* mwl = (unsigned short*)w; w += 128*128*2;

  const int nscan = (Nn + 255)/256;
  const int nrt = (Nn + 63)/64;
  const int mrt = (M2 + 63)/64;

  // ---- prep (weights + zero CSR/scan state) ----
  wprep_all<<<nscan, 256, 0, stream>>>(W1, gW, mW, w1h, w1l, gwh, gwl, mwh, mwl,
                                       deg, bstat, bctr, Nn, NL*16384, nscan);

  // ---- CSR build ----
  hist_k<<<(E+255)/256, 256, 0, stream>>>(dstv, deg, E);
  scan_onepass<<<nscan, 256, 0, stream>>>(deg, rp, cur, bstat, bctr, Nn, E);
  scatter_k<<<(E+255)/256, 256, 0, stream>>>(srcv, dstv, cur, ssorted, E);

  // ---- lin1 ----
  gemm_lin1<<<nrt, 256, 0, stream>>>(x, w1h, w1l, b1, h16, Nn);

  // ---- 3 GAT layers ----
  for (int l = 0; l < NL; ++l){
    gemm_mfma<2, true, true><<<nrt, 256, 0, stream>>>(
        h16, gwh + (size_t)l*128*128, gwl + (size_t)l*128*128,
        g_asrc + l*128, g_adst + l*128, hsR, asO, adO, Nn);
    gat_agg<<<(Nn+15)/16, 256, 0, stream>>>(ssorted, rp, asO, adO,
        (const uint4*)hsR, g_b + l*128, (uint4*)h16, Nn);
  }

  // ---- readout ----
  pool_relu<<<(G+15)/16, 256, 0, stream>>>((const uint4*)h16, batch,
      (uint4*)(h16 + (size_t)Nn*128), Nn, G);
  gemm_mfma<2, true, true><<<mrt, 256, 0, stream>>>(
      h16, mwh, mwl, m_asrc, m_adst, hsR, asO, adO, M2);
  mol_agg<<<G, 128, 0, stream>>>(asO, adO + Nn, hsR, batch, m_b, W2, b2, (float*)d_out, Nn);
}

// Round 10
// 302.706 us; speedup vs baseline: 1.8601x; 1.0508x over previous
//
#include <hip/hip_runtime.h>
#include <hip/hip_fp16.h>
#include <math.h>
#include <stdint.h>

#define DEV __device__ __forceinline__

using f32x4 = __attribute__((ext_vector_type(4))) float;
using half8 = __attribute__((ext_vector_type(8))) _Float16;
typedef union { uint4 u; half8 h; } u4h8;

DEV float lrelu(float x){ return x > 0.f ? x : 0.01f*x; }
DEV float elu1(float x){ return x > 0.f ? x : __expf(x)-1.f; }

DEV int lower_bound_i(const int* __restrict__ a, int n, int key){
  int lo = 0, hi = n;
  while (lo < hi){ int mid = (lo+hi)>>1; if (a[mid] < key) lo = mid+1; else hi = mid; }
  return lo;
}

// ============ combined prep: all weight splits + zero CSR/scan state ============
DEV void wsplit(float v, unsigned short* __restrict__ H, unsigned short* __restrict__ L, size_t o){
  __half h = __float2half_rn(v);
  float lo = (v - __half2float(h)) * 1024.f;
  H[o] = __half_as_ushort(h);
  L[o] = __half_as_ushort(__float2half_rn(lo));
}

__global__ void wprep_all(const float* __restrict__ W1, const float* __restrict__ gW,
    const float* __restrict__ mW,
    unsigned short* __restrict__ w1h, unsigned short* __restrict__ w1l,
    unsigned short* __restrict__ gwh, unsigned short* __restrict__ gwl,
    unsigned short* __restrict__ mwh, unsigned short* __restrict__ mwl,
    int* __restrict__ deg, unsigned long long* __restrict__ bstat,
    int* __restrict__ bctr, int Nn, int nG, int nscan)
{
  int i = blockIdx.x*256 + threadIdx.x;
  if (i < Nn) deg[i] = 0;
  if (i < nscan) bstat[i] = 0ull;
  if (i == 0) *bctr = 0;
  if (i < 8192){                       // W1 [64][128] -> [128][64]
    int k = i >> 7, n = i & 127;
    wsplit(W1[i], w1h, w1l, (size_t)n*64 + k);
  }
  if (i < nG){                         // gW [NL][128][128] -> [NL][128][128]T
    int mat = i >> 14; int rem = i & 16383;
    int k = rem >> 7, n = rem & 127;
    wsplit(gW[i], gwh, gwl, (size_t)mat*16384 + (size_t)n*128 + k);
  }
  if (i < 16384){                      // mW
    int k = i >> 7, n = i & 127;
    wsplit(mW[i], mwh, mwl, (size_t)n*128 + k);
  }
}

// ============ lin1 GEMM: h = lrelu(x[M,64] @ W1 + b1) -> fp16 (x converted in-kernel) ============
__global__ __launch_bounds__(256, 3) void gemm_lin1(
    const float* __restrict__ X, const unsigned short* __restrict__ Wt_hi,
    const unsigned short* __restrict__ Wt_lo, const float* __restrict__ bias,
    unsigned short* __restrict__ Ch, int M)
{
  const int tid = threadIdx.x;
  const int lane = tid & 63;
  const int wv = tid >> 6;
  const int ml = lane & 15;
  const int kg = lane >> 4;
  const int R0 = blockIdx.x * 64;

  __shared__ uint32_t sA[2][1024];
  __shared__ float sC[4][32][36];

  const unsigned short* bhp[2];
  const unsigned short* blp[2];
  #pragma unroll
  for (int nt = 0; nt < 2; ++nt){
    int n = wv*32 + nt*16 + ml;
    bhp[nt] = Wt_hi + (size_t)n*64 + kg*8;
    blp[nt] = Wt_lo + (size_t)n*64 + kg*8;
  }

  {
    int row = tid >> 2, kq = tid & 3;
    int gr = R0 + row; gr = gr < M ? gr : M-1;
    const float4* xp = (const float4*)(X + (size_t)gr*64 + kq*16);
    int sub = kq >> 1;
    #pragma unroll
    for (int i = 0; i < 4; ++i){
      float4 v = xp[i];
      __half2 h0 = __floats2half2_rn(v.x, v.y);
      __half2 h1 = __floats2half2_rn(v.z, v.w);
      int slot = (kq & 1)*2 + (i >> 1);
      int slot_s = slot ^ ((row >> 1) & 3);
      int byte = row*64 + slot_s*16 + (i & 1)*8;
      *(uint2*)((char*)&sA[sub][0] + byte) = make_uint2(*(uint32_t*)&h0, *(uint32_t*)&h1);
    }
  }
  __syncthreads();

  f32x4 accH[4][2], accL[4][2];
  #pragma unroll
  for (int mt = 0; mt < 4; ++mt)
    #pragma unroll
    for (int nt = 0; nt < 2; ++nt){
      accH[mt][nt] = (f32x4){0.f,0.f,0.f,0.f};
      accL[mt][nt] = (f32x4){0.f,0.f,0.f,0.f};
    }

  #pragma unroll
  for (int sc = 0; sc < 2; ++sc){
    u4h8 bh[2], bl[2];
    #pragma unroll
    for (int nt = 0; nt < 2; ++nt){
      bh[nt].u = *(const uint4*)(bhp[nt] + sc*32);
      bl[nt].u = *(const uint4*)(blp[nt] + sc*32);
    }
    const char* buf = (const char*)&sA[sc][0];
    #pragma unroll
    for (int mt = 0; mt < 4; ++mt){
      int row = mt*16 + ml;
      int ba = row*64 + ((kg ^ ((row >> 1) & 3)) * 16);
      u4h8 A_;
      A_.u = *(const uint4*)(buf + ba);
      #pragma unroll
      for (int nt = 0; nt < 2; ++nt){
        accH[mt][nt] = __builtin_amdgcn_mfma_f32_16x16x32_f16(A_.h, bh[nt].h, accH[mt][nt], 0, 0, 0);
        accL[mt][nt] = __builtin_amdgcn_mfma_f32_16x16x32_f16(A_.h, bl[nt].h, accL[mt][nt], 0, 0, 0);
      }
    }
  }

  float bv[2] = { bias[wv*32 + ml], bias[wv*32 + 16 + ml] };
  #pragma unroll
  for (int p = 0; p < 2; ++p){
    #pragma unroll
    for (int mh = 0; mh < 2; ++mh){
      int mt = p*2 + mh;
      #pragma unroll
      for (int nt = 0; nt < 2; ++nt){
        #pragma unroll
        for (int r = 0; r < 4; ++r){
          float v = accH[mt][nt][r] + accL[mt][nt][r] * 9.765625e-4f;
          v = lrelu(v + bv[nt]);
          sC[wv][mh*16 + kg*4 + r][nt*16 + ml] = v;
        }
      }
    }
    __syncthreads();
    #pragma unroll
    for (int j = 0; j < 4; ++j){
      int row_l = j*8 + (lane >> 3);
      int c4 = (lane & 7) * 4;
      int grow = R0 + p*32 + row_l;
      if (grow < M){
        float4 v = *(const float4*)&sC[wv][row_l][c4];
        int gcol = wv*32 + c4;
        __half2 h0 = __floats2half2_rn(v.x, v.y);
        __half2 h1 = __floats2half2_rn(v.z, v.w);
        *(uint2*)(Ch + (size_t)grow*128 + gcol) = make_uint2(*(uint32_t*)&h0, *(uint32_t*)&h1);
      }
    }
    __syncthreads();
  }
}

// ============ main MFMA GEMM: C[M,128] = A[M,128] @ W, f16 dual-acc ============
// LDS: sA (16 KB staging) UNIONed with sC (18 KB epilogue bounce) -> 20.5 KB total.
// B re-loaded per sub-chunk from L2 (frees ~32 VGPR) -> 4 waves/SIMD.
template<int OUTMODE, bool DOTA, bool DOTB>
__global__ __launch_bounds__(256, 4) void gemm_mfma(
    const unsigned short* __restrict__ Ah, const unsigned short* __restrict__ Wt_hi,
    const unsigned short* __restrict__ Wt_lo,
    const float* __restrict__ va, const float* __restrict__ vb,
    unsigned short* __restrict__ Ch,
    float* __restrict__ outa, float* __restrict__ outb, int M)
{
  constexpr int K = 128;
  const int tid = threadIdx.x;
  const int lane = tid & 63;
  const int wv = tid >> 6;
  const int ml = lane & 15;
  const int kg = lane >> 4;
  const int R0 = blockIdx.x * 64;

  __shared__ char smem[18432];       // union: sA[4][1024] u32 (16 KB) / sC[4][32][36] f32 (18 KB)
  __shared__ float sd[4][64][2];
  uint32_t* sA = (uint32_t*)smem;
  typedef float sC_t[32][36];
  sC_t* sC = (sC_t*)smem;

  const unsigned short* bhp[2];
  const unsigned short* blp[2];
  #pragma unroll
  for (int nt = 0; nt < 2; ++nt){
    int n = wv*32 + nt*16 + ml;
    bhp[nt] = Wt_hi + (size_t)n*K + kg*8;
    blp[nt] = Wt_lo + (size_t)n*K + kg*8;
  }

  auto STAGE = [&](int ch){
    #pragma unroll
    for (int j = 0; j < 2; ++j){
      int sc = ch*2 + j;
      int o = tid*16;
      int row = o >> 6;
      int t = (o >> 4) & 3;
      int gr = R0 + row; gr = gr < M ? gr : M-1;
      int jj = t ^ ((row >> 1) & 3);
      const char* src = (const char*)(Ah + (size_t)gr*K + sc*32 + jj*8);
      char* dst = (char*)sA + ((ch & 1)*2 + j)*4096 + wv*1024;
      __builtin_amdgcn_global_load_lds(
          (const __attribute__((address_space(1))) void*)src,
          (__attribute__((address_space(3))) void*)dst, 16, 0, 0);
    }
  };

  f32x4 accH[4][2], accL[4][2];
  #pragma unroll
  for (int mt = 0; mt < 4; ++mt)
    #pragma unroll
    for (int nt = 0; nt < 2; ++nt){
      accH[mt][nt] = (f32x4){0.f,0.f,0.f,0.f};
      accL[mt][nt] = (f32x4){0.f,0.f,0.f,0.f};
    }

  STAGE(0);
  __syncthreads();

  #pragma unroll
  for (int ch = 0; ch < 2; ++ch){
    if (ch == 0) STAGE(1);
    #pragma unroll
    for (int js = 0; js < 2; ++js){
      int sc = ch*2 + js;
      u4h8 bh[2], bl[2];
      #pragma unroll
      for (int nt = 0; nt < 2; ++nt){
        bh[nt].u = *(const uint4*)(bhp[nt] + sc*32);
        bl[nt].u = *(const uint4*)(blp[nt] + sc*32);
      }
      const char* buf = (const char*)sA + ((ch & 1)*2 + js)*4096;
      #pragma unroll
      for (int mt = 0; mt < 4; ++mt){
        int row = mt*16 + ml;
        int ba = row*64 + ((kg ^ ((row >> 1) & 3)) * 16);
        u4h8 A_;
        A_.u = *(const uint4*)(buf + ba);
        #pragma unroll
        for (int nt = 0; nt < 2; ++nt){
          accH[mt][nt] = __builtin_amdgcn_mfma_f32_16x16x32_f16(A_.h, bh[nt].h, accH[mt][nt], 0, 0, 0);
          accL[mt][nt] = __builtin_amdgcn_mfma_f32_16x16x32_f16(A_.h, bl[nt].h, accL[mt][nt], 0, 0, 0);
        }
      }
    }
    __syncthreads();
  }

  #pragma unroll
  for (int mt = 0; mt < 4; ++mt)
    #pragma unroll
    for (int nt = 0; nt < 2; ++nt)
      accH[mt][nt] = accH[mt][nt] + accL[mt][nt] * 9.765625e-4f;

  if constexpr (DOTA || DOTB){
    float vaL[2] = {0.f,0.f}, vbL[2] = {0.f,0.f};
    if constexpr (DOTA){ vaL[0] = va[wv*32 + ml]; vaL[1] = va[wv*32 + 16 + ml]; }
    if constexpr (DOTB){ vbL[0] = vb[wv*32 + ml]; vbL[1] = vb[wv*32 + 16 + ml]; }
    #pragma unroll
    for (int mt = 0; mt < 4; ++mt){
      #pragma unroll
      for (int r = 0; r < 4; ++r){
        float pa = 0.f, pb = 0.f;
        #pragma unroll
        for (int nt = 0; nt < 2; ++nt){
          float v = accH[mt][nt][r];
          if constexpr (DOTA) pa = fmaf(v, vaL[nt], pa);
          if constexpr (DOTB) pb = fmaf(v, vbL[nt], pb);
        }
        #pragma unroll
        for (int o = 8; o; o >>= 1){
          if constexpr (DOTA) pa += __shfl_xor(pa, o, 64);
          if constexpr (DOTB) pb += __shfl_xor(pb, o, 64);
        }
        if (ml == 0){
          int rl = mt*16 + kg*4 + r;
          sd[wv][rl][0] = pa;
          sd[wv][rl][1] = pb;
        }
      }
    }
    __syncthreads();
    if (tid < 64){
      int row = R0 + tid;
      if (row < M){
        if constexpr (DOTA)
          outa[row] = sd[0][tid][0] + sd[1][tid][0] + sd[2][tid][0] + sd[3][tid][0];
        if constexpr (DOTB)
          outb[row] = sd[0][tid][1] + sd[1][tid][1] + sd[2][tid][1] + sd[3][tid][1];
      }
    }
    __syncthreads();   // sd done; also fences before sC overwrite of sA region
  }

  if constexpr (OUTMODE == 2){
    #pragma unroll
    for (int p = 0; p < 2; ++p){
      #pragma unroll
      for (int mh = 0; mh < 2; ++mh){
        int mt = p*2 + mh;
        #pragma unroll
        for (int nt = 0; nt < 2; ++nt){
          #pragma unroll
          for (int r = 0; r < 4; ++r)
            sC[wv][mh*16 + kg*4 + r][nt*16 + ml] = accH[mt][nt][r];
        }
      }
      __syncthreads();
      #pragma unroll
      for (int j = 0; j < 4; ++j){
        int row_l = j*8 + (lane >> 3);
        int c4 = (lane & 7) * 4;
        int grow = R0 + p*32 + row_l;
        if (grow < M){
          float4 v = *(const float4*)&sC[wv][row_l][c4];
          int gcol = wv*32 + c4;
          __half2 h0 = __floats2half2_rn(v.x, v.y);
          __half2 h1 = __floats2half2_rn(v.z, v.w);
          *(uint2*)(Ch + (size_t)grow*128 + gcol) = make_uint2(*(uint32_t*)&h0, *(uint32_t*)&h1);
        }
      }
      __syncthreads();
    }
  }
}

// ============ CSR build ============
__global__ void hist_k(const int* __restrict__ dstv, int* __restrict__ deg, int E){
  int e = blockIdx.x*256 + threadIdx.x;
  if (e < E) atomicAdd(&deg[dstv[e]], 1);
}

// single-pass scan with decoupled lookback (ticket-ordered, all blocks resident)
__global__ void scan_onepass(const int* __restrict__ deg, int* __restrict__ rp,
    int* __restrict__ cur, unsigned long long* __restrict__ bstat,
    int* __restrict__ bctr, int n, int E)
{
  __shared__ int sbid;
  __shared__ int swsum[4];
  __shared__ int sprev;
  if (threadIdx.x == 0) sbid = atomicAdd(bctr, 1);
  __syncthreads();
  const int bid = sbid;
  int i = bid*256 + threadIdx.x;
  int lane = threadIdx.x & 63, wv = threadIdx.x >> 6;
  int v = (i < n) ? deg[i] : 0;
  int inc = v;
  #pragma unroll
  for (int o = 1; o < 64; o <<= 1){
    int u = __shfl_up(inc, o, 64);
    if (lane >= o) inc += u;
  }
  if (lane == 63) swsum[wv] = inc;
  __syncthreads();
  if (threadIdx.x == 0){
    int bsum = swsum[0]+swsum[1]+swsum[2]+swsum[3];
    atomicExch(&bstat[bid], (1ull << 62) | (unsigned long long)(unsigned)bsum);
    int prev = 0;
    for (int j = bid - 1; j >= 0; --j){
      unsigned long long s;
      do { s = atomicAdd(&bstat[j], 0ull); } while ((s >> 62) == 0);
      prev += (int)(s & 0xffffffffull);
      if ((s >> 62) == 2) break;
    }
    atomicExch(&bstat[bid], (2ull << 62) | (unsigned long long)(unsigned)(prev + bsum));
    sprev = prev;
  }
  __syncthreads();
  int woff = sprev;
  for (int wq = 0; wq < wv; ++wq) woff += swsum[wq];
  int excl = woff + inc - v;
  if (i < n){ rp[i] = excl; cur[i] = excl; }
  if (bid == 0 && threadIdx.x == 0) rp[n] = E;
}

__global__ void scatter_k(const int* __restrict__ srcv, const int* __restrict__ dstv,
                          int* __restrict__ cur, int* __restrict__ ssorted, int E){
  int e = blockIdx.x*256 + threadIdx.x;
  if (e < E){
    int p = atomicAdd(&cur[dstv[e]], 1);
    ssorted[p] = srcv[e];
  }
}

// ============ fused segment softmax + aggregation: 16-lane group per dst node ============
// 4 dst/wave. Lane covers 8 features (uint4 = 16B loads). Inner loop: unconditional
// 4-wide batches (ghost lanes have alpha==0, sid==0) -> 4 gathers in flight.
__global__ __launch_bounds__(256) void gat_agg(const int* __restrict__ ssorted,
    const int* __restrict__ rp,
    const float* __restrict__ asn, const float* __restrict__ adn,
    const uint4* __restrict__ hsv, const float* __restrict__ bias,
    uint4* __restrict__ outv, int Nn)
{
  const int lane = threadIdx.x & 63;
  const int wv = threadIdx.x >> 6;
  const int l16 = lane & 15;
  const int gbase = lane & 48;
  const int d = blockIdx.x*16 + wv*4 + (lane >> 4);
  const bool valid = d < Nn;
  const int dc = valid ? d : Nn-1;
  const int lo = rp[dc], hi = rp[dc+1];
  const int deg = valid ? (hi - lo) : 0;
  const float ad = adn[dc];
  float acc[8] = {0.f,0.f,0.f,0.f,0.f,0.f,0.f,0.f};

  const bool fast = (deg <= 16);
  const int fdeg = fast ? deg : 0;
  int mdeg = fdeg;
  mdeg = max(mdeg, __shfl_xor(mdeg, 16, 64));
  mdeg = max(mdeg, __shfl_xor(mdeg, 32, 64));
  const int nb = (mdeg + 3) & ~3;          // wave-uniform, <= 16

  int sid = 0; float lg = -1e30f;
  if (l16 < fdeg){
    sid = ssorted[lo + l16];
    lg = lrelu(asn[sid] + ad);
  }
  float m = lg;
  m = fmaxf(m, __shfl_xor(m, 8, 64));
  m = fmaxf(m, __shfl_xor(m, 4, 64));
  m = fmaxf(m, __shfl_xor(m, 2, 64));
  m = fmaxf(m, __shfl_xor(m, 1, 64));
  float p = (l16 < fdeg) ? __expf(lg - m) : 0.f;
  float s = p;
  s += __shfl_xor(s, 8, 64);
  s += __shfl_xor(s, 4, 64);
  s += __shfl_xor(s, 2, 64);
  s += __shfl_xor(s, 1, 64);
  float alpha = p * (1.f / (s + 1e-16f));

  for (int i = 0; i < nb; i += 4){
    float al[4]; int sd[4]; uint4 v[4];
    #pragma unroll
    for (int j = 0; j < 4; ++j){
      al[j] = __shfl(alpha, gbase + i + j, 64);
      sd[j] = __shfl(sid, gbase + i + j, 64);
    }
    #pragma unroll
    for (int j = 0; j < 4; ++j)
      v[j] = hsv[(size_t)sd[j]*16 + l16];
    #pragma unroll
    for (int j = 0; j < 4; ++j){
      float2 f0 = __half22float2(*(__half2*)&v[j].x);
      float2 f1 = __half22float2(*(__half2*)&v[j].y);
      float2 f2 = __half22float2(*(__half2*)&v[j].z);
      float2 f3 = __half22float2(*(__half2*)&v[j].w);
      acc[0] = fmaf(al[j], f0.x, acc[0]); acc[1] = fmaf(al[j], f0.y, acc[1]);
      acc[2] = fmaf(al[j], f1.x, acc[2]); acc[3] = fmaf(al[j], f1.y, acc[3]);
      acc[4] = fmaf(al[j], f2.x, acc[4]); acc[5] = fmaf(al[j], f2.y, acc[5]);
      acc[6] = fmaf(al[j], f3.x, acc[6]); acc[7] = fmaf(al[j], f3.y, acc[7]);
    }
  }

  if (!fast){                                // rare: deg > 16
    float mg = -1e30f;
    for (int e = l16; e < deg; e += 16){
      int sd = ssorted[lo + e];
      mg = fmaxf(mg, lrelu(asn[sd] + ad));
    }
    mg = fmaxf(mg, __shfl_xor(mg, 8, 64));
    mg = fmaxf(mg, __shfl_xor(mg, 4, 64));
    mg = fmaxf(mg, __shfl_xor(mg, 2, 64));
    mg = fmaxf(mg, __shfl_xor(mg, 1, 64));
    float sg = 0.f;
    for (int e = l16; e < deg; e += 16){
      int sd = ssorted[lo + e];
      sg += __expf(lrelu(asn[sd] + ad) - mg);
    }
    sg += __shfl_xor(sg, 8, 64);
    sg += __shfl_xor(sg, 4, 64);
    sg += __shfl_xor(sg, 2, 64);
    sg += __shfl_xor(sg, 1, 64);
    float inv = 1.f / (sg + 1e-16f);
    for (int e = 0; e < deg; ++e){
      int sd = ssorted[lo + e];
      float a = __expf(lrelu(asn[sd] + ad) - mg) * inv;
      uint4 v = hsv[(size_t)sd*16 + l16];
      float2 f0 = __half22float2(*(__half2*)&v.x);
      float2 f1 = __half22float2(*(__half2*)&v.y);
      float2 f2 = __half22float2(*(__half2*)&v.z);
      float2 f3 = __half22float2(*(__half2*)&v.w);
      acc[0] = fmaf(a, f0.x, acc[0]); acc[1] = fmaf(a, f0.y, acc[1]);
      acc[2] = fmaf(a, f1.x, acc[2]); acc[3] = fmaf(a, f1.y, acc[3]);
      acc[4] = fmaf(a, f2.x, acc[4]); acc[5] = fmaf(a, f2.y, acc[5]);
      acc[6] = fmaf(a, f3.x, acc[6]); acc[7] = fmaf(a, f3.y, acc[7]);
    }
  }

  if (valid){
    float4 b0 = ((const float4*)bias)[l16*2];
    float4 b1 = ((const float4*)bias)[l16*2 + 1];
    __half2 h0 = __floats2half2_rn(elu1(acc[0]+b0.x), elu1(acc[1]+b0.y));
    __half2 h1 = __floats2half2_rn(elu1(acc[2]+b0.z), elu1(acc[3]+b0.w));
    __half2 h2 = __floats2half2_rn(elu1(acc[4]+b1.x), elu1(acc[5]+b1.y));
    __half2 h3 = __floats2half2_rn(elu1(acc[6]+b1.z), elu1(acc[7]+b1.w));
    outv[(size_t)d*16 + l16] = make_uint4(*(uint32_t*)&h0, *(uint32_t*)&h1,
                                          *(uint32_t*)&h2, *(uint32_t*)&h3);
  }
}

// ============ graph pooling: 16-lane group per graph ============
__global__ __launch_bounds__(256) void pool_relu(const uint4* __restrict__ hv,
    const int* __restrict__ batch, uint4* __restrict__ ptail, int Nn, int G)
{
  const int lane = threadIdx.x & 63;
  const int wv = threadIdx.x >> 6;
  const int l16 = lane & 15;
  const int g = blockIdx.x*16 + wv*4 + (lane >> 4);
  if (g >= G) return;
  const int lo = lower_bound_i(batch, Nn, g);
  const int hi = lower_bound_i(batch, Nn, g + 1);
  float acc[8] = {0.f,0.f,0.f,0.f,0.f,0.f,0.f,0.f};
  for (int i = lo; i < hi; ++i){
    uint4 v = hv[(size_t)i*16 + l16];
    float2 f0 = __half22float2(*(__half2*)&v.x);
    float2 f1 = __half22float2(*(__half2*)&v.y);
    float2 f2 = __half22float2(*(__half2*)&v.z);
    float2 f3 = __half22float2(*(__half2*)&v.w);
    acc[0] += f0.x; acc[1] += f0.y; acc[2] += f1.x; acc[3] += f1.y;
    acc[4] += f2.x; acc[5] += f2.y; acc[6] += f3.x; acc[7] += f3.y;
  }
  __half2 h0 = __floats2half2_rn(fmaxf(acc[0],0.f), fmaxf(acc[1],0.f));
  __half2 h1 = __floats2half2_rn(fmaxf(acc[2],0.f), fmaxf(acc[3],0.f));
  __half2 h2 = __floats2half2_rn(fmaxf(acc[4],0.f), fmaxf(acc[5],0.f));
  __half2 h3 = __floats2half2_rn(fmaxf(acc[6],0.f), fmaxf(acc[7],0.f));
  ptail[(size_t)g*16 + l16] = make_uint4(*(uint32_t*)&h0, *(uint32_t*)&h1,
                                         *(uint32_t*)&h2, *(uint32_t*)&h3);
}

// ============ molecular GAT aggregate + final linear (fused) ============
__global__ __launch_bounds__(128) void mol_agg(const float* __restrict__ as2,
    const float* __restrict__ ad2, const unsigned short* __restrict__ hs2,
    const int* __restrict__ batch, const float* __restrict__ bias,
    const float* __restrict__ W2, const float* __restrict__ b2,
    float* __restrict__ out, int Nn)
{
  const int g = blockIdx.x;
  const int c = threadIdx.x;
  __shared__ int sb[2];
  __shared__ float red[2];
  if (c < 2) sb[c] = lower_bound_i(batch, Nn, g + c);
  __syncthreads();
  const int lo = sb[0], hi = sb[1];
  const float ad = ad2[g];

  float mt = -1e30f;
  for (int i = lo + c; i < hi; i += 128) mt = fmaxf(mt, lrelu(as2[i] + ad));
  #pragma unroll
  for (int o = 32; o; o >>= 1) mt = fmaxf(mt, __shfl_xor(mt, o, 64));
  if ((c & 63) == 0) red[c >> 6] = mt;
  __syncthreads();
  const float m = fmaxf(red[0], red[1]);

  float st = 0.f;
  for (int i = lo + c; i < hi; i += 128) st += __expf(lrelu(as2[i] + ad) - m);
  #pragma unroll
  for (int o = 32; o; o >>= 1) st += __shfl_xor(st, o, 64);
  __syncthreads();
  if ((c & 63) == 0) red[c >> 6] = st;
  __syncthreads();
  const float inv = 1.f / (red[0] + red[1] + 1e-16f);

  float acc = 0.f;
  for (int i = lo; i < hi; ++i){
    float wgt = __expf(lrelu(as2[i] + ad) - m) * inv;
    acc = fmaf(wgt, __half2float(__ushort_as_half(hs2[(size_t)i*128 + c])), acc);
  }
  float v = elu1(acc + bias[c]);

  float r = v * W2[c];
  #pragma unroll
  for (int o = 32; o; o >>= 1) r += __shfl_xor(r, o, 64);
  __syncthreads();
  if ((c & 63) == 0) red[c >> 6] = r;
  __syncthreads();
  if (c == 0) out[g] = red[0] + red[1] + b2[0];
}

extern "C" void kernel_launch(void* const* d_in, const int* in_sizes, int n_in,
                              void* d_out, int out_size, void* d_ws, size_t ws_size,
                              hipStream_t stream)
{
  const float* x      = (const float*)d_in[0];
  const int*   ei     = (const int*)  d_in[1];
  const int*   batch  = (const int*)  d_in[2];
  const float* W1     = (const float*)d_in[3];
  const float* b1     = (const float*)d_in[4];
  const float* gW     = (const float*)d_in[5];
  const float* g_asrc = (const float*)d_in[6];
  const float* g_adst = (const float*)d_in[7];
  const float* g_b    = (const float*)d_in[8];
  const float* mW     = (const float*)d_in[9];
  const float* m_asrc = (const float*)d_in[10];
  const float* m_adst = (const float*)d_in[11];
  const float* m_b    = (const float*)d_in[12];
  const float* W2     = (const float*)d_in[13];
  const float* b2     = (const float*)d_in[14];

  const int Nn = in_sizes[0] / 64;            // 100000
  const int E  = in_sizes[1] / 2;             // 400000
  const int G  = out_size;                    // 5000
  const int NL = in_sizes[5] / (128*128);     // 3
  const int M2 = Nn + G;
  const int* srcv = ei;
  const int* dstv = ei + E;

  char* w = (char*)d_ws;
  unsigned short* h16 = (unsigned short*)w; w += (size_t)(M2+64)*128*2;
  unsigned short* hsR = (unsigned short*)w; w += (size_t)(M2+64)*128*2;
  float* asO      = (float*)w; w += (size_t)(M2+64)*4;
  float* adO      = (float*)w; w += (size_t)(M2+64)*4;
  int*   deg      = (int*)w;   w += (size_t)Nn*4;
  int*   rp       = (int*)w;   w += (size_t)(Nn+64)*4;
  int*   cur      = (int*)w;   w += (size_t)Nn*4;
  int*   ssorted  = (int*)w;   w += (size_t)E*4;
  unsigned long long* bstat = (unsigned long long*)w; w += 512*8;
  int*   bctr     = (int*)w;   w += 64;
  unsigned short* w1h = (unsigned short*)w; w += 64*128*2;
  unsigned short* w1l = (unsigned short*)w; w += 64*128*2;
  unsigned short* gwh = (unsigned short*)w; w += (size_t)NL*128*128*2;
  unsigned short* gwl = (unsigned short*)w; w += (size_t)NL*128*128*2;
  unsigned short* mwh = (unsigned short*)w; w += 128*128*2;
  unsigned short* mwl = (unsigned short*)w; w += 128*128*2;

  const int nscan = (Nn + 255)/256;
  const int nrt = (Nn + 63)/64;
  const int mrt = (M2 + 63)/64;

  // ---- prep (weights + zero CSR/scan state) ----
  wprep_all<<<nscan, 256, 0, stream>>>(W1, gW, mW, w1h, w1l, gwh, gwl, mwh, mwl,
                                       deg, bstat, bctr, Nn, NL*16384, nscan);

  // ---- CSR build ----
  hist_k<<<(E+255)/256, 256, 0, stream>>>(dstv, deg, E);
  scan_onepass<<<nscan, 256, 0, stream>>>(deg, rp, cur, bstat, bctr, Nn, E);
  scatter_k<<<(E+255)/256, 256, 0, stream>>>(srcv, dstv, cur, ssorted, E);

  // ---- lin1 ----
  gemm_lin1<<<nrt, 256, 0, stream>>>(x, w1h, w1l, b1, h16, Nn);

  // ---- 3 GAT layers ----
  for (int l = 0; l < NL; ++l){
    gemm_mfma<2, true, true><<<nrt, 256, 0, stream>>>(
        h16, gwh + (size_t)l*128*128, gwl + (size_t)l*128*128,
        g_asrc + l*128, g_adst + l*128, hsR, asO, adO, Nn);
    gat_agg<<<(Nn+15)/16, 256, 0, stream>>>(ssorted, rp, asO, adO,
        (const uint4*)hsR, g_b + l*128, (uint4*)h16, Nn);
  }

  // ---- readout ----
  pool_relu<<<(G+15)/16, 256, 0, stream>>>((const uint4*)h16, batch,
      (uint4*)(h16 + (size_t)Nn*128), Nn, G);
  gemm_mfma<2, true, true><<<mrt, 256, 0, stream>>>(
      h16, mwh, mwl, m_asrc, m_adst, hsR, asO, adO, M2);
  mol_agg<<<G, 128, 0, stream>>>(asO, adO + Nn, hsR, batch, m_b, W2, b2, (float*)d_out, Nn);
}